// Round 2
// baseline (18245.914 us; speedup 1.0000x reference)
//
#include <hip/hip_runtime.h>
#include <hip/hip_bf16.h>

#define B_    2
#define T_    1024
#define V_    50257
#define E_    768
#define H_    12
#define L_    12
#define D_    64
#define FF_   3072
#define NTOK  (B_*T_)          // 2048
#define SCALE_ (1.0f/((float)E_*(float)E_))

typedef float f32x4 __attribute__((ext_vector_type(4)));
typedef __bf16 bfrag __attribute__((ext_vector_type(8)));   // 8 bf16 = 4 VGPR
typedef short short8 __attribute__((ext_vector_type(8)));

__device__ __forceinline__ float bits2f(short s) {
    unsigned u = ((unsigned)(unsigned short)s) << 16;
    float f; __builtin_memcpy(&f, &u, 4); return f;
}
__device__ __forceinline__ short f2b(float f) {
    unsigned u; __builtin_memcpy(&u, &f, 4);
    unsigned r = (u + 0x7FFFu + ((u >> 16) & 1u)) >> 16;   // RNE
    return (short)r;
}

// ---------------- embedding: x = tok_emb[idx] + pos_emb (all fp32) ----------------
__global__ __launch_bounds__(256) void embed_kernel(
    const int* __restrict__ idx, const float* __restrict__ tok,
    const float* __restrict__ pos, float* __restrict__ x)
{
    int m = blockIdx.x;                   // token index 0..2047
    int tid = threadIdx.x;
    int row = idx[m];
    int t = m & (T_-1);
    #pragma unroll
    for (int i = 0; i < 3; i++) {
        int e = tid + i*256;
        x[(size_t)m*E_ + e] = tok[(size_t)row*E_ + e] + pos[(size_t)t*E_ + e];
    }
}

// ---------------- layernorm: h = LN(x)*g + b (f32 in, bf16 out) ----------------
__device__ __forceinline__ float block_sum256(float v, float* red) {
    #pragma unroll
    for (int off = 32; off; off >>= 1) v += __shfl_xor(v, off, 64);
    int w = threadIdx.x >> 6;
    __syncthreads();
    if ((threadIdx.x & 63) == 0) red[w] = v;
    __syncthreads();
    return red[0] + red[1] + red[2] + red[3];
}

__global__ __launch_bounds__(256) void ln_kernel(
    const float* __restrict__ x, const float* __restrict__ g,
    const float* __restrict__ bb, short* __restrict__ out)
{
    __shared__ float red[4];
    int m = blockIdx.x, tid = threadIdx.x;
    const float* xr = x + (size_t)m*E_;
    float loc[3]; float s = 0.f;
    #pragma unroll
    for (int i = 0; i < 3; i++) { loc[i] = xr[tid + i*256]; s += loc[i]; }
    s = block_sum256(s, red);
    float mean = s * (1.0f/E_);
    float vs = 0.f;
    #pragma unroll
    for (int i = 0; i < 3; i++) { float d = loc[i] - mean; vs += d*d; }
    vs = block_sum256(vs, red);
    float rstd = rsqrtf(vs * (1.0f/E_) + 1e-5f);
    #pragma unroll
    for (int i = 0; i < 3; i++) {
        int e = tid + i*256;
        out[(size_t)m*E_ + e] = f2b((loc[i] - mean) * rstd * g[e] + bb[e]);
    }
}

// ---------------- generic MFMA GEMM: bf16 A (ws) x fp32 B (input, converted) ----------------
// C[M,N] = A[M,K] @ B[K,N];  b_addr(k,n) = (n>>6)*hs + k*ldb + (n&63)
//   normal row-major B: hs=64, ldb=N.   QKV weights [H,E,D]: hs=E*D, ldb=64.
// MODE 0: OutF = acc + bias[n]  (fp32, LM head -> d_out)
// MODE 1: Out  = bf16(relu(acc + bias[n]))   (FFN1 -> midb)
// MODE 2: X[row*E+col] += acc + bias[n]      (f32 residual; proj/FFN2)
// MODE 3: qkv scatter bf16: Out[((b*H+h)*T+t)*64+d]
template<int MODE>
__global__ __launch_bounds__(256) void gemm_kernel(
    const short* __restrict__ A, const float* __restrict__ Bm,
    const float* __restrict__ bias, float* __restrict__ X,
    short* __restrict__ Out, float* __restrict__ OutF,
    int M, int N, int K, int lda, int ldb, size_t hs, size_t ldc)
{
    __shared__ __align__(16) short As[64*40];   // A[row][k], padded row=40
    __shared__ __align__(16) short Bs[64*40];   // B^T: Bs[col][k]

    int tid  = threadIdx.x;
    int lane = tid & 63, wave = tid >> 6;
    int wm = wave >> 1, wn = wave & 1;          // 2x2 wave grid
    int m0 = blockIdx.x * 64, n0 = blockIdx.y * 64;

    f32x4 acc[2][2];
    #pragma unroll
    for (int i = 0; i < 2; i++)
        #pragma unroll
        for (int j = 0; j < 2; j++) acc[i][j] = (f32x4){0.f,0.f,0.f,0.f};

    const bool bvec = ((ldb & 3) == 0);         // 16B-aligned float4 loads ok

    for (int k0 = 0; k0 < K; k0 += 32) {
        { // stage A tile 64x32 (bf16 vector, always in-bounds: M%64==0, K%32==0)
            int row = tid >> 2, cg = (tid & 3) << 3;
            const short* src = A + (size_t)(m0 + row)*lda + k0 + cg;
            *(short8*)&As[row*40 + cg] = *(const short8*)src;
        }
        { // stage B tile 32x64 transposed into Bs (fp32 -> bf16)
            int kk = tid >> 3, ng = (tid & 7) << 3;
            int nn = n0 + ng;
            size_t base = (size_t)(nn >> 6)*hs + (size_t)(k0 + kk)*ldb + (nn & 63);
            float tmp[8];
            if (bvec && (nn + 8 <= N)) {
                f32x4 v0 = *(const f32x4*)(Bm + base);
                f32x4 v1 = *(const f32x4*)(Bm + base + 4);
                #pragma unroll
                for (int j = 0; j < 4; j++) { tmp[j] = v0[j]; tmp[4+j] = v1[j]; }
            } else {
                #pragma unroll
                for (int j = 0; j < 8; j++) tmp[j] = (nn + j < N) ? Bm[base + j] : 0.f;
            }
            #pragma unroll
            for (int j = 0; j < 8; j++) Bs[(ng + j)*40 + kk] = f2b(tmp[j]);
        }
        __syncthreads();

        int r  = lane & 15;
        int ks = (lane >> 4) << 3;
        bfrag af0 = *(const bfrag*)&As[(wm*32 +      r)*40 + ks];
        bfrag af1 = *(const bfrag*)&As[(wm*32 + 16 + r)*40 + ks];
        bfrag bg0 = *(const bfrag*)&Bs[(wn*32 +      r)*40 + ks];
        bfrag bg1 = *(const bfrag*)&Bs[(wn*32 + 16 + r)*40 + ks];
        acc[0][0] = __builtin_amdgcn_mfma_f32_16x16x32_bf16(af0, bg0, acc[0][0], 0, 0, 0);
        acc[0][1] = __builtin_amdgcn_mfma_f32_16x16x32_bf16(af0, bg1, acc[0][1], 0, 0, 0);
        acc[1][0] = __builtin_amdgcn_mfma_f32_16x16x32_bf16(af1, bg0, acc[1][0], 0, 0, 0);
        acc[1][1] = __builtin_amdgcn_mfma_f32_16x16x32_bf16(af1, bg1, acc[1][1], 0, 0, 0);
        __syncthreads();
    }

    // epilogue — C/D layout: col = lane&15, row = 4*(lane>>4)+reg   [m89]
    int rbase = (lane >> 4) << 2;
    int cbase = lane & 15;
    #pragma unroll
    for (int mi = 0; mi < 2; mi++) {
        #pragma unroll
        for (int ni = 0; ni < 2; ni++) {
            #pragma unroll
            for (int j = 0; j < 4; j++) {
                int row = m0 + wm*32 + mi*16 + rbase + j;
                int col = n0 + wn*32 + ni*16 + cbase;
                if (col >= N) continue;
                float v = acc[mi][ni][j];
                if (MODE == 0) {
                    OutF[(size_t)row*ldc + col] = v + bias[col];
                } else if (MODE == 1) {
                    v += bias[col];
                    v = v > 0.f ? v : 0.f;
                    Out[(size_t)row*ldc + col] = f2b(v);
                } else if (MODE == 2) {
                    X[(size_t)row*E_ + col] += v + bias[col];
                } else {
                    int b = row >> 10, t = row & (T_-1);
                    int h = col >> 6,  d = col & 63;
                    Out[(((size_t)(b*H_ + h)*T_ + t) << 6) + d] = f2b(v);
                }
            }
        }
    }
}

// ---------------- attention: one wave per (b,h,t), online softmax ----------------
// scores[t,s] = (k[t] . q[s]) * SCALE, s <= t  (faithful to source: k @ q^T)
__global__ __launch_bounds__(256) void attn_kernel(
    const short* __restrict__ q, const short* __restrict__ k,
    const short* __restrict__ v, short* __restrict__ ao)
{
    int wid  = blockIdx.x*4 + (threadIdx.x >> 6);   // 0 .. B*H*T-1
    int lane = threadIdx.x & 63;                    // = d
    int t  = wid & (T_-1);
    int bh = wid >> 10;                             // b*H + h
    int h  = bh % H_;
    int b  = bh / H_;
    size_t base = (size_t)bh * T_ * 64;

    float kt = bits2f(k[base + (size_t)t*64 + lane]);
    float m_run = -3.0e38f, l_run = 0.f, o = 0.f;
    for (int s = 0; s <= t; ++s) {
        float qs = bits2f(q[base + (size_t)s*64 + lane]);
        float p  = kt * qs;
        #pragma unroll
        for (int off = 32; off; off >>= 1) p += __shfl_xor(p, off, 64);
        float sc = p * SCALE_;
        float mn = fmaxf(m_run, sc);
        float alpha = __expf(m_run - mn);
        float pw    = __expf(sc - mn);
        l_run = l_run*alpha + pw;
        float vs = bits2f(v[base + (size_t)s*64 + lane]);
        o = o*alpha + pw*vs;
        m_run = mn;
    }
    ao[((size_t)(b*T_ + t))*E_ + h*64 + lane] = f2b(o / l_run);
}

// ---------------- host launch ----------------
extern "C" void kernel_launch(void* const* d_in, const int* in_sizes, int n_in,
                              void* d_out, int out_size, void* d_ws, size_t ws_size,
                              hipStream_t stream)
{
    (void)in_sizes; (void)n_in; (void)out_size; (void)ws_size;

    const int*   idx     = (const int*)  d_in[0];
    const float* tok_emb = (const float*)d_in[1];
    const float* pos_emb = (const float*)d_in[2];
    const float* Wk      = (const float*)d_in[3];
    const float* Wq      = (const float*)d_in[4];
    const float* Wv      = (const float*)d_in[5];
    const float* Wproj   = (const float*)d_in[6];
    const float* bproj   = (const float*)d_in[7];
    const float* ln1_g   = (const float*)d_in[8];
    const float* ln1_b   = (const float*)d_in[9];
    const float* W1      = (const float*)d_in[10];
    const float* b1      = (const float*)d_in[11];
    const float* W2      = (const float*)d_in[12];
    const float* b2      = (const float*)d_in[13];
    const float* ln2_g   = (const float*)d_in[14];
    const float* ln2_b   = (const float*)d_in[15];
    const float* lnf_g   = (const float*)d_in[16];
    const float* lnf_b   = (const float*)d_in[17];
    const float* Wlm     = (const float*)d_in[18];
    const float* blm     = (const float*)d_in[19];
    float* out = (float*)d_out;

    char* w = (char*)d_ws;
    float* x    = (float*)w; w += (size_t)NTOK*E_*4;
    short* hbuf = (short*)w; w += (size_t)NTOK*E_*2;
    short* qb   = (short*)w; w += (size_t)NTOK*E_*2;
    short* kb   = (short*)w; w += (size_t)NTOK*E_*2;
    short* vb   = (short*)w; w += (size_t)NTOK*E_*2;
    short* aob  = (short*)w; w += (size_t)NTOK*E_*2;
    short* midb = (short*)w; w += (size_t)NTOK*FF_*2;

    embed_kernel<<<NTOK, 256, 0, stream>>>(idx, tok_emb, pos_emb, x);

    const size_t HED = (size_t)H_*E_*D_;   // per-layer qkv weight stride
    dim3 gE (NTOK/64, E_/64);              // 32 x 12
    dim3 gFF(NTOK/64, FF_/64);             // 32 x 48
    dim3 gV (NTOK/64, (V_ + 63)/64);       // 32 x 786

    for (int l = 0; l < L_; l++) {
        ln_kernel<<<NTOK, 256, 0, stream>>>(x, ln1_g + (size_t)l*E_, ln1_b + (size_t)l*E_, hbuf);

        gemm_kernel<3><<<gE, 256, 0, stream>>>(hbuf, Wq + (size_t)l*HED, nullptr, nullptr, qb, nullptr,
                                               NTOK, E_, E_, E_, D_, (size_t)E_*D_, 0);
        gemm_kernel<3><<<gE, 256, 0, stream>>>(hbuf, Wk + (size_t)l*HED, nullptr, nullptr, kb, nullptr,
                                               NTOK, E_, E_, E_, D_, (size_t)E_*D_, 0);
        gemm_kernel<3><<<gE, 256, 0, stream>>>(hbuf, Wv + (size_t)l*HED, nullptr, nullptr, vb, nullptr,
                                               NTOK, E_, E_, E_, D_, (size_t)E_*D_, 0);

        attn_kernel<<<B_*H_*T_/4, 256, 0, stream>>>(qb, kb, vb, aob);

        gemm_kernel<2><<<gE, 256, 0, stream>>>(aob, Wproj + (size_t)l*E_*E_, bproj + (size_t)l*E_,
                                               x, nullptr, nullptr, NTOK, E_, E_, E_, E_, 64, 0);

        ln_kernel<<<NTOK, 256, 0, stream>>>(x, ln2_g + (size_t)l*E_, ln2_b + (size_t)l*E_, hbuf);

        gemm_kernel<1><<<gFF, 256, 0, stream>>>(hbuf, W1 + (size_t)l*E_*FF_, b1 + (size_t)l*FF_,
                                                nullptr, midb, nullptr, NTOK, FF_, E_, E_, FF_, 64, FF_);

        gemm_kernel<2><<<gE, 256, 0, stream>>>(midb, W2 + (size_t)l*FF_*E_, b2 + (size_t)l*E_,
                                               x, nullptr, nullptr, NTOK, E_, FF_, FF_, E_, 64, 0);
    }

    ln_kernel<<<NTOK, 256, 0, stream>>>(x, lnf_g, lnf_b, hbuf);
    gemm_kernel<0><<<gV, 256, 0, stream>>>(hbuf, Wlm, blm, nullptr, nullptr, out,
                                           NTOK, V_, E_, E_, V_, 64, V_);
}

// Round 3
// 13949.921 us; speedup vs baseline: 1.3080x; 1.3080x over previous
//
#include <hip/hip_runtime.h>
#include <hip/hip_bf16.h>
#include <stdint.h>

#define B_    2
#define T_    1024
#define V_    50257
#define E_    768
#define H_    12
#define L_    12
#define D_    64
#define FF_   3072
#define NTOK  (B_*T_)          // 2048
#define SCALE_ (1.0f/((float)E_*(float)E_))

typedef float f32x4 __attribute__((ext_vector_type(4)));
typedef __bf16 bf16x8 __attribute__((ext_vector_type(8)));
typedef short short8 __attribute__((ext_vector_type(8)));

__device__ __forceinline__ float bits2f(short s) {
    unsigned u = ((unsigned)(unsigned short)s) << 16;
    float f; __builtin_memcpy(&f, &u, 4); return f;
}
__device__ __forceinline__ short f2b(float f) {
    unsigned u; __builtin_memcpy(&u, &f, 4);
    unsigned r = (u + 0x7FFFu + ((u >> 16) & 1u)) >> 16;   // RNE
    return (short)r;
}

// ---------------- embedding ----------------
__global__ __launch_bounds__(256) void embed_kernel(
    const int* __restrict__ idx, const float* __restrict__ tok,
    const float* __restrict__ pos, float* __restrict__ x)
{
    int m = blockIdx.x, tid = threadIdx.x;
    int row = idx[m];
    int t = m & (T_-1);
    #pragma unroll
    for (int i = 0; i < 3; i++) {
        int e = tid + i*256;
        x[(size_t)m*E_ + e] = tok[(size_t)row*E_ + e] + pos[(size_t)t*E_ + e];
    }
}

// ---------------- layernorm (f32 in, bf16 out) ----------------
__device__ __forceinline__ float block_sum256(float v, float* red) {
    #pragma unroll
    for (int off = 32; off; off >>= 1) v += __shfl_xor(v, off, 64);
    int w = threadIdx.x >> 6;
    __syncthreads();
    if ((threadIdx.x & 63) == 0) red[w] = v;
    __syncthreads();
    return red[0] + red[1] + red[2] + red[3];
}

__global__ __launch_bounds__(256) void ln_kernel(
    const float* __restrict__ x, const float* __restrict__ g,
    const float* __restrict__ bb, short* __restrict__ out)
{
    __shared__ float red[4];
    int m = blockIdx.x, tid = threadIdx.x;
    const float* xr = x + (size_t)m*E_;
    float loc[3]; float s = 0.f;
    #pragma unroll
    for (int i = 0; i < 3; i++) { loc[i] = xr[tid + i*256]; s += loc[i]; }
    s = block_sum256(s, red);
    float mean = s * (1.0f/E_);
    float vs = 0.f;
    #pragma unroll
    for (int i = 0; i < 3; i++) { float d = loc[i] - mean; vs += d*d; }
    vs = block_sum256(vs, red);
    float rstd = rsqrtf(vs * (1.0f/E_) + 1e-5f);
    #pragma unroll
    for (int i = 0; i < 3; i++) {
        int e = tid + i*256;
        out[(size_t)m*E_ + e] = f2b((loc[i] - mean) * rstd * g[e] + bb[e]);
    }
}

// ---------------- 128x128 MFMA GEMM: bf16 A (ws) x fp32 B (input) ----------------
// MODE 0: OutF[row*ldc+col] = acc + bias       (fp32, LM head)
// MODE 1: Out[row*ldc+col]  = bf16(relu(acc+bias))  (FFN1)
// MODE 2: X[row*E+col]     += acc + bias       (f32 residual; proj/FFN2)
// MODE 3: fused QKV scatter bf16 -> Out + nsel*NTOK*E, [(b*H+h)*T+t]*64+d
// B addressing: QKV3 -> [H,E,D] per selected matrix, kstride=64; else B[k*kstride + n0+n].
template<int MODE, bool QKV3>
__global__ __launch_bounds__(256) void gemm2(
    const short* __restrict__ A,
    const float* __restrict__ Bq, const float* __restrict__ Bk2, const float* __restrict__ Bv2,
    const float* __restrict__ bias,
    float* __restrict__ X, short* __restrict__ Out, float* __restrict__ OutF,
    int M, int Ntot, int K, int lda, int kstride, int ldc)
{
    __shared__ __align__(16) short As[128*32];   // (row,k) swizzled 16B slots
    __shared__ __align__(16) short Bs[128*32];   // (col,k) swizzled 16B slots

    const int tid  = threadIdx.x;
    const int lane = tid & 63, wave = tid >> 6;
    const int wm = wave & 1, wn = wave >> 1;
    const int m0 = blockIdx.x * 128;
    const int n0 = blockIdx.y * 128;
    const int g  = lane >> 4;

    const float* Bm = Bq;
    int nsel = 0, c0 = n0;
    if (QKV3) {
        nsel = n0 / 768;
        c0 = n0 - nsel*768;
        Bm = (nsel == 0) ? Bq : (nsel == 1 ? Bk2 : Bv2);
    }

    f32x4 acc[4][4];
    #pragma unroll
    for (int i = 0; i < 4; i++)
        #pragma unroll
        for (int j = 0; j < 4; j++) acc[i][j] = (f32x4){0.f,0.f,0.f,0.f};

    // B staging mapping: one column per thread, 16 k's
    const int bn  = tid & 127;
    const int bkh = tid >> 7;              // 0/1
    const int cg  = c0 + bn;               // col within selected matrix
    const bool bvalid = QKV3 ? true : (cg < Ntot);
    size_t bbase;
    if (QKV3) bbase = (size_t)(cg >> 6) * ((size_t)E_*D_) + (cg & 63);
    else      bbase = (size_t)cg;

    for (int k0 = 0; k0 < K; k0 += 32) {
        // ---- stage A (bf16, vector) ----
        #pragma unroll
        for (int is = 0; is < 2; is++) {
            int idx = is*256 + tid;
            int row = idx >> 2, sl = idx & 3;
            short8 v = *(const short8*)(A + (size_t)(m0+row)*lda + k0 + sl*8);
            int sl2 = sl ^ ((row ^ (row>>2)) & 3);
            *(short8*)&As[row*32 + sl2*8] = v;
        }
        // ---- stage B (fp32 -> bf16, 16 coalesced scalar loads) ----
        {
            float bv[16];
            #pragma unroll
            for (int i = 0; i < 16; i++) {
                int k = k0 + bkh*16 + i;
                bv[i] = bvalid ? Bm[bbase + (size_t)k*kstride] : 0.f;
            }
            short bh16[16];
            #pragma unroll
            for (int i = 0; i < 16; i++) {
                __bf16 h = (__bf16)bv[i];
                bh16[i] = __builtin_bit_cast(short, h);
            }
            #pragma unroll
            for (int q = 0; q < 2; q++) {
                int kb  = bkh*2 + q;
                int sl2 = kb ^ ((bn ^ (bn>>2)) & 3);
                *(short8*)&Bs[bn*32 + sl2*8] = *(short8*)&bh16[q*8];
            }
        }
        __syncthreads();

        // ---- frags + 16 MFMA ----
        bf16x8 af[4];
        #pragma unroll
        for (int mi = 0; mi < 4; mi++) {
            int row = wm*64 + mi*16 + (lane & 15);
            int sl2 = g ^ ((row ^ (row>>2)) & 3);
            af[mi] = *(const bf16x8*)&As[row*32 + sl2*8];
        }
        #pragma unroll
        for (int ni = 0; ni < 4; ni++) {
            int nn  = wn*64 + ni*16 + (lane & 15);
            int sl2 = g ^ ((nn ^ (nn>>2)) & 3);
            bf16x8 bfr = *(const bf16x8*)&Bs[nn*32 + sl2*8];
            #pragma unroll
            for (int mi = 0; mi < 4; mi++)
                acc[mi][ni] = __builtin_amdgcn_mfma_f32_16x16x32_bf16(af[mi], bfr, acc[mi][ni], 0,0,0);
        }
        __syncthreads();
    }

    // ---- epilogue: C/D layout col=lane&15, row=4*(lane>>4)+reg [m89] ----
    const int rb = g << 2;
    const int cb = lane & 15;
    #pragma unroll
    for (int mi = 0; mi < 4; mi++) {
      #pragma unroll
      for (int ni = 0; ni < 4; ni++) {
        #pragma unroll
        for (int j = 0; j < 4; j++) {
            int row = m0 + wm*64 + mi*16 + rb + j;
            int col = n0 + wn*64 + ni*16 + cb;
            float v = acc[mi][ni][j];
            if (MODE == 0) {
                if (col < Ntot) OutF[(size_t)row*ldc + col] = v + bias[col];
            } else if (MODE == 1) {
                v += bias[col];
                v = v > 0.f ? v : 0.f;
                Out[(size_t)row*ldc + col] = f2b(v);
            } else if (MODE == 2) {
                X[(size_t)row*E_ + col] += v + bias[col];
            } else {
                int c = col - nsel*768;
                int h = c >> 6, d = c & 63;
                int b = row >> 10, t = row & (T_-1);
                short* dst = Out + (size_t)nsel*((size_t)NTOK*E_);
                dst[(((size_t)(b*H_ + h)*T_ + t) << 6) + d] = f2b(v);
            }
        }
      }
    }
}

// ---------------- flash attention (faithful swap: "Q"=k-proj, "K"=q-proj) ----------------
// scores[t,s] = (k[t].q[s])*SCALE, causal s<=t. Block: 64 t-rows, 4 waves x 16 rows.
__global__ __launch_bounds__(256) void attn2(
    const short* __restrict__ qg, const short* __restrict__ kg,
    const short* __restrict__ vg, short* __restrict__ ao)
{
    __shared__ __align__(16) short Kt[64*64];      // A tile (t rows)
    __shared__ __align__(16) short Qs[64*64];      // B tile (s rows)
    __shared__ __align__(16) short Vs[64*64];      // V^T tile [d][s]
    __shared__ __align__(16) short Ps[4][16*64];   // wave-private P

    const int tid = threadIdx.x, lane = tid & 63, w = tid >> 6, g = lane >> 4;
    const int t0 = blockIdx.x * 64;
    const int bh = blockIdx.y;
    const size_t base = (size_t)bh * T_ * 64;

    // stage Kt once
    #pragma unroll
    for (int is = 0; is < 2; is++) {
        int idx = is*256 + tid;
        int row = idx >> 3, sl = idx & 7;
        short8 v = *(const short8*)(kg + base + (size_t)(t0+row)*64 + sl*8);
        *(short8*)&Kt[row*64 + (sl ^ (row&7))*8] = v;
    }
    __syncthreads();

    bf16x8 akt[2];
    {
        int lt = w*16 + (lane & 15);
        #pragma unroll
        for (int c = 0; c < 2; c++)
            akt[c] = *(const bf16x8*)&Kt[lt*64 + ((c*4+g) ^ (lt&7))*8];
    }

    f32x4 o[4]; float m_run[4], l_run[4];
    #pragma unroll
    for (int i = 0; i < 4; i++) { o[i] = (f32x4){0,0,0,0}; m_run[i] = -1e30f; l_run[i] = 0.f; }

    const int vd0 = (tid & 31) * 2;
    const int vsh = tid >> 5;          // 0..7

    const int ntiles = (t0 >> 6) + 1;
    for (int it = 0; it < ntiles; ++it) {
        const int s0 = it*64;
        __syncthreads();               // previous tile fully consumed
        // stage Qs (s rows)
        #pragma unroll
        for (int is = 0; is < 2; is++) {
            int idx = is*256 + tid;
            int row = idx >> 3, sl = idx & 7;
            short8 v = *(const short8*)(qg + base + (size_t)(s0+row)*64 + sl*8);
            *(short8*)&Qs[row*64 + (sl ^ (row&7))*8] = v;
        }
        // stage Vs transposed [d][s]
        {
            unsigned vv[8];
            #pragma unroll
            for (int i = 0; i < 8; i++)
                vv[i] = *(const unsigned*)(vg + base + (size_t)(s0 + vsh*8 + i)*64 + vd0);
            #pragma unroll
            for (int dp = 0; dp < 2; dp++) {
                int d = vd0 + dp;
                short tmp[8];
                #pragma unroll
                for (int i = 0; i < 8; i++) tmp[i] = (short)((vv[i] >> (dp*16)) & 0xffffu);
                *(short8*)&Vs[d*64 + (vsh ^ (d&7))*8] = *(short8*)tmp;
            }
        }
        __syncthreads();

        // ---- QK^T ----
        f32x4 s4[4];
        #pragma unroll
        for (int j = 0; j < 4; j++) s4[j] = (f32x4){0,0,0,0};
        #pragma unroll
        for (int c = 0; c < 2; c++) {
            #pragma unroll
            for (int j = 0; j < 4; j++) {
                int sr = j*16 + (lane & 15);
                bf16x8 bq = *(const bf16x8*)&Qs[sr*64 + ((c*4+g) ^ (sr&7))*8];
                s4[j] = __builtin_amdgcn_mfma_f32_16x16x32_bf16(akt[c], bq, s4[j], 0,0,0);
            }
        }
        // scale + causal mask (diagonal tile only)
        float p[4][4];
        const bool diag = (it == ntiles-1);
        #pragma unroll
        for (int j = 0; j < 4; j++) {
          #pragma unroll
          for (int r = 0; r < 4; r++) {
            float v = s4[j][r] * SCALE_;
            if (diag) {
                int tglob = t0 + w*16 + g*4 + r;
                int sglob = s0 + j*16 + (lane & 15);
                if (sglob > tglob) v = -1e30f;
            }
            p[j][r] = v;
          }
        }
        // online softmax per row r
        #pragma unroll
        for (int r = 0; r < 4; r++) {
            float mx = fmaxf(fmaxf(p[0][r], p[1][r]), fmaxf(p[2][r], p[3][r]));
            #pragma unroll
            for (int off = 1; off < 16; off <<= 1) mx = fmaxf(mx, __shfl_xor(mx, off, 64));
            float mnew  = fmaxf(m_run[r], mx);
            float alpha = __expf(m_run[r] - mnew);
            float rs = 0.f;
            #pragma unroll
            for (int j = 0; j < 4; j++) { p[j][r] = __expf(p[j][r] - mnew); rs += p[j][r]; }
            #pragma unroll
            for (int off = 1; off < 16; off <<= 1) rs += __shfl_xor(rs, off, 64);
            l_run[r] = l_run[r]*alpha + rs;
            m_run[r] = mnew;
            #pragma unroll
            for (int ni = 0; ni < 4; ni++) o[ni][r] *= alpha;
        }
        // write P (bf16) to wave-private LDS
        #pragma unroll
        for (int j = 0; j < 4; j++) {
          #pragma unroll
          for (int r = 0; r < 4; r++) {
            int tl = g*4 + r, sc = j*16 + (lane & 15);
            Ps[w][tl*64 + ((sc>>3) ^ (tl&7))*8 + (sc&7)] = f2b(p[j][r]);
          }
        }
        asm volatile("s_waitcnt lgkmcnt(0)" ::: "memory");
        __builtin_amdgcn_sched_barrier(0);
        // ---- PV ----
        #pragma unroll
        for (int c = 0; c < 2; c++) {
            int tl = lane & 15;
            bf16x8 pa = *(const bf16x8*)&Ps[w][tl*64 + ((c*4+g) ^ (tl&7))*8];
            #pragma unroll
            for (int ni = 0; ni < 4; ni++) {
                int d = ni*16 + (lane & 15);
                bf16x8 bv = *(const bf16x8*)&Vs[d*64 + ((c*4+g) ^ (d&7))*8];
                o[ni] = __builtin_amdgcn_mfma_f32_16x16x32_bf16(pa, bv, o[ni], 0,0,0);
            }
        }
    }

    // epilogue -> aob [b,t,E] with head offset
    const int b = bh / H_, h = bh - b*H_;
    #pragma unroll
    for (int ni = 0; ni < 4; ni++) {
      #pragma unroll
      for (int r = 0; r < 4; r++) {
        int t = t0 + w*16 + g*4 + r;
        int d = ni*16 + (lane & 15);
        ao[((size_t)(b*T_ + t))*E_ + h*64 + d] = f2b(o[ni][r] / l_run[r]);
      }
    }
}

// ---------------- host launch ----------------
extern "C" void kernel_launch(void* const* d_in, const int* in_sizes, int n_in,
                              void* d_out, int out_size, void* d_ws, size_t ws_size,
                              hipStream_t stream)
{
    (void)in_sizes; (void)n_in; (void)out_size; (void)ws_size;

    const int*   idx     = (const int*)  d_in[0];
    const float* tok_emb = (const float*)d_in[1];
    const float* pos_emb = (const float*)d_in[2];
    const float* Wk      = (const float*)d_in[3];
    const float* Wq      = (const float*)d_in[4];
    const float* Wv      = (const float*)d_in[5];
    const float* Wproj   = (const float*)d_in[6];
    const float* bproj   = (const float*)d_in[7];
    const float* ln1_g   = (const float*)d_in[8];
    const float* ln1_b   = (const float*)d_in[9];
    const float* W1      = (const float*)d_in[10];
    const float* b1      = (const float*)d_in[11];
    const float* W2      = (const float*)d_in[12];
    const float* b2      = (const float*)d_in[13];
    const float* ln2_g   = (const float*)d_in[14];
    const float* ln2_b   = (const float*)d_in[15];
    const float* lnf_g   = (const float*)d_in[16];
    const float* lnf_b   = (const float*)d_in[17];
    const float* Wlm     = (const float*)d_in[18];
    const float* blm     = (const float*)d_in[19];
    float* out = (float*)d_out;

    char* w = (char*)d_ws;
    float* x    = (float*)w; w += (size_t)NTOK*E_*4;
    short* hbuf = (short*)w; w += (size_t)NTOK*E_*2;
    short* qb   = (short*)w; w += (size_t)NTOK*E_*2;   // qb,kb,vb consecutive (mode-3 scatter)
    short* kb   = (short*)w; w += (size_t)NTOK*E_*2;
    short* vb   = (short*)w; w += (size_t)NTOK*E_*2;
    short* aob  = (short*)w; w += (size_t)NTOK*E_*2;
    short* midb = (short*)w; w += (size_t)NTOK*FF_*2;

    embed_kernel<<<NTOK, 256, 0, stream>>>(idx, tok_emb, pos_emb, x);

    const size_t HED = (size_t)H_*E_*D_;
    dim3 gQKV(16, 18);                 // M/128 x 2304/128
    dim3 gP  (16, 6);                  // N=768
    dim3 gF1 (16, 24);                 // N=3072
    dim3 gLM (16, 393);                // N=50257 (393*128=50304)
    dim3 gAT (T_/64, B_*H_);

    for (int l = 0; l < L_; l++) {
        ln_kernel<<<NTOK, 256, 0, stream>>>(x, ln1_g + (size_t)l*E_, ln1_b + (size_t)l*E_, hbuf);

        gemm2<3,true><<<gQKV, 256, 0, stream>>>(hbuf,
            Wq + (size_t)l*HED, Wk + (size_t)l*HED, Wv + (size_t)l*HED,
            nullptr, nullptr, qb, nullptr,
            NTOK, 2304, E_, E_, 64, 0);

        attn2<<<gAT, 256, 0, stream>>>(qb, kb, vb, aob);

        gemm2<2,false><<<gP, 256, 0, stream>>>(aob,
            Wproj + (size_t)l*E_*E_, nullptr, nullptr, bproj + (size_t)l*E_,
            x, nullptr, nullptr, NTOK, E_, E_, E_, E_, 0);

        ln_kernel<<<NTOK, 256, 0, stream>>>(x, ln2_g + (size_t)l*E_, ln2_b + (size_t)l*E_, hbuf);

        gemm2<1,false><<<gF1, 256, 0, stream>>>(hbuf,
            W1 + (size_t)l*E_*FF_, nullptr, nullptr, b1 + (size_t)l*FF_,
            nullptr, midb, nullptr, NTOK, FF_, E_, E_, FF_, FF_);

        gemm2<2,false><<<gP, 256, 0, stream>>>(midb,
            W2 + (size_t)l*FF_*E_, nullptr, nullptr, b2 + (size_t)l*E_,
            x, nullptr, nullptr, NTOK, E_, FF_, FF_, E_, 0);
    }

    ln_kernel<<<NTOK, 256, 0, stream>>>(x, lnf_g, lnf_b, hbuf);
    gemm2<0,false><<<gLM, 256, 0, stream>>>(hbuf,
        Wlm, nullptr, nullptr, blm,
        nullptr, nullptr, out, NTOK, V_, E_, E_, V_, V_);
}

// Round 4
// 2891.612 us; speedup vs baseline: 6.3099x; 4.8243x over previous
//
#include <hip/hip_runtime.h>
#include <hip/hip_bf16.h>
#include <stdint.h>

#define B_    2
#define T_    1024
#define V_    50257
#define VPAD_ 50304
#define E_    768
#define H_    12
#define L_    12
#define D_    64
#define FF_   3072
#define NTOK  (B_*T_)          // 2048
#define SCALE_ (1.0f/((float)E_*(float)E_))

typedef float f32x4 __attribute__((ext_vector_type(4)));
typedef __bf16 bf16x8 __attribute__((ext_vector_type(8)));
typedef short short8 __attribute__((ext_vector_type(8)));

__device__ __forceinline__ float bits2f(short s) {
    unsigned u = ((unsigned)(unsigned short)s) << 16;
    float f; __builtin_memcpy(&f, &u, 4); return f;
}
__device__ __forceinline__ short f2b(float f) {
    unsigned u; __builtin_memcpy(&u, &f, 4);
    unsigned r = (u + 0x7FFFu + ((u >> 16) & 1u)) >> 16;   // RNE
    return (short)r;
}

#define GLOAD16(gsrc, ldst) __builtin_amdgcn_global_load_lds( \
    (const __attribute__((address_space(1))) unsigned*)(gsrc), \
    (__attribute__((address_space(3))) unsigned*)(ldst), 16, 0, 0)

// ---------------- embedding ----------------
__global__ __launch_bounds__(256) void embed_kernel(
    const int* __restrict__ idx, const float* __restrict__ tok,
    const float* __restrict__ pos, float* __restrict__ x)
{
    int m = blockIdx.x, tid = threadIdx.x;
    int row = idx[m];
    int t = m & (T_-1);
    #pragma unroll
    for (int i = 0; i < 3; i++) {
        int e = tid + i*256;
        x[(size_t)m*E_ + e] = tok[(size_t)row*E_ + e] + pos[(size_t)t*E_ + e];
    }
}

// ---------------- layernorm (f32 in, bf16 out) ----------------
__device__ __forceinline__ float block_sum256(float v, float* red) {
    #pragma unroll
    for (int off = 32; off; off >>= 1) v += __shfl_xor(v, off, 64);
    int w = threadIdx.x >> 6;
    __syncthreads();
    if ((threadIdx.x & 63) == 0) red[w] = v;
    __syncthreads();
    return red[0] + red[1] + red[2] + red[3];
}

__global__ __launch_bounds__(256) void ln_kernel(
    const float* __restrict__ x, const float* __restrict__ g,
    const float* __restrict__ bb, short* __restrict__ out)
{
    __shared__ float red[4];
    int m = blockIdx.x, tid = threadIdx.x;
    const float* xr = x + (size_t)m*E_;
    float loc[3]; float s = 0.f;
    #pragma unroll
    for (int i = 0; i < 3; i++) { loc[i] = xr[tid + i*256]; s += loc[i]; }
    s = block_sum256(s, red);
    float mean = s * (1.0f/E_);
    float vs = 0.f;
    #pragma unroll
    for (int i = 0; i < 3; i++) { float d = loc[i] - mean; vs += d*d; }
    vs = block_sum256(vs, red);
    float rstd = rsqrtf(vs * (1.0f/E_) + 1e-5f);
    #pragma unroll
    for (int i = 0; i < 3; i++) {
        int e = tid + i*256;
        out[(size_t)m*E_ + e] = f2b((loc[i] - mean) * rstd * g[e] + bb[e]);
    }
}

// ---------------- weight packing ----------------
// generic transpose-pack: src fp32 [srcK][srcN] (row stride srcN) -> dst bf16 [dstRows][srcK]
// dst rows beyond srcN are zero-filled (reads guarded). grid: (srcK/64, dstRows/64, L)
__global__ __launch_bounds__(256) void pack_t(
    const float* __restrict__ src, short* __restrict__ dst,
    int srcK, int srcN, size_t sstride, size_t dstride)
{
    __shared__ float tile[64][65];
    int k0 = blockIdx.x*64, n0 = blockIdx.y*64, l = blockIdx.z;
    const float* s = src + (size_t)l*sstride;
    short* d = dst + (size_t)l*dstride;
    int tid = threadIdx.x;
    #pragma unroll
    for (int i = 0; i < 16; i++) {
        int idx = i*256 + tid;
        int r = idx >> 6, c = idx & 63;
        float v = (n0 + c < srcN) ? s[(size_t)(k0+r)*srcN + n0 + c] : 0.f;
        tile[r][c] = v;
    }
    __syncthreads();
    #pragma unroll
    for (int i = 0; i < 16; i++) {
        int idx = i*256 + tid;
        int r2 = idx >> 6, c2 = idx & 63;           // r2 = dst row offset (src col), c2 = k
        d[(size_t)(n0+r2)*srcK + k0 + c2] = f2b(tile[c2][r2]);
    }
}

// QKV pack: Wq/Wk/Wv [L,H,E,D] fp32 -> dst bf16 [L][2304][768]  (row j = sel*768+h*64+d, col e)
// grid: (E/64=12, 36, L); y = sel*12 + h
__global__ __launch_bounds__(256) void pack_qkv(
    const float* __restrict__ Wq, const float* __restrict__ Wk,
    const float* __restrict__ Wv, short* __restrict__ dst)
{
    __shared__ float tile[64][65];
    int e0 = blockIdx.x*64;
    int y = blockIdx.y, sel = y/12, h = y - sel*12;
    int l = blockIdx.z;
    const float* s = (sel == 0 ? Wq : (sel == 1 ? Wk : Wv)) + (((size_t)l*H_ + h)*E_)*D_;
    int tid = threadIdx.x;
    #pragma unroll
    for (int i = 0; i < 16; i++) {
        int idx = i*256 + tid;
        int r = idx >> 6, c = idx & 63;             // r = e_local, c = d
        tile[r][c] = s[(size_t)(e0+r)*D_ + c];
    }
    __syncthreads();
    short* d_ = dst + (size_t)l*2304*E_;
    #pragma unroll
    for (int i = 0; i < 16; i++) {
        int idx = i*256 + tid;
        int r2 = idx >> 6, c2 = idx & 63;           // r2 = d, c2 = e_local
        d_[(size_t)(sel*768 + h*64 + r2)*E_ + e0 + c2] = f2b(tile[c2][r2]);
    }
}

// ---------------- fast bf16 GEMM (m97 structure) ----------------
// C[2048,N] = A[2048,K] @ Bt[N,K]^T ; 128x128 tile, BK=32, global_load_lds staging.
// MODE 0: OutF[row*ldc+col] = acc + bias[col]  (col < Nreal only)
// MODE 1: Out[row*ldc+col]  = bf16(relu(acc+bias))
// MODE 2: X[row*E+col]     += acc + bias
// MODE 3: qkv scatter bf16 (col in 0..2303)
template<int MODE>
__global__ __launch_bounds__(256) void gemm3(
    const short* __restrict__ A, const short* __restrict__ Bt,
    const float* __restrict__ bias,
    float* __restrict__ X, short* __restrict__ Out, float* __restrict__ OutF,
    int K, int lda, int ldc, int Nreal, int cpx)
{
    __shared__ __align__(16) short As[128*32];
    __shared__ __align__(16) short Bs[128*32];

    const int tid  = threadIdx.x;
    const int lane = tid & 63, wv = tid >> 6;
    const int wm = wv & 1, wn = wv >> 1;

    // XCD swizzle: group the 16 M-blocks of each N-panel on one XCD
    int bid = blockIdx.x;
    int g   = (bid & 7)*cpx + (bid >> 3);
    const int m0 = (g & 15) * 128;
    const int n0 = (g >> 4) * 128;

    f32x4 acc[4][4];
    #pragma unroll
    for (int i = 0; i < 4; i++)
        #pragma unroll
        for (int j = 0; j < 4; j++) acc[i][j] = (f32x4){0.f,0.f,0.f,0.f};

    // staging geometry: chunk c = wv*128 + i*64 + lane; row = c>>2, sl = c&3
    const int srow0 = wv*32 + (lane >> 2);
    const int ssl   = lane & 3;

    for (int k0 = 0; k0 < K; k0 += 32) {
        #pragma unroll
        for (int i = 0; i < 2; i++) {
            int row = srow0 + i*16;
            GLOAD16(A  + (size_t)(m0 + row)*lda + k0 + ssl*8, &As[(wv*128 + i*64)*8]);
            GLOAD16(Bt + (size_t)(n0 + row)*K   + k0 + ssl*8, &Bs[(wv*128 + i*64)*8]);
        }
        __syncthreads();

        bf16x8 af[4], bf[4];
        #pragma unroll
        for (int mi = 0; mi < 4; mi++) {
            int row = wm*64 + mi*16 + (lane & 15);
            af[mi] = *(const bf16x8*)&As[row*32 + (lane >> 4)*8];
        }
        #pragma unroll
        for (int ni = 0; ni < 4; ni++) {
            int col = wn*64 + ni*16 + (lane & 15);
            bf[ni] = *(const bf16x8*)&Bs[col*32 + (lane >> 4)*8];
        }
        #pragma unroll
        for (int ni = 0; ni < 4; ni++)
            #pragma unroll
            for (int mi = 0; mi < 4; mi++)
                acc[mi][ni] = __builtin_amdgcn_mfma_f32_16x16x32_bf16(af[mi], bf[ni], acc[mi][ni], 0,0,0);
        __syncthreads();
    }

    // epilogue — C/D: col = lane&15, row = 4*(lane>>4)+reg [m89]
    const int rb = (lane >> 4) << 2;
    const int cb = lane & 15;
    #pragma unroll
    for (int mi = 0; mi < 4; mi++) {
      #pragma unroll
      for (int ni = 0; ni < 4; ni++) {
        #pragma unroll
        for (int j = 0; j < 4; j++) {
            int row = m0 + wm*64 + mi*16 + rb + j;
            int col = n0 + wn*64 + ni*16 + cb;
            float v = acc[mi][ni][j];
            if (MODE == 0) {
                if (col < Nreal) OutF[(size_t)row*ldc + col] = v + bias[col];
            } else if (MODE == 1) {
                v += bias[col];
                v = v > 0.f ? v : 0.f;
                Out[(size_t)row*ldc + col] = f2b(v);
            } else if (MODE == 2) {
                X[(size_t)row*E_ + col] += v + bias[col];
            } else {
                int nsel = col / 768;
                int c = col - nsel*768;
                int h = c >> 6, d = c & 63;
                int b = row >> 10, t = row & (T_-1);
                short* dst = Out + (size_t)nsel*((size_t)NTOK*E_);
                dst[(((size_t)(b*H_ + h)*T_ + t) << 6) + d] = f2b(v);
            }
        }
      }
    }
}

// ---------------- fallback GEMM (round-3, fp32 B on the fly) ----------------
template<int MODE, bool QKV3>
__global__ __launch_bounds__(256) void gemm2(
    const short* __restrict__ A,
    const float* __restrict__ Bq, const float* __restrict__ Bk2, const float* __restrict__ Bv2,
    const float* __restrict__ bias,
    float* __restrict__ X, short* __restrict__ Out, float* __restrict__ OutF,
    int M, int Ntot, int K, int lda, int kstride, int ldc)
{
    __shared__ __align__(16) short As[128*32];
    __shared__ __align__(16) short Bs[128*32];

    const int tid  = threadIdx.x;
    const int lane = tid & 63, wave = tid >> 6;
    const int wm = wave & 1, wn = wave >> 1;
    const int m0 = blockIdx.x * 128;
    const int n0 = blockIdx.y * 128;
    const int g  = lane >> 4;

    const float* Bm = Bq;
    int nsel = 0, c0 = n0;
    if (QKV3) {
        nsel = n0 / 768;
        c0 = n0 - nsel*768;
        Bm = (nsel == 0) ? Bq : (nsel == 1 ? Bk2 : Bv2);
    }

    f32x4 acc[4][4];
    #pragma unroll
    for (int i = 0; i < 4; i++)
        #pragma unroll
        for (int j = 0; j < 4; j++) acc[i][j] = (f32x4){0.f,0.f,0.f,0.f};

    const int bn  = tid & 127;
    const int bkh = tid >> 7;
    const int cg  = c0 + bn;
    const bool bvalid = QKV3 ? true : (cg < Ntot);
    size_t bbase;
    if (QKV3) bbase = (size_t)(cg >> 6) * ((size_t)E_*D_) + (cg & 63);
    else      bbase = (size_t)cg;

    for (int k0 = 0; k0 < K; k0 += 32) {
        #pragma unroll
        for (int is = 0; is < 2; is++) {
            int idx = is*256 + tid;
            int row = idx >> 2, sl = idx & 3;
            short8 v = *(const short8*)(A + (size_t)(m0+row)*lda + k0 + sl*8);
            int sl2 = sl ^ ((row ^ (row>>2)) & 3);
            *(short8*)&As[row*32 + sl2*8] = v;
        }
        {
            float bv[16];
            #pragma unroll
            for (int i = 0; i < 16; i++) {
                int k = k0 + bkh*16 + i;
                bv[i] = bvalid ? Bm[bbase + (size_t)k*kstride] : 0.f;
            }
            short bh16[16];
            #pragma unroll
            for (int i = 0; i < 16; i++) {
                __bf16 h = (__bf16)bv[i];
                bh16[i] = __builtin_bit_cast(short, h);
            }
            #pragma unroll
            for (int q = 0; q < 2; q++) {
                int kb  = bkh*2 + q;
                int sl2 = kb ^ ((bn ^ (bn>>2)) & 3);
                *(short8*)&Bs[bn*32 + sl2*8] = *(short8*)&bh16[q*8];
            }
        }
        __syncthreads();

        bf16x8 af[4];
        #pragma unroll
        for (int mi = 0; mi < 4; mi++) {
            int row = wm*64 + mi*16 + (lane & 15);
            int sl2 = g ^ ((row ^ (row>>2)) & 3);
            af[mi] = *(const bf16x8*)&As[row*32 + sl2*8];
        }
        #pragma unroll
        for (int ni = 0; ni < 4; ni++) {
            int nn  = wn*64 + ni*16 + (lane & 15);
            int sl2 = g ^ ((nn ^ (nn>>2)) & 3);
            bf16x8 bfr = *(const bf16x8*)&Bs[nn*32 + sl2*8];
            #pragma unroll
            for (int mi = 0; mi < 4; mi++)
                acc[mi][ni] = __builtin_amdgcn_mfma_f32_16x16x32_bf16(af[mi], bfr, acc[mi][ni], 0,0,0);
        }
        __syncthreads();
    }

    const int rb = g << 2;
    const int cb = lane & 15;
    #pragma unroll
    for (int mi = 0; mi < 4; mi++) {
      #pragma unroll
      for (int ni = 0; ni < 4; ni++) {
        #pragma unroll
        for (int j = 0; j < 4; j++) {
            int row = m0 + wm*64 + mi*16 + rb + j;
            int col = n0 + wn*64 + ni*16 + cb;
            float v = acc[mi][ni][j];
            if (MODE == 0) {
                if (col < Ntot) OutF[(size_t)row*ldc + col] = v + bias[col];
            } else if (MODE == 1) {
                v += bias[col];
                v = v > 0.f ? v : 0.f;
                Out[(size_t)row*ldc + col] = f2b(v);
            } else if (MODE == 2) {
                X[(size_t)row*E_ + col] += v + bias[col];
            } else {
                int c = col - nsel*768;
                int h = c >> 6, d = c & 63;
                int b = row >> 10, t = row & (T_-1);
                short* dst = Out + (size_t)nsel*((size_t)NTOK*E_);
                dst[(((size_t)(b*H_ + h)*T_ + t) << 6) + d] = f2b(v);
            }
        }
      }
    }
}

// ---------------- flash attention (faithful swap: "Q"=k-proj, "K"=q-proj) ----------------
__global__ __launch_bounds__(256) void attn2(
    const short* __restrict__ qg, const short* __restrict__ kg,
    const short* __restrict__ vg, short* __restrict__ ao)
{
    __shared__ __align__(16) short Kt[64*64];
    __shared__ __align__(16) short Qs[64*64];
    __shared__ __align__(16) short Vs[64*64];
    __shared__ __align__(16) short Ps[4][16*64];

    const int tid = threadIdx.x, lane = tid & 63, w = tid >> 6, g = lane >> 4;
    const int t0 = blockIdx.x * 64;
    const int bh = blockIdx.y;
    const size_t base = (size_t)bh * T_ * 64;

    #pragma unroll
    for (int is = 0; is < 2; is++) {
        int idx = is*256 + tid;
        int row = idx >> 3, sl = idx & 7;
        short8 v = *(const short8*)(kg + base + (size_t)(t0+row)*64 + sl*8);
        *(short8*)&Kt[row*64 + (sl ^ (row&7))*8] = v;
    }
    __syncthreads();

    bf16x8 akt[2];
    {
        int lt = w*16 + (lane & 15);
        #pragma unroll
        for (int c = 0; c < 2; c++)
            akt[c] = *(const bf16x8*)&Kt[lt*64 + ((c*4+g) ^ (lt&7))*8];
    }

    f32x4 o[4]; float m_run[4], l_run[4];
    #pragma unroll
    for (int i = 0; i < 4; i++) { o[i] = (f32x4){0,0,0,0}; m_run[i] = -1e30f; l_run[i] = 0.f; }

    const int vd0 = (tid & 31) * 2;
    const int vsh = tid >> 5;

    const int ntiles = (t0 >> 6) + 1;
    for (int it = 0; it < ntiles; ++it) {
        const int s0 = it*64;
        __syncthreads();
        #pragma unroll
        for (int is = 0; is < 2; is++) {
            int idx = is*256 + tid;
            int row = idx >> 3, sl = idx & 7;
            short8 v = *(const short8*)(qg + base + (size_t)(s0+row)*64 + sl*8);
            *(short8*)&Qs[row*64 + (sl ^ (row&7))*8] = v;
        }
        {
            unsigned vv[8];
            #pragma unroll
            for (int i = 0; i < 8; i++)
                vv[i] = *(const unsigned*)(vg + base + (size_t)(s0 + vsh*8 + i)*64 + vd0);
            #pragma unroll
            for (int dp = 0; dp < 2; dp++) {
                int d = vd0 + dp;
                short tmp[8];
                #pragma unroll
                for (int i = 0; i < 8; i++) tmp[i] = (short)((vv[i] >> (dp*16)) & 0xffffu);
                *(short8*)&Vs[d*64 + (vsh ^ (d&7))*8] = *(short8*)tmp;
            }
        }
        __syncthreads();

        f32x4 s4[4];
        #pragma unroll
        for (int j = 0; j < 4; j++) s4[j] = (f32x4){0,0,0,0};
        #pragma unroll
        for (int c = 0; c < 2; c++) {
            #pragma unroll
            for (int j = 0; j < 4; j++) {
                int sr = j*16 + (lane & 15);
                bf16x8 bq = *(const bf16x8*)&Qs[sr*64 + ((c*4+g) ^ (sr&7))*8];
                s4[j] = __builtin_amdgcn_mfma_f32_16x16x32_bf16(akt[c], bq, s4[j], 0,0,0);
            }
        }
        float p[4][4];
        const bool diag = (it == ntiles-1);
        #pragma unroll
        for (int j = 0; j < 4; j++) {
          #pragma unroll
          for (int r = 0; r < 4; r++) {
            float v = s4[j][r] * SCALE_;
            if (diag) {
                int tglob = t0 + w*16 + g*4 + r;
                int sglob = s0 + j*16 + (lane & 15);
                if (sglob > tglob) v = -1e30f;
            }
            p[j][r] = v;
          }
        }
        #pragma unroll
        for (int r = 0; r < 4; r++) {
            float mx = fmaxf(fmaxf(p[0][r], p[1][r]), fmaxf(p[2][r], p[3][r]));
            #pragma unroll
            for (int off = 1; off < 16; off <<= 1) mx = fmaxf(mx, __shfl_xor(mx, off, 64));
            float mnew  = fmaxf(m_run[r], mx);
            float alpha = __expf(m_run[r] - mnew);
            float rs = 0.f;
            #pragma unroll
            for (int j = 0; j < 4; j++) { p[j][r] = __expf(p[j][r] - mnew); rs += p[j][r]; }
            #pragma unroll
            for (int off = 1; off < 16; off <<= 1) rs += __shfl_xor(rs, off, 64);
            l_run[r] = l_run[r]*alpha + rs;
            m_run[r] = mnew;
            #pragma unroll
            for (int ni = 0; ni < 4; ni++) o[ni][r] *= alpha;
        }
        #pragma unroll
        for (int j = 0; j < 4; j++) {
          #pragma unroll
          for (int r = 0; r < 4; r++) {
            int tl = g*4 + r, sc = j*16 + (lane & 15);
            Ps[w][tl*64 + ((sc>>3) ^ (tl&7))*8 + (sc&7)] = f2b(p[j][r]);
          }
        }
        asm volatile("s_waitcnt lgkmcnt(0)" ::: "memory");
        __builtin_amdgcn_sched_barrier(0);
        #pragma unroll
        for (int c = 0; c < 2; c++) {
            int tl = lane & 15;
            bf16x8 pa = *(const bf16x8*)&Ps[w][tl*64 + ((c*4+g) ^ (tl&7))*8];
            #pragma unroll
            for (int ni = 0; ni < 4; ni++) {
                int d = ni*16 + (lane & 15);
                bf16x8 bv = *(const bf16x8*)&Vs[d*64 + ((c*4+g) ^ (d&7))*8];
                o[ni] = __builtin_amdgcn_mfma_f32_16x16x32_bf16(pa, bv, o[ni], 0,0,0);
            }
        }
    }

    const int b = bh / H_, h = bh - b*H_;
    #pragma unroll
    for (int ni = 0; ni < 4; ni++) {
      #pragma unroll
      for (int r = 0; r < 4; r++) {
        int t = t0 + w*16 + g*4 + r;
        int d = ni*16 + (lane & 15);
        ao[((size_t)(b*T_ + t))*E_ + h*64 + d] = f2b(o[ni][r] / l_run[r]);
      }
    }
}

// ---------------- host launch ----------------
extern "C" void kernel_launch(void* const* d_in, const int* in_sizes, int n_in,
                              void* d_out, int out_size, void* d_ws, size_t ws_size,
                              hipStream_t stream)
{
    (void)in_sizes; (void)n_in; (void)out_size;

    const int*   idx     = (const int*)  d_in[0];
    const float* tok_emb = (const float*)d_in[1];
    const float* pos_emb = (const float*)d_in[2];
    const float* Wk      = (const float*)d_in[3];
    const float* Wq      = (const float*)d_in[4];
    const float* Wv      = (const float*)d_in[5];
    const float* Wproj   = (const float*)d_in[6];
    const float* bproj   = (const float*)d_in[7];
    const float* ln1_g   = (const float*)d_in[8];
    const float* ln1_b   = (const float*)d_in[9];
    const float* W1      = (const float*)d_in[10];
    const float* b1      = (const float*)d_in[11];
    const float* W2      = (const float*)d_in[12];
    const float* b2      = (const float*)d_in[13];
    const float* ln2_g   = (const float*)d_in[14];
    const float* ln2_b   = (const float*)d_in[15];
    const float* lnf_g   = (const float*)d_in[16];
    const float* lnf_b   = (const float*)d_in[17];
    const float* Wlm     = (const float*)d_in[18];
    const float* blm     = (const float*)d_in[19];
    float* out = (float*)d_out;

    char* w = (char*)d_ws;
    float* x    = (float*)w; w += (size_t)NTOK*E_*4;
    short* hbuf = (short*)w; w += (size_t)NTOK*E_*2;
    short* qb   = (short*)w; w += (size_t)NTOK*E_*2;
    short* kb   = (short*)w; w += (size_t)NTOK*E_*2;
    short* vb   = (short*)w; w += (size_t)NTOK*E_*2;
    short* aob  = (short*)w; w += (size_t)NTOK*E_*2;
    short* midb = (short*)w; w += (size_t)NTOK*FF_*2;

    const size_t act_bytes = (size_t)(w - (char*)d_ws);
    const size_t wqkv_n = (size_t)L_*2304*E_;
    const size_t wproj_n = (size_t)L_*E_*E_;
    const size_t wff_n = (size_t)L_*E_*FF_;
    const size_t wlm_n = (size_t)VPAD_*E_;
    const size_t need = act_bytes + 2*(wqkv_n + wproj_n + 2*wff_n + wlm_n);

    const size_t HED = (size_t)H_*E_*D_;
    dim3 gAT(T_/64, B_*H_);

    embed_kernel<<<NTOK, 256, 0, stream>>>(idx, tok_emb, pos_emb, x);

    if (ws_size >= need) {
        // ---------- fast path: prepack weights to bf16 (B^T layout) ----------
        short* qkvw = (short*)w; w += wqkv_n*2;
        short* projw= (short*)w; w += wproj_n*2;
        short* w1w  = (short*)w; w += wff_n*2;
        short* w2w  = (short*)w; w += wff_n*2;
        short* lmw  = (short*)w;

        pack_qkv<<<dim3(E_/64, 36, L_), 256, 0, stream>>>(Wq, Wk, Wv, qkvw);
        pack_t<<<dim3(E_/64, E_/64, L_), 256, 0, stream>>>(Wproj, projw, E_, E_, (size_t)E_*E_, (size_t)E_*E_);
        pack_t<<<dim3(E_/64, FF_/64, L_), 256, 0, stream>>>(W1, w1w, E_, FF_, (size_t)E_*FF_, (size_t)E_*FF_);
        pack_t<<<dim3(FF_/64, E_/64, L_), 256, 0, stream>>>(W2, w2w, FF_, E_, (size_t)E_*FF_, (size_t)E_*FF_);
        pack_t<<<dim3(E_/64, VPAD_/64, 1), 256, 0, stream>>>(Wlm, lmw, E_, V_, 0, 0);

        const int nQKV = 16*(2304/128), nP = 16*(E_/128), nF1 = 16*(FF_/128), nLM = 16*(VPAD_/128);

        for (int l = 0; l < L_; l++) {
            ln_kernel<<<NTOK, 256, 0, stream>>>(x, ln1_g + (size_t)l*E_, ln1_b + (size_t)l*E_, hbuf);
            gemm3<3><<<nQKV, 256, 0, stream>>>(hbuf, qkvw + (size_t)l*2304*E_, nullptr,
                                               nullptr, qb, nullptr, E_, E_, 0, 2304, nQKV/8);
            attn2<<<gAT, 256, 0, stream>>>(qb, kb, vb, aob);
            gemm3<2><<<nP, 256, 0, stream>>>(aob, projw + (size_t)l*E_*E_, bproj + (size_t)l*E_,
                                             x, nullptr, nullptr, E_, E_, 0, E_, nP/8);
            ln_kernel<<<NTOK, 256, 0, stream>>>(x, ln2_g + (size_t)l*E_, ln2_b + (size_t)l*E_, hbuf);
            gemm3<1><<<nF1, 256, 0, stream>>>(hbuf, w1w + (size_t)l*E_*FF_, b1 + (size_t)l*FF_,
                                              nullptr, midb, nullptr, E_, E_, FF_, FF_, nF1/8);
            gemm3<2><<<nP, 256, 0, stream>>>(midb, w2w + (size_t)l*E_*FF_, b2 + (size_t)l*E_,
                                             x, nullptr, nullptr, FF_, FF_, 0, E_, nP/8);
        }
        ln_kernel<<<NTOK, 256, 0, stream>>>(x, lnf_g, lnf_b, hbuf);
        gemm3<0><<<nLM, 256, 0, stream>>>(hbuf, lmw, blm, nullptr, nullptr, out,
                                          E_, E_, V_, V_, nLM/8);
    } else {
        // ---------- fallback: round-3 path ----------
        dim3 gQKV(16, 18), gP(16, 6), gF1(16, 24), gLM(16, 393);
        for (int l = 0; l < L_; l++) {
            ln_kernel<<<NTOK, 256, 0, stream>>>(x, ln1_g + (size_t)l*E_, ln1_b + (size_t)l*E_, hbuf);
            gemm2<3,true><<<gQKV, 256, 0, stream>>>(hbuf,
                Wq + (size_t)l*HED, Wk + (size_t)l*HED, Wv + (size_t)l*HED,
                nullptr, nullptr, qb, nullptr, NTOK, 2304, E_, E_, 64, 0);
            attn2<<<gAT, 256, 0, stream>>>(qb, kb, vb, aob);
            gemm2<2,false><<<gP, 256, 0, stream>>>(aob,
                Wproj + (size_t)l*E_*E_, nullptr, nullptr, bproj + (size_t)l*E_,
                x, nullptr, nullptr, NTOK, E_, E_, E_, E_, 0);
            ln_kernel<<<NTOK, 256, 0, stream>>>(x, ln2_g + (size_t)l*E_, ln2_b + (size_t)l*E_, hbuf);
            gemm2<1,false><<<gF1, 256, 0, stream>>>(hbuf,
                W1 + (size_t)l*E_*FF_, nullptr, nullptr, b1 + (size_t)l*FF_,
                nullptr, midb, nullptr, NTOK, FF_, E_, E_, FF_, FF_);
            gemm2<2,false><<<gP, 256, 0, stream>>>(midb,
                W2 + (size_t)l*FF_*E_, nullptr, nullptr, b2 + (size_t)l*E_,
                x, nullptr, nullptr, NTOK, E_, FF_, FF_, E_, 0);
        }
        ln_kernel<<<NTOK, 256, 0, stream>>>(x, lnf_g, lnf_b, hbuf);
        gemm2<0,false><<<gLM, 256, 0, stream>>>(hbuf,
            Wlm, nullptr, nullptr, blm,
            nullptr, nullptr, out, NTOK, V_, E_, E_, V_, V_);
    }
}

// Round 5
// 2806.239 us; speedup vs baseline: 6.5019x; 1.0304x over previous
//
#include <hip/hip_runtime.h>
#include <hip/hip_bf16.h>
#include <stdint.h>

#define B_    2
#define T_    1024
#define V_    50257
#define VPAD_ 50304
#define E_    768
#define H_    12
#define L_    12
#define D_    64
#define FF_   3072
#define NTOK  (B_*T_)          // 2048
#define SCALE_ (1.0f/((float)E_*(float)E_))

typedef float f32x4 __attribute__((ext_vector_type(4)));
typedef __bf16 bf16x8 __attribute__((ext_vector_type(8)));
typedef short short8 __attribute__((ext_vector_type(8)));

__device__ __forceinline__ float bits2f(short s) {
    unsigned u = ((unsigned)(unsigned short)s) << 16;
    float f; __builtin_memcpy(&f, &u, 4); return f;
}
__device__ __forceinline__ short f2b(float f) {
    unsigned u; __builtin_memcpy(&u, &f, 4);
    unsigned r = (u + 0x7FFFu + ((u >> 16) & 1u)) >> 16;   // RNE
    return (short)r;
}

#define GLOAD16(gsrc, ldst) __builtin_amdgcn_global_load_lds( \
    (const __attribute__((address_space(1))) unsigned*)(gsrc), \
    (__attribute__((address_space(3))) unsigned*)(ldst), 16, 0, 0)

// ---------------- embedding ----------------
__global__ __launch_bounds__(256) void embed_kernel(
    const int* __restrict__ idx, const float* __restrict__ tok,
    const float* __restrict__ pos, float* __restrict__ x)
{
    int m = blockIdx.x, tid = threadIdx.x;
    int row = idx[m];
    int t = m & (T_-1);
    #pragma unroll
    for (int i = 0; i < 3; i++) {
        int e = tid + i*256;
        x[(size_t)m*E_ + e] = tok[(size_t)row*E_ + e] + pos[(size_t)t*E_ + e];
    }
}

// ---------------- layernorm (f32 in, bf16 out) ----------------
__device__ __forceinline__ float block_sum256(float v, float* red) {
    #pragma unroll
    for (int off = 32; off; off >>= 1) v += __shfl_xor(v, off, 64);
    int w = threadIdx.x >> 6;
    __syncthreads();
    if ((threadIdx.x & 63) == 0) red[w] = v;
    __syncthreads();
    return red[0] + red[1] + red[2] + red[3];
}

__global__ __launch_bounds__(256) void ln_kernel(
    const float* __restrict__ x, const float* __restrict__ g,
    const float* __restrict__ bb, short* __restrict__ out)
{
    __shared__ float red[4];
    int m = blockIdx.x, tid = threadIdx.x;
    const float* xr = x + (size_t)m*E_;
    float loc[3]; float s = 0.f;
    #pragma unroll
    for (int i = 0; i < 3; i++) { loc[i] = xr[tid + i*256]; s += loc[i]; }
    s = block_sum256(s, red);
    float mean = s * (1.0f/E_);
    float vs = 0.f;
    #pragma unroll
    for (int i = 0; i < 3; i++) { float d = loc[i] - mean; vs += d*d; }
    vs = block_sum256(vs, red);
    float rstd = rsqrtf(vs * (1.0f/E_) + 1e-5f);
    #pragma unroll
    for (int i = 0; i < 3; i++) {
        int e = tid + i*256;
        out[(size_t)m*E_ + e] = f2b((loc[i] - mean) * rstd * g[e] + bb[e]);
    }
}

// ---------------- weight packing ----------------
__global__ __launch_bounds__(256) void pack_t(
    const float* __restrict__ src, short* __restrict__ dst,
    int srcK, int srcN, size_t sstride, size_t dstride)
{
    __shared__ float tile[64][65];
    int k0 = blockIdx.x*64, n0 = blockIdx.y*64, l = blockIdx.z;
    const float* s = src + (size_t)l*sstride;
    short* d = dst + (size_t)l*dstride;
    int tid = threadIdx.x;
    #pragma unroll
    for (int i = 0; i < 16; i++) {
        int idx = i*256 + tid;
        int r = idx >> 6, c = idx & 63;
        float v = (n0 + c < srcN) ? s[(size_t)(k0+r)*srcN + n0 + c] : 0.f;
        tile[r][c] = v;
    }
    __syncthreads();
    #pragma unroll
    for (int i = 0; i < 16; i++) {
        int idx = i*256 + tid;
        int r2 = idx >> 6, c2 = idx & 63;
        d[(size_t)(n0+r2)*srcK + k0 + c2] = f2b(tile[c2][r2]);
    }
}

__global__ __launch_bounds__(256) void pack_qkv(
    const float* __restrict__ Wq, const float* __restrict__ Wk,
    const float* __restrict__ Wv, short* __restrict__ dst)
{
    __shared__ float tile[64][65];
    int e0 = blockIdx.x*64;
    int y = blockIdx.y, sel = y/12, h = y - sel*12;
    int l = blockIdx.z;
    const float* s = (sel == 0 ? Wq : (sel == 1 ? Wk : Wv)) + (((size_t)l*H_ + h)*E_)*D_;
    int tid = threadIdx.x;
    #pragma unroll
    for (int i = 0; i < 16; i++) {
        int idx = i*256 + tid;
        int r = idx >> 6, c = idx & 63;
        tile[r][c] = s[(size_t)(e0+r)*D_ + c];
    }
    __syncthreads();
    short* d_ = dst + (size_t)l*2304*E_;
    #pragma unroll
    for (int i = 0; i < 16; i++) {
        int idx = i*256 + tid;
        int r2 = idx >> 6, c2 = idx & 63;
        d_[(size_t)(sel*768 + h*64 + r2)*E_ + e0 + c2] = f2b(tile[c2][r2]);
    }
}

// ---------------- fast bf16 GEMM (m97 structure) ----------------
// MODE 0: OutF = acc + bias (col < Nreal);  MODE 1: relu->bf16;  MODE 3: qkv scatter
template<int MODE>
__global__ __launch_bounds__(256) void gemm3(
    const short* __restrict__ A, const short* __restrict__ Bt,
    const float* __restrict__ bias,
    float* __restrict__ X, short* __restrict__ Out, float* __restrict__ OutF,
    int K, int lda, int ldc, int Nreal, int cpx)
{
    __shared__ __align__(16) short As[128*32];
    __shared__ __align__(16) short Bs[128*32];

    const int tid  = threadIdx.x;
    const int lane = tid & 63, wv = tid >> 6;
    const int wm = wv & 1, wn = wv >> 1;

    int bid = blockIdx.x;
    int g   = (bid & 7)*cpx + (bid >> 3);
    const int m0 = (g & 15) * 128;
    const int n0 = (g >> 4) * 128;

    f32x4 acc[4][4];
    #pragma unroll
    for (int i = 0; i < 4; i++)
        #pragma unroll
        for (int j = 0; j < 4; j++) acc[i][j] = (f32x4){0.f,0.f,0.f,0.f};

    const int srow0 = wv*32 + (lane >> 2);
    const int ssl   = lane & 3;

    for (int k0 = 0; k0 < K; k0 += 32) {
        #pragma unroll
        for (int i = 0; i < 2; i++) {
            int row = srow0 + i*16;
            GLOAD16(A  + (size_t)(m0 + row)*lda + k0 + ssl*8, &As[(wv*128 + i*64)*8]);
            GLOAD16(Bt + (size_t)(n0 + row)*K   + k0 + ssl*8, &Bs[(wv*128 + i*64)*8]);
        }
        __syncthreads();

        bf16x8 af[4], bf[4];
        #pragma unroll
        for (int mi = 0; mi < 4; mi++) {
            int row = wm*64 + mi*16 + (lane & 15);
            af[mi] = *(const bf16x8*)&As[row*32 + (lane >> 4)*8];
        }
        #pragma unroll
        for (int ni = 0; ni < 4; ni++) {
            int col = wn*64 + ni*16 + (lane & 15);
            bf[ni] = *(const bf16x8*)&Bs[col*32 + (lane >> 4)*8];
        }
        #pragma unroll
        for (int ni = 0; ni < 4; ni++)
            #pragma unroll
            for (int mi = 0; mi < 4; mi++)
                acc[mi][ni] = __builtin_amdgcn_mfma_f32_16x16x32_bf16(af[mi], bf[ni], acc[mi][ni], 0,0,0);
        __syncthreads();
    }

    const int rb = (lane >> 4) << 2;
    const int cb = lane & 15;
    #pragma unroll
    for (int mi = 0; mi < 4; mi++) {
      #pragma unroll
      for (int ni = 0; ni < 4; ni++) {
        #pragma unroll
        for (int j = 0; j < 4; j++) {
            int row = m0 + wm*64 + mi*16 + rb + j;
            int col = n0 + wn*64 + ni*16 + cb;
            float v = acc[mi][ni][j];
            if (MODE == 0) {
                if (col < Nreal) OutF[(size_t)row*ldc + col] = v + bias[col];
            } else if (MODE == 1) {
                v += bias[col];
                v = v > 0.f ? v : 0.f;
                Out[(size_t)row*ldc + col] = f2b(v);
            } else {
                int nsel = col / 768;
                int c = col - nsel*768;
                int h = c >> 6, d = c & 63;
                int b = row >> 10, t = row & (T_-1);
                short* dst = Out + (size_t)nsel*((size_t)NTOK*E_);
                dst[(((size_t)(b*H_ + h)*T_ + t) << 6) + d] = f2b(v);
            }
        }
      }
    }
}

// ---------------- split-K GEMM, accumulate into fp32 X via atomicAdd ----------------
// grid.x = nPanels*SPLITS; panel p: m0=(p&15)*128, n0=(p>>4)*128. bias added by slice 0.
template<int SPLITS>
__global__ __launch_bounds__(256) void gemm3_sk(
    const short* __restrict__ A, const short* __restrict__ Bt,
    const float* __restrict__ bias, float* __restrict__ X,
    int K, int lda)
{
    __shared__ __align__(16) short As[128*32];
    __shared__ __align__(16) short Bs[128*32];

    const int tid  = threadIdx.x;
    const int lane = tid & 63, wv = tid >> 6;
    const int wm = wv & 1, wn = wv >> 1;

    const int panel = blockIdx.x / SPLITS;
    const int sp    = blockIdx.x % SPLITS;
    const int m0 = (panel & 15) * 128;
    const int n0 = (panel >> 4) * 128;
    const int Ks = K / SPLITS;
    const int kbeg = sp * Ks;

    f32x4 acc[4][4];
    #pragma unroll
    for (int i = 0; i < 4; i++)
        #pragma unroll
        for (int j = 0; j < 4; j++) acc[i][j] = (f32x4){0.f,0.f,0.f,0.f};

    const int srow0 = wv*32 + (lane >> 2);
    const int ssl   = lane & 3;

    for (int k0 = kbeg; k0 < kbeg + Ks; k0 += 32) {
        #pragma unroll
        for (int i = 0; i < 2; i++) {
            int row = srow0 + i*16;
            GLOAD16(A  + (size_t)(m0 + row)*lda + k0 + ssl*8, &As[(wv*128 + i*64)*8]);
            GLOAD16(Bt + (size_t)(n0 + row)*K   + k0 + ssl*8, &Bs[(wv*128 + i*64)*8]);
        }
        __syncthreads();

        bf16x8 af[4], bf[4];
        #pragma unroll
        for (int mi = 0; mi < 4; mi++) {
            int row = wm*64 + mi*16 + (lane & 15);
            af[mi] = *(const bf16x8*)&As[row*32 + (lane >> 4)*8];
        }
        #pragma unroll
        for (int ni = 0; ni < 4; ni++) {
            int col = wn*64 + ni*16 + (lane & 15);
            bf[ni] = *(const bf16x8*)&Bs[col*32 + (lane >> 4)*8];
        }
        #pragma unroll
        for (int ni = 0; ni < 4; ni++)
            #pragma unroll
            for (int mi = 0; mi < 4; mi++)
                acc[mi][ni] = __builtin_amdgcn_mfma_f32_16x16x32_bf16(af[mi], bf[ni], acc[mi][ni], 0,0,0);
        __syncthreads();
    }

    const int rb = (lane >> 4) << 2;
    const int cb = lane & 15;
    #pragma unroll
    for (int mi = 0; mi < 4; mi++) {
      #pragma unroll
      for (int ni = 0; ni < 4; ni++) {
        #pragma unroll
        for (int j = 0; j < 4; j++) {
            int row = m0 + wm*64 + mi*16 + rb + j;
            int col = n0 + wn*64 + ni*16 + cb;
            float v = acc[mi][ni][j];
            if (sp == 0) v += bias[col];
            atomicAdd(&X[(size_t)row*E_ + col], v);
        }
      }
    }
}

// ---------------- flash attention (faithful swap: "Q"=k-proj, "K"=q-proj) ----------------
__global__ __launch_bounds__(256) void attn2(
    const short* __restrict__ qg, const short* __restrict__ kg,
    const short* __restrict__ vg, short* __restrict__ ao)
{
    __shared__ __align__(16) short Kt[64*64];
    __shared__ __align__(16) short Qs[64*64];
    __shared__ __align__(16) short Vs[64*64];
    __shared__ __align__(16) short Ps[4][16*64];

    const int tid = threadIdx.x, lane = tid & 63, w = tid >> 6, g = lane >> 4;
    const int t0 = blockIdx.x * 64;
    const int bh = blockIdx.y;
    const size_t base = (size_t)bh * T_ * 64;

    #pragma unroll
    for (int is = 0; is < 2; is++) {
        int idx = is*256 + tid;
        int row = idx >> 3, sl = idx & 7;
        short8 v = *(const short8*)(kg + base + (size_t)(t0+row)*64 + sl*8);
        *(short8*)&Kt[row*64 + (sl ^ (row&7))*8] = v;
    }
    __syncthreads();

    bf16x8 akt[2];
    {
        int lt = w*16 + (lane & 15);
        #pragma unroll
        for (int c = 0; c < 2; c++)
            akt[c] = *(const bf16x8*)&Kt[lt*64 + ((c*4+g) ^ (lt&7))*8];
    }

    f32x4 o[4]; float m_run[4], l_run[4];
    #pragma unroll
    for (int i = 0; i < 4; i++) { o[i] = (f32x4){0,0,0,0}; m_run[i] = -1e30f; l_run[i] = 0.f; }

    const int vd0 = (tid & 31) * 2;
    const int vsh = tid >> 5;

    const int ntiles = (t0 >> 6) + 1;
    for (int it = 0; it < ntiles; ++it) {
        const int s0 = it*64;
        __syncthreads();
        #pragma unroll
        for (int is = 0; is < 2; is++) {
            int idx = is*256 + tid;
            int row = idx >> 3, sl = idx & 7;
            short8 v = *(const short8*)(qg + base + (size_t)(s0+row)*64 + sl*8);
            *(short8*)&Qs[row*64 + (sl ^ (row&7))*8] = v;
        }
        {
            unsigned vv[8];
            #pragma unroll
            for (int i = 0; i < 8; i++)
                vv[i] = *(const unsigned*)(vg + base + (size_t)(s0 + vsh*8 + i)*64 + vd0);
            #pragma unroll
            for (int dp = 0; dp < 2; dp++) {
                int d = vd0 + dp;
                short tmp[8];
                #pragma unroll
                for (int i = 0; i < 8; i++) tmp[i] = (short)((vv[i] >> (dp*16)) & 0xffffu);
                *(short8*)&Vs[d*64 + (vsh ^ (d&7))*8] = *(short8*)tmp;
            }
        }
        __syncthreads();

        f32x4 s4[4];
        #pragma unroll
        for (int j = 0; j < 4; j++) s4[j] = (f32x4){0,0,0,0};
        #pragma unroll
        for (int c = 0; c < 2; c++) {
            #pragma unroll
            for (int j = 0; j < 4; j++) {
                int sr = j*16 + (lane & 15);
                bf16x8 bq = *(const bf16x8*)&Qs[sr*64 + ((c*4+g) ^ (sr&7))*8];
                s4[j] = __builtin_amdgcn_mfma_f32_16x16x32_bf16(akt[c], bq, s4[j], 0,0,0);
            }
        }
        float p[4][4];
        const bool diag = (it == ntiles-1);
        #pragma unroll
        for (int j = 0; j < 4; j++) {
          #pragma unroll
          for (int r = 0; r < 4; r++) {
            float v = s4[j][r] * SCALE_;
            if (diag) {
                int tglob = t0 + w*16 + g*4 + r;
                int sglob = s0 + j*16 + (lane & 15);
                if (sglob > tglob) v = -1e30f;
            }
            p[j][r] = v;
          }
        }
        #pragma unroll
        for (int r = 0; r < 4; r++) {
            float mx = fmaxf(fmaxf(p[0][r], p[1][r]), fmaxf(p[2][r], p[3][r]));
            #pragma unroll
            for (int off = 1; off < 16; off <<= 1) mx = fmaxf(mx, __shfl_xor(mx, off, 64));
            float mnew  = fmaxf(m_run[r], mx);
            float alpha = __expf(m_run[r] - mnew);
            float rs = 0.f;
            #pragma unroll
            for (int j = 0; j < 4; j++) { p[j][r] = __expf(p[j][r] - mnew); rs += p[j][r]; }
            #pragma unroll
            for (int off = 1; off < 16; off <<= 1) rs += __shfl_xor(rs, off, 64);
            l_run[r] = l_run[r]*alpha + rs;
            m_run[r] = mnew;
            #pragma unroll
            for (int ni = 0; ni < 4; ni++) o[ni][r] *= alpha;
        }
        #pragma unroll
        for (int j = 0; j < 4; j++) {
          #pragma unroll
          for (int r = 0; r < 4; r++) {
            int tl = g*4 + r, sc = j*16 + (lane & 15);
            Ps[w][tl*64 + ((sc>>3) ^ (tl&7))*8 + (sc&7)] = f2b(p[j][r]);
          }
        }
        asm volatile("s_waitcnt lgkmcnt(0)" ::: "memory");
        __builtin_amdgcn_sched_barrier(0);
        #pragma unroll
        for (int c = 0; c < 2; c++) {
            int tl = lane & 15;
            bf16x8 pa = *(const bf16x8*)&Ps[w][tl*64 + ((c*4+g) ^ (tl&7))*8];
            #pragma unroll
            for (int ni = 0; ni < 4; ni++) {
                int d = ni*16 + (lane & 15);
                bf16x8 bv = *(const bf16x8*)&Vs[d*64 + ((c*4+g) ^ (d&7))*8];
                o[ni] = __builtin_amdgcn_mfma_f32_16x16x32_bf16(pa, bv, o[ni], 0,0,0);
            }
        }
    }

    const int b = bh / H_, h = bh - b*H_;
    #pragma unroll
    for (int ni = 0; ni < 4; ni++) {
      #pragma unroll
      for (int r = 0; r < 4; r++) {
        int t = t0 + w*16 + g*4 + r;
        int d = ni*16 + (lane & 15);
        ao[((size_t)(b*T_ + t))*E_ + h*64 + d] = f2b(o[ni][r] / l_run[r]);
      }
    }
}

// ---------------- fallback GEMM (fp32 B on the fly) ----------------
template<int MODE, bool QKV3>
__global__ __launch_bounds__(256) void gemm2(
    const short* __restrict__ A,
    const float* __restrict__ Bq, const float* __restrict__ Bk2, const float* __restrict__ Bv2,
    const float* __restrict__ bias,
    float* __restrict__ X, short* __restrict__ Out, float* __restrict__ OutF,
    int M, int Ntot, int K, int lda, int kstride, int ldc)
{
    __shared__ __align__(16) short As[128*32];
    __shared__ __align__(16) short Bs[128*32];

    const int tid  = threadIdx.x;
    const int lane = tid & 63, wave = tid >> 6;
    const int wm = wave & 1, wn = wave >> 1;
    const int m0 = blockIdx.x * 128;
    const int n0 = blockIdx.y * 128;
    const int g  = lane >> 4;

    const float* Bm = Bq;
    int nsel = 0, c0 = n0;
    if (QKV3) {
        nsel = n0 / 768;
        c0 = n0 - nsel*768;
        Bm = (nsel == 0) ? Bq : (nsel == 1 ? Bk2 : Bv2);
    }

    f32x4 acc[4][4];
    #pragma unroll
    for (int i = 0; i < 4; i++)
        #pragma unroll
        for (int j = 0; j < 4; j++) acc[i][j] = (f32x4){0.f,0.f,0.f,0.f};

    const int bn  = tid & 127;
    const int bkh = tid >> 7;
    const int cg  = c0 + bn;
    const bool bvalid = QKV3 ? true : (cg < Ntot);
    size_t bbase;
    if (QKV3) bbase = (size_t)(cg >> 6) * ((size_t)E_*D_) + (cg & 63);
    else      bbase = (size_t)cg;

    for (int k0 = 0; k0 < K; k0 += 32) {
        #pragma unroll
        for (int is = 0; is < 2; is++) {
            int idx = is*256 + tid;
            int row = idx >> 2, sl = idx & 3;
            short8 v = *(const short8*)(A + (size_t)(m0+row)*lda + k0 + sl*8);
            int sl2 = sl ^ ((row ^ (row>>2)) & 3);
            *(short8*)&As[row*32 + sl2*8] = v;
        }
        {
            float bv[16];
            #pragma unroll
            for (int i = 0; i < 16; i++) {
                int k = k0 + bkh*16 + i;
                bv[i] = bvalid ? Bm[bbase + (size_t)k*kstride] : 0.f;
            }
            short bh16[16];
            #pragma unroll
            for (int i = 0; i < 16; i++) {
                __bf16 h = (__bf16)bv[i];
                bh16[i] = __builtin_bit_cast(short, h);
            }
            #pragma unroll
            for (int q = 0; q < 2; q++) {
                int kb  = bkh*2 + q;
                int sl2 = kb ^ ((bn ^ (bn>>2)) & 3);
                *(short8*)&Bs[bn*32 + sl2*8] = *(short8*)&bh16[q*8];
            }
        }
        __syncthreads();

        bf16x8 af[4];
        #pragma unroll
        for (int mi = 0; mi < 4; mi++) {
            int row = wm*64 + mi*16 + (lane & 15);
            int sl2 = g ^ ((row ^ (row>>2)) & 3);
            af[mi] = *(const bf16x8*)&As[row*32 + sl2*8];
        }
        #pragma unroll
        for (int ni = 0; ni < 4; ni++) {
            int nn  = wn*64 + ni*16 + (lane & 15);
            int sl2 = g ^ ((nn ^ (nn>>2)) & 3);
            bf16x8 bfr = *(const bf16x8*)&Bs[nn*32 + sl2*8];
            #pragma unroll
            for (int mi = 0; mi < 4; mi++)
                acc[mi][ni] = __builtin_amdgcn_mfma_f32_16x16x32_bf16(af[mi], bfr, acc[mi][ni], 0,0,0);
        }
        __syncthreads();
    }

    const int rb = g << 2;
    const int cb = lane & 15;
    #pragma unroll
    for (int mi = 0; mi < 4; mi++) {
      #pragma unroll
      for (int ni = 0; ni < 4; ni++) {
        #pragma unroll
        for (int j = 0; j < 4; j++) {
            int row = m0 + wm*64 + mi*16 + rb + j;
            int col = n0 + wn*64 + ni*16 + cb;
            float v = acc[mi][ni][j];
            if (MODE == 0) {
                if (col < Ntot) OutF[(size_t)row*ldc + col] = v + bias[col];
            } else if (MODE == 1) {
                v += bias[col];
                v = v > 0.f ? v : 0.f;
                Out[(size_t)row*ldc + col] = f2b(v);
            } else if (MODE == 2) {
                X[(size_t)row*E_ + col] += v + bias[col];
            } else {
                int c = col - nsel*768;
                int h = c >> 6, d = c & 63;
                int b = row >> 10, t = row & (T_-1);
                short* dst = Out + (size_t)nsel*((size_t)NTOK*E_);
                dst[(((size_t)(b*H_ + h)*T_ + t) << 6) + d] = f2b(v);
            }
        }
      }
    }
}

// ---------------- host launch ----------------
extern "C" void kernel_launch(void* const* d_in, const int* in_sizes, int n_in,
                              void* d_out, int out_size, void* d_ws, size_t ws_size,
                              hipStream_t stream)
{
    (void)in_sizes; (void)n_in; (void)out_size;

    const int*   idx     = (const int*)  d_in[0];
    const float* tok_emb = (const float*)d_in[1];
    const float* pos_emb = (const float*)d_in[2];
    const float* Wk      = (const float*)d_in[3];
    const float* Wq      = (const float*)d_in[4];
    const float* Wv      = (const float*)d_in[5];
    const float* Wproj   = (const float*)d_in[6];
    const float* bproj   = (const float*)d_in[7];
    const float* ln1_g   = (const float*)d_in[8];
    const float* ln1_b   = (const float*)d_in[9];
    const float* W1      = (const float*)d_in[10];
    const float* b1      = (const float*)d_in[11];
    const float* W2      = (const float*)d_in[12];
    const float* b2      = (const float*)d_in[13];
    const float* ln2_g   = (const float*)d_in[14];
    const float* ln2_b   = (const float*)d_in[15];
    const float* lnf_g   = (const float*)d_in[16];
    const float* lnf_b   = (const float*)d_in[17];
    const float* Wlm     = (const float*)d_in[18];
    const float* blm     = (const float*)d_in[19];
    float* out = (float*)d_out;

    char* w = (char*)d_ws;
    float* x    = (float*)w; w += (size_t)NTOK*E_*4;
    short* hbuf = (short*)w; w += (size_t)NTOK*E_*2;
    short* qb   = (short*)w; w += (size_t)NTOK*E_*2;
    short* kb   = (short*)w; w += (size_t)NTOK*E_*2;
    short* vb   = (short*)w; w += (size_t)NTOK*E_*2;
    short* aob  = (short*)w; w += (size_t)NTOK*E_*2;
    short* midb = (short*)w; w += (size_t)NTOK*FF_*2;

    const size_t act_bytes = (size_t)(w - (char*)d_ws);
    const size_t wqkv_n = (size_t)L_*2304*E_;
    const size_t wproj_n = (size_t)L_*E_*E_;
    const size_t wff_n = (size_t)L_*E_*FF_;
    const size_t wlm_n = (size_t)VPAD_*E_;
    const size_t need = act_bytes + 2*(wqkv_n + wproj_n + 2*wff_n + wlm_n);

    const size_t HED = (size_t)H_*E_*D_;
    dim3 gAT(T_/64, B_*H_);

    embed_kernel<<<NTOK, 256, 0, stream>>>(idx, tok_emb, pos_emb, x);

    if (ws_size >= need) {
        // ---------- fast path: prepack weights to bf16 (B^T layout) ----------
        short* qkvw = (short*)w; w += wqkv_n*2;
        short* projw= (short*)w; w += wproj_n*2;
        short* w1w  = (short*)w; w += wff_n*2;
        short* w2w  = (short*)w; w += wff_n*2;
        short* lmw  = (short*)w;

        pack_qkv<<<dim3(E_/64, 36, L_), 256, 0, stream>>>(Wq, Wk, Wv, qkvw);
        pack_t<<<dim3(E_/64, E_/64, L_), 256, 0, stream>>>(Wproj, projw, E_, E_, (size_t)E_*E_, (size_t)E_*E_);
        pack_t<<<dim3(E_/64, FF_/64, L_), 256, 0, stream>>>(W1, w1w, E_, FF_, (size_t)E_*FF_, (size_t)E_*FF_);
        pack_t<<<dim3(FF_/64, E_/64, L_), 256, 0, stream>>>(W2, w2w, FF_, E_, (size_t)E_*FF_, (size_t)E_*FF_);
        pack_t<<<dim3(E_/64, VPAD_/64, 1), 256, 0, stream>>>(Wlm, lmw, E_, V_, 0, 0);

        const int nQKV = 16*(2304/128), nF1 = 16*(FF_/128), nLM = 16*(VPAD_/128);
        const int nP = 16*(E_/128);    // 96 panels for N=768

        for (int l = 0; l < L_; l++) {
            ln_kernel<<<NTOK, 256, 0, stream>>>(x, ln1_g + (size_t)l*E_, ln1_b + (size_t)l*E_, hbuf);
            gemm3<3><<<nQKV, 256, 0, stream>>>(hbuf, qkvw + (size_t)l*2304*E_, nullptr,
                                               nullptr, qb, nullptr, E_, E_, 0, 2304, nQKV/8);
            attn2<<<gAT, 256, 0, stream>>>(qb, kb, vb, aob);
            gemm3_sk<2><<<nP*2, 256, 0, stream>>>(aob, projw + (size_t)l*E_*E_,
                                                  bproj + (size_t)l*E_, x, E_, E_);
            ln_kernel<<<NTOK, 256, 0, stream>>>(x, ln2_g + (size_t)l*E_, ln2_b + (size_t)l*E_, hbuf);
            gemm3<1><<<nF1, 256, 0, stream>>>(hbuf, w1w + (size_t)l*E_*FF_, b1 + (size_t)l*FF_,
                                              nullptr, midb, nullptr, E_, E_, FF_, FF_, nF1/8);
            gemm3_sk<4><<<nP*4, 256, 0, stream>>>(midb, w2w + (size_t)l*E_*FF_,
                                                  b2 + (size_t)l*E_, x, FF_, FF_);
        }
        ln_kernel<<<NTOK, 256, 0, stream>>>(x, lnf_g, lnf_b, hbuf);
        gemm3<0><<<nLM, 256, 0, stream>>>(hbuf, lmw, blm, nullptr, nullptr, out,
                                          E_, E_, V_, V_, nLM/8);
    } else {
        // ---------- fallback: round-3 path ----------
        dim3 gQKV(16, 18), gP(16, 6), gF1(16, 24), gLM(16, 393);
        for (int l = 0; l < L_; l++) {
            ln_kernel<<<NTOK, 256, 0, stream>>>(x, ln1_g + (size_t)l*E_, ln1_b + (size_t)l*E_, hbuf);
            gemm2<3,true><<<gQKV, 256, 0, stream>>>(hbuf,
                Wq + (size_t)l*HED, Wk + (size_t)l*HED, Wv + (size_t)l*HED,
                nullptr, nullptr, qb, nullptr, NTOK, 2304, E_, E_, 64, 0);
            attn2<<<gAT, 256, 0, stream>>>(qb, kb, vb, aob);
            gemm2<2,false><<<gP, 256, 0, stream>>>(aob,
                Wproj + (size_t)l*E_*E_, nullptr, nullptr, bproj + (size_t)l*E_,
                x, nullptr, nullptr, NTOK, E_, E_, E_, E_, 0);
            ln_kernel<<<NTOK, 256, 0, stream>>>(x, ln2_g + (size_t)l*E_, ln2_b + (size_t)l*E_, hbuf);
            gemm2<1,false><<<gF1, 256, 0, stream>>>(hbuf,
                W1 + (size_t)l*E_*FF_, nullptr, nullptr, b1 + (size_t)l*FF_,
                nullptr, midb, nullptr, NTOK, FF_, E_, E_, FF_, FF_);
            gemm2<2,false><<<gP, 256, 0, stream>>>(midb,
                W2 + (size_t)l*FF_*E_, nullptr, nullptr, b2 + (size_t)l*E_,
                x, nullptr, nullptr, NTOK, E_, FF_, FF_, E_, 0);
        }
        ln_kernel<<<NTOK, 256, 0, stream>>>(x, lnf_g, lnf_b, hbuf);
        gemm2<0,false><<<gLM, 256, 0, stream>>>(hbuf,
            Wlm, nullptr, nullptr, blm,
            nullptr, nullptr, out, NTOK, V_, E_, E_, V_, V_);
    }
}

// Round 6
// 2718.382 us; speedup vs baseline: 6.7120x; 1.0323x over previous
//
#include <hip/hip_runtime.h>
#include <hip/hip_bf16.h>
#include <stdint.h>

#define B_    2
#define T_    1024
#define V_    50257
#define VPAD_ 50304
#define E_    768
#define H_    12
#define L_    12
#define D_    64
#define FF_   3072
#define NTOK  (B_*T_)          // 2048
#define SCALE_ (1.0f/((float)E_*(float)E_))

typedef float f32x4 __attribute__((ext_vector_type(4)));
typedef __bf16 bf16x8 __attribute__((ext_vector_type(8)));
typedef short short8 __attribute__((ext_vector_type(8)));

__device__ __forceinline__ float bits2f(short s) {
    unsigned u = ((unsigned)(unsigned short)s) << 16;
    float f; __builtin_memcpy(&f, &u, 4); return f;
}
__device__ __forceinline__ short f2b(float f) {
    unsigned u; __builtin_memcpy(&u, &f, 4);
    unsigned r = (u + 0x7FFFu + ((u >> 16) & 1u)) >> 16;   // RNE
    return (short)r;
}

#define GLOAD16(gsrc, ldst) __builtin_amdgcn_global_load_lds( \
    (const __attribute__((address_space(1))) unsigned*)(gsrc), \
    (__attribute__((address_space(3))) unsigned*)(ldst), 16, 0, 0)

// ---------------- embedding ----------------
__global__ __launch_bounds__(256) void embed_kernel(
    const int* __restrict__ idx, const float* __restrict__ tok,
    const float* __restrict__ pos, float* __restrict__ x)
{
    int m = blockIdx.x, tid = threadIdx.x;
    int row = idx[m];
    int t = m & (T_-1);
    #pragma unroll
    for (int i = 0; i < 3; i++) {
        int e = tid + i*256;
        x[(size_t)m*E_ + e] = tok[(size_t)row*E_ + e] + pos[(size_t)t*E_ + e];
    }
}

// ---------------- layernorm (f32 in, bf16 out) ----------------
__device__ __forceinline__ float block_sum256(float v, float* red) {
    #pragma unroll
    for (int off = 32; off; off >>= 1) v += __shfl_xor(v, off, 64);
    int w = threadIdx.x >> 6;
    __syncthreads();
    if ((threadIdx.x & 63) == 0) red[w] = v;
    __syncthreads();
    return red[0] + red[1] + red[2] + red[3];
}

__global__ __launch_bounds__(256) void ln_kernel(
    const float* __restrict__ x, const float* __restrict__ g,
    const float* __restrict__ bb, short* __restrict__ out)
{
    __shared__ float red[4];
    int m = blockIdx.x, tid = threadIdx.x;
    const float* xr = x + (size_t)m*E_;
    float loc[3]; float s = 0.f;
    #pragma unroll
    for (int i = 0; i < 3; i++) { loc[i] = xr[tid + i*256]; s += loc[i]; }
    s = block_sum256(s, red);
    float mean = s * (1.0f/E_);
    float vs = 0.f;
    #pragma unroll
    for (int i = 0; i < 3; i++) { float d = loc[i] - mean; vs += d*d; }
    vs = block_sum256(vs, red);
    float rstd = rsqrtf(vs * (1.0f/E_) + 1e-5f);
    #pragma unroll
    for (int i = 0; i < 3; i++) {
        int e = tid + i*256;
        out[(size_t)m*E_ + e] = f2b((loc[i] - mean) * rstd * g[e] + bb[e]);
    }
}

// ---------------- weight packing ----------------
__global__ __launch_bounds__(256) void pack_t(
    const float* __restrict__ src, short* __restrict__ dst,
    int srcK, int srcN, size_t sstride, size_t dstride)
{
    __shared__ float tile[64][65];
    int k0 = blockIdx.x*64, n0 = blockIdx.y*64, l = blockIdx.z;
    const float* s = src + (size_t)l*sstride;
    short* d = dst + (size_t)l*dstride;
    int tid = threadIdx.x;
    #pragma unroll
    for (int i = 0; i < 16; i++) {
        int idx = i*256 + tid;
        int r = idx >> 6, c = idx & 63;
        float v = (n0 + c < srcN) ? s[(size_t)(k0+r)*srcN + n0 + c] : 0.f;
        tile[r][c] = v;
    }
    __syncthreads();
    #pragma unroll
    for (int i = 0; i < 16; i++) {
        int idx = i*256 + tid;
        int r2 = idx >> 6, c2 = idx & 63;
        d[(size_t)(n0+r2)*srcK + k0 + c2] = f2b(tile[c2][r2]);
    }
}

__global__ __launch_bounds__(256) void pack_qkv(
    const float* __restrict__ Wq, const float* __restrict__ Wk,
    const float* __restrict__ Wv, short* __restrict__ dst)
{
    __shared__ float tile[64][65];
    int e0 = blockIdx.x*64;
    int y = blockIdx.y, sel = y/12, h = y - sel*12;
    int l = blockIdx.z;
    const float* s = (sel == 0 ? Wq : (sel == 1 ? Wk : Wv)) + (((size_t)l*H_ + h)*E_)*D_;
    int tid = threadIdx.x;
    #pragma unroll
    for (int i = 0; i < 16; i++) {
        int idx = i*256 + tid;
        int r = idx >> 6, c = idx & 63;
        tile[r][c] = s[(size_t)(e0+r)*D_ + c];
    }
    __syncthreads();
    short* d_ = dst + (size_t)l*2304*E_;
    #pragma unroll
    for (int i = 0; i < 16; i++) {
        int idx = i*256 + tid;
        int r2 = idx >> 6, c2 = idx & 63;
        d_[(size_t)(sel*768 + h*64 + r2)*E_ + e0 + c2] = f2b(tile[c2][r2]);
    }
}

// ---------------- fast bf16 GEMM: 2-phase double-buffered (T3-minimum) ----------------
// MODE 0: OutF = acc + bias (col < Nreal);  MODE 1: relu->bf16;  MODE 3: qkv scatter
template<int MODE>
__global__ __launch_bounds__(256) void gemm3(
    const short* __restrict__ A, const short* __restrict__ Bt,
    const float* __restrict__ bias,
    float* __restrict__ X, short* __restrict__ Out, float* __restrict__ OutF,
    int K, int lda, int ldc, int Nreal, int cpx)
{
    __shared__ __align__(16) short As[2][128*32];
    __shared__ __align__(16) short Bs[2][128*32];

    const int tid  = threadIdx.x;
    const int lane = tid & 63, wv = tid >> 6;
    const int wm = wv & 1, wn = wv >> 1;

    int bid = blockIdx.x;
    int g   = (bid & 7)*cpx + (bid >> 3);
    const int m0 = (g & 15) * 128;
    const int n0 = (g >> 4) * 128;

    f32x4 acc[4][4];
    #pragma unroll
    for (int i = 0; i < 4; i++)
        #pragma unroll
        for (int j = 0; j < 4; j++) acc[i][j] = (f32x4){0.f,0.f,0.f,0.f};

    const int srow0 = wv*32 + (lane >> 2);
    const int ssl   = lane & 3;

#define STAGE3(buf, kk) do {                                                  \
    _Pragma("unroll")                                                         \
    for (int i_ = 0; i_ < 2; i_++) {                                          \
        int row_ = srow0 + i_*16;                                             \
        GLOAD16(A  + (size_t)(m0 + row_)*lda + (kk) + ssl*8,                  \
                &As[buf][(wv*128 + i_*64)*8]);                                \
        GLOAD16(Bt + (size_t)(n0 + row_)*K   + (kk) + ssl*8,                  \
                &Bs[buf][(wv*128 + i_*64)*8]);                                \
    } } while(0)

    const int nt = K >> 5;
    STAGE3(0, 0);
    __syncthreads();

    for (int kt = 0; kt < nt; ++kt) {
        const int cur = kt & 1;
        if (kt + 1 < nt) STAGE3(cur ^ 1, (kt + 1) << 5);

        bf16x8 af[4], bf[4];
        #pragma unroll
        for (int mi = 0; mi < 4; mi++) {
            int row = wm*64 + mi*16 + (lane & 15);
            af[mi] = *(const bf16x8*)&As[cur][row*32 + (lane >> 4)*8];
        }
        #pragma unroll
        for (int ni = 0; ni < 4; ni++) {
            int col = wn*64 + ni*16 + (lane & 15);
            bf[ni] = *(const bf16x8*)&Bs[cur][col*32 + (lane >> 4)*8];
        }
        #pragma unroll
        for (int ni = 0; ni < 4; ni++)
            #pragma unroll
            for (int mi = 0; mi < 4; mi++)
                acc[mi][ni] = __builtin_amdgcn_mfma_f32_16x16x32_bf16(af[mi], bf[ni], acc[mi][ni], 0,0,0);
        __syncthreads();   // drains stage(nxt) + everyone done reading cur
    }
#undef STAGE3

    const int rb = (lane >> 4) << 2;
    const int cb = lane & 15;
    #pragma unroll
    for (int mi = 0; mi < 4; mi++) {
      #pragma unroll
      for (int ni = 0; ni < 4; ni++) {
        #pragma unroll
        for (int j = 0; j < 4; j++) {
            int row = m0 + wm*64 + mi*16 + rb + j;
            int col = n0 + wn*64 + ni*16 + cb;
            float v = acc[mi][ni][j];
            if (MODE == 0) {
                if (col < Nreal) OutF[(size_t)row*ldc + col] = v + bias[col];
            } else if (MODE == 1) {
                v += bias[col];
                v = v > 0.f ? v : 0.f;
                Out[(size_t)row*ldc + col] = f2b(v);
            } else {
                int nsel = col / 768;
                int c = col - nsel*768;
                int h = c >> 6, d = c & 63;
                int b = row >> 10, t = row & (T_-1);
                short* dst = Out + (size_t)nsel*((size_t)NTOK*E_);
                dst[(((size_t)(b*H_ + h)*T_ + t) << 6) + d] = f2b(v);
            }
        }
      }
    }
}

// ---------------- split-K GEMM (2-phase dbuf), accumulate into fp32 X ----------------
template<int SPLITS>
__global__ __launch_bounds__(256) void gemm3_sk(
    const short* __restrict__ A, const short* __restrict__ Bt,
    const float* __restrict__ bias, float* __restrict__ X,
    int K, int lda)
{
    __shared__ __align__(16) short As[2][128*32];
    __shared__ __align__(16) short Bs[2][128*32];

    const int tid  = threadIdx.x;
    const int lane = tid & 63, wv = tid >> 6;
    const int wm = wv & 1, wn = wv >> 1;

    const int panel = blockIdx.x / SPLITS;
    const int sp    = blockIdx.x % SPLITS;
    const int m0 = (panel & 15) * 128;
    const int n0 = (panel >> 4) * 128;
    const int Ks = K / SPLITS;
    const int kbeg = sp * Ks;

    f32x4 acc[4][4];
    #pragma unroll
    for (int i = 0; i < 4; i++)
        #pragma unroll
        for (int j = 0; j < 4; j++) acc[i][j] = (f32x4){0.f,0.f,0.f,0.f};

    const int srow0 = wv*32 + (lane >> 2);
    const int ssl   = lane & 3;

#define STAGESK(buf, kk) do {                                                 \
    _Pragma("unroll")                                                         \
    for (int i_ = 0; i_ < 2; i_++) {                                          \
        int row_ = srow0 + i_*16;                                             \
        GLOAD16(A  + (size_t)(m0 + row_)*lda + (kk) + ssl*8,                  \
                &As[buf][(wv*128 + i_*64)*8]);                                \
        GLOAD16(Bt + (size_t)(n0 + row_)*K   + (kk) + ssl*8,                  \
                &Bs[buf][(wv*128 + i_*64)*8]);                                \
    } } while(0)

    const int nt = Ks >> 5;
    STAGESK(0, kbeg);
    __syncthreads();

    for (int kt = 0; kt < nt; ++kt) {
        const int cur = kt & 1;
        if (kt + 1 < nt) STAGESK(cur ^ 1, kbeg + ((kt + 1) << 5));

        bf16x8 af[4], bf[4];
        #pragma unroll
        for (int mi = 0; mi < 4; mi++) {
            int row = wm*64 + mi*16 + (lane & 15);
            af[mi] = *(const bf16x8*)&As[cur][row*32 + (lane >> 4)*8];
        }
        #pragma unroll
        for (int ni = 0; ni < 4; ni++) {
            int col = wn*64 + ni*16 + (lane & 15);
            bf[ni] = *(const bf16x8*)&Bs[cur][col*32 + (lane >> 4)*8];
        }
        #pragma unroll
        for (int ni = 0; ni < 4; ni++)
            #pragma unroll
            for (int mi = 0; mi < 4; mi++)
                acc[mi][ni] = __builtin_amdgcn_mfma_f32_16x16x32_bf16(af[mi], bf[ni], acc[mi][ni], 0,0,0);
        __syncthreads();
    }
#undef STAGESK

    const int rb = (lane >> 4) << 2;
    const int cb = lane & 15;
    #pragma unroll
    for (int mi = 0; mi < 4; mi++) {
      #pragma unroll
      for (int ni = 0; ni < 4; ni++) {
        #pragma unroll
        for (int j = 0; j < 4; j++) {
            int row = m0 + wm*64 + mi*16 + rb + j;
            int col = n0 + wn*64 + ni*16 + cb;
            float v = acc[mi][ni][j];
            if (sp == 0) v += bias[col];
            atomicAdd(&X[(size_t)row*E_ + col], v);
        }
      }
    }
}

// ---------------- flash attention (faithful swap: "Q"=k-proj, "K"=q-proj) ----------------
__global__ __launch_bounds__(256) void attn2(
    const short* __restrict__ qg, const short* __restrict__ kg,
    const short* __restrict__ vg, short* __restrict__ ao)
{
    __shared__ __align__(16) short Kt[64*64];
    __shared__ __align__(16) short Qs[64*64];
    __shared__ __align__(16) short Vs[64*64];
    __shared__ __align__(16) short Ps[4][16*64];

    const int tid = threadIdx.x, lane = tid & 63, w = tid >> 6, g = lane >> 4;
    const int t0 = blockIdx.x * 64;
    const int bh = blockIdx.y;
    const size_t base = (size_t)bh * T_ * 64;

    #pragma unroll
    for (int is = 0; is < 2; is++) {
        int idx = is*256 + tid;
        int row = idx >> 3, sl = idx & 7;
        short8 v = *(const short8*)(kg + base + (size_t)(t0+row)*64 + sl*8);
        *(short8*)&Kt[row*64 + (sl ^ (row&7))*8] = v;
    }
    __syncthreads();

    bf16x8 akt[2];
    {
        int lt = w*16 + (lane & 15);
        #pragma unroll
        for (int c = 0; c < 2; c++)
            akt[c] = *(const bf16x8*)&Kt[lt*64 + ((c*4+g) ^ (lt&7))*8];
    }

    f32x4 o[4]; float m_run[4], l_run[4];
    #pragma unroll
    for (int i = 0; i < 4; i++) { o[i] = (f32x4){0,0,0,0}; m_run[i] = -1e30f; l_run[i] = 0.f; }

    const int vd0 = (tid & 31) * 2;
    const int vsh = tid >> 5;

    const int ntiles = (t0 >> 6) + 1;
    for (int it = 0; it < ntiles; ++it) {
        const int s0 = it*64;
        __syncthreads();
        #pragma unroll
        for (int is = 0; is < 2; is++) {
            int idx = is*256 + tid;
            int row = idx >> 3, sl = idx & 7;
            short8 v = *(const short8*)(qg + base + (size_t)(s0+row)*64 + sl*8);
            *(short8*)&Qs[row*64 + (sl ^ (row&7))*8] = v;
        }
        {
            unsigned vv[8];
            #pragma unroll
            for (int i = 0; i < 8; i++)
                vv[i] = *(const unsigned*)(vg + base + (size_t)(s0 + vsh*8 + i)*64 + vd0);
            #pragma unroll
            for (int dp = 0; dp < 2; dp++) {
                int d = vd0 + dp;
                short tmp[8];
                #pragma unroll
                for (int i = 0; i < 8; i++) tmp[i] = (short)((vv[i] >> (dp*16)) & 0xffffu);
                *(short8*)&Vs[d*64 + (vsh ^ (d&7))*8] = *(short8*)tmp;
            }
        }
        __syncthreads();

        f32x4 s4[4];
        #pragma unroll
        for (int j = 0; j < 4; j++) s4[j] = (f32x4){0,0,0,0};
        #pragma unroll
        for (int c = 0; c < 2; c++) {
            #pragma unroll
            for (int j = 0; j < 4; j++) {
                int sr = j*16 + (lane & 15);
                bf16x8 bq = *(const bf16x8*)&Qs[sr*64 + ((c*4+g) ^ (sr&7))*8];
                s4[j] = __builtin_amdgcn_mfma_f32_16x16x32_bf16(akt[c], bq, s4[j], 0,0,0);
            }
        }
        float p[4][4];
        const bool diag = (it == ntiles-1);
        #pragma unroll
        for (int j = 0; j < 4; j++) {
          #pragma unroll
          for (int r = 0; r < 4; r++) {
            float v = s4[j][r] * SCALE_;
            if (diag) {
                int tglob = t0 + w*16 + g*4 + r;
                int sglob = s0 + j*16 + (lane & 15);
                if (sglob > tglob) v = -1e30f;
            }
            p[j][r] = v;
          }
        }
        #pragma unroll
        for (int r = 0; r < 4; r++) {
            float mx = fmaxf(fmaxf(p[0][r], p[1][r]), fmaxf(p[2][r], p[3][r]));
            #pragma unroll
            for (int off = 1; off < 16; off <<= 1) mx = fmaxf(mx, __shfl_xor(mx, off, 64));
            float mnew  = fmaxf(m_run[r], mx);
            float alpha = __expf(m_run[r] - mnew);
            float rs = 0.f;
            #pragma unroll
            for (int j = 0; j < 4; j++) { p[j][r] = __expf(p[j][r] - mnew); rs += p[j][r]; }
            #pragma unroll
            for (int off = 1; off < 16; off <<= 1) rs += __shfl_xor(rs, off, 64);
            l_run[r] = l_run[r]*alpha + rs;
            m_run[r] = mnew;
            #pragma unroll
            for (int ni = 0; ni < 4; ni++) o[ni][r] *= alpha;
        }
        #pragma unroll
        for (int j = 0; j < 4; j++) {
          #pragma unroll
          for (int r = 0; r < 4; r++) {
            int tl = g*4 + r, sc = j*16 + (lane & 15);
            Ps[w][tl*64 + ((sc>>3) ^ (tl&7))*8 + (sc&7)] = f2b(p[j][r]);
          }
        }
        asm volatile("s_waitcnt lgkmcnt(0)" ::: "memory");
        __builtin_amdgcn_sched_barrier(0);
        #pragma unroll
        for (int c = 0; c < 2; c++) {
            int tl = lane & 15;
            bf16x8 pa = *(const bf16x8*)&Ps[w][tl*64 + ((c*4+g) ^ (tl&7))*8];
            #pragma unroll
            for (int ni = 0; ni < 4; ni++) {
                int d = ni*16 + (lane & 15);
                bf16x8 bv = *(const bf16x8*)&Vs[d*64 + ((c*4+g) ^ (d&7))*8];
                o[ni] = __builtin_amdgcn_mfma_f32_16x16x32_bf16(pa, bv, o[ni], 0,0,0);
            }
        }
    }

    const int b = bh / H_, h = bh - b*H_;
    #pragma unroll
    for (int ni = 0; ni < 4; ni++) {
      #pragma unroll
      for (int r = 0; r < 4; r++) {
        int t = t0 + w*16 + g*4 + r;
        int d = ni*16 + (lane & 15);
        ao[((size_t)(b*T_ + t))*E_ + h*64 + d] = f2b(o[ni][r] / l_run[r]);
      }
    }
}

// ---------------- fallback GEMM (fp32 B on the fly) ----------------
template<int MODE, bool QKV3>
__global__ __launch_bounds__(256) void gemm2(
    const short* __restrict__ A,
    const float* __restrict__ Bq, const float* __restrict__ Bk2, const float* __restrict__ Bv2,
    const float* __restrict__ bias,
    float* __restrict__ X, short* __restrict__ Out, float* __restrict__ OutF,
    int M, int Ntot, int K, int lda, int kstride, int ldc)
{
    __shared__ __align__(16) short As[128*32];
    __shared__ __align__(16) short Bs[128*32];

    const int tid  = threadIdx.x;
    const int lane = tid & 63, wave = tid >> 6;
    const int wm = wave & 1, wn = wave >> 1;
    const int m0 = blockIdx.x * 128;
    const int n0 = blockIdx.y * 128;
    const int g  = lane >> 4;

    const float* Bm = Bq;
    int nsel = 0, c0 = n0;
    if (QKV3) {
        nsel = n0 / 768;
        c0 = n0 - nsel*768;
        Bm = (nsel == 0) ? Bq : (nsel == 1 ? Bk2 : Bv2);
    }

    f32x4 acc[4][4];
    #pragma unroll
    for (int i = 0; i < 4; i++)
        #pragma unroll
        for (int j = 0; j < 4; j++) acc[i][j] = (f32x4){0.f,0.f,0.f,0.f};

    const int bn  = tid & 127;
    const int bkh = tid >> 7;
    const int cg  = c0 + bn;
    const bool bvalid = QKV3 ? true : (cg < Ntot);
    size_t bbase;
    if (QKV3) bbase = (size_t)(cg >> 6) * ((size_t)E_*D_) + (cg & 63);
    else      bbase = (size_t)cg;

    for (int k0 = 0; k0 < K; k0 += 32) {
        #pragma unroll
        for (int is = 0; is < 2; is++) {
            int idx = is*256 + tid;
            int row = idx >> 2, sl = idx & 3;
            short8 v = *(const short8*)(A + (size_t)(m0+row)*lda + k0 + sl*8);
            int sl2 = sl ^ ((row ^ (row>>2)) & 3);
            *(short8*)&As[row*32 + sl2*8] = v;
        }
        {
            float bv[16];
            #pragma unroll
            for (int i = 0; i < 16; i++) {
                int k = k0 + bkh*16 + i;
                bv[i] = bvalid ? Bm[bbase + (size_t)k*kstride] : 0.f;
            }
            short bh16[16];
            #pragma unroll
            for (int i = 0; i < 16; i++) {
                __bf16 h = (__bf16)bv[i];
                bh16[i] = __builtin_bit_cast(short, h);
            }
            #pragma unroll
            for (int q = 0; q < 2; q++) {
                int kb  = bkh*2 + q;
                int sl2 = kb ^ ((bn ^ (bn>>2)) & 3);
                *(short8*)&Bs[bn*32 + sl2*8] = *(short8*)&bh16[q*8];
            }
        }
        __syncthreads();

        bf16x8 af[4];
        #pragma unroll
        for (int mi = 0; mi < 4; mi++) {
            int row = wm*64 + mi*16 + (lane & 15);
            int sl2 = g ^ ((row ^ (row>>2)) & 3);
            af[mi] = *(const bf16x8*)&As[row*32 + sl2*8];
        }
        #pragma unroll
        for (int ni = 0; ni < 4; ni++) {
            int nn  = wn*64 + ni*16 + (lane & 15);
            int sl2 = g ^ ((nn ^ (nn>>2)) & 3);
            bf16x8 bfr = *(const bf16x8*)&Bs[nn*32 + sl2*8];
            #pragma unroll
            for (int mi = 0; mi < 4; mi++)
                acc[mi][ni] = __builtin_amdgcn_mfma_f32_16x16x32_bf16(af[mi], bfr, acc[mi][ni], 0,0,0);
        }
        __syncthreads();
    }

    const int rb = g << 2;
    const int cb = lane & 15;
    #pragma unroll
    for (int mi = 0; mi < 4; mi++) {
      #pragma unroll
      for (int ni = 0; ni < 4; ni++) {
        #pragma unroll
        for (int j = 0; j < 4; j++) {
            int row = m0 + wm*64 + mi*16 + rb + j;
            int col = n0 + wn*64 + ni*16 + cb;
            float v = acc[mi][ni][j];
            if (MODE == 0) {
                if (col < Ntot) OutF[(size_t)row*ldc + col] = v + bias[col];
            } else if (MODE == 1) {
                v += bias[col];
                v = v > 0.f ? v : 0.f;
                Out[(size_t)row*ldc + col] = f2b(v);
            } else if (MODE == 2) {
                X[(size_t)row*E_ + col] += v + bias[col];
            } else {
                int c = col - nsel*768;
                int h = c >> 6, d = c & 63;
                int b = row >> 10, t = row & (T_-1);
                short* dst = Out + (size_t)nsel*((size_t)NTOK*E_);
                dst[(((size_t)(b*H_ + h)*T_ + t) << 6) + d] = f2b(v);
            }
        }
      }
    }
}

// ---------------- host launch ----------------
extern "C" void kernel_launch(void* const* d_in, const int* in_sizes, int n_in,
                              void* d_out, int out_size, void* d_ws, size_t ws_size,
                              hipStream_t stream)
{
    (void)in_sizes; (void)n_in; (void)out_size;

    const int*   idx     = (const int*)  d_in[0];
    const float* tok_emb = (const float*)d_in[1];
    const float* pos_emb = (const float*)d_in[2];
    const float* Wk      = (const float*)d_in[3];
    const float* Wq      = (const float*)d_in[4];
    const float* Wv      = (const float*)d_in[5];
    const float* Wproj   = (const float*)d_in[6];
    const float* bproj   = (const float*)d_in[7];
    const float* ln1_g   = (const float*)d_in[8];
    const float* ln1_b   = (const float*)d_in[9];
    const float* W1      = (const float*)d_in[10];
    const float* b1      = (const float*)d_in[11];
    const float* W2      = (const float*)d_in[12];
    const float* b2      = (const float*)d_in[13];
    const float* ln2_g   = (const float*)d_in[14];
    const float* ln2_b   = (const float*)d_in[15];
    const float* lnf_g   = (const float*)d_in[16];
    const float* lnf_b   = (const float*)d_in[17];
    const float* Wlm     = (const float*)d_in[18];
    const float* blm     = (const float*)d_in[19];
    float* out = (float*)d_out;

    char* w = (char*)d_ws;
    float* x    = (float*)w; w += (size_t)NTOK*E_*4;
    short* hbuf = (short*)w; w += (size_t)NTOK*E_*2;
    short* qb   = (short*)w; w += (size_t)NTOK*E_*2;
    short* kb   = (short*)w; w += (size_t)NTOK*E_*2;
    short* vb   = (short*)w; w += (size_t)NTOK*E_*2;
    short* aob  = (short*)w; w += (size_t)NTOK*E_*2;
    short* midb = (short*)w; w += (size_t)NTOK*FF_*2;

    const size_t act_bytes = (size_t)(w - (char*)d_ws);
    const size_t wqkv_n = (size_t)L_*2304*E_;
    const size_t wproj_n = (size_t)L_*E_*E_;
    const size_t wff_n = (size_t)L_*E_*FF_;
    const size_t wlm_n = (size_t)VPAD_*E_;
    const size_t need = act_bytes + 2*(wqkv_n + wproj_n + 2*wff_n + wlm_n);

    const size_t HED = (size_t)H_*E_*D_;
    dim3 gAT(T_/64, B_*H_);

    embed_kernel<<<NTOK, 256, 0, stream>>>(idx, tok_emb, pos_emb, x);

    if (ws_size >= need) {
        // ---------- fast path: prepack weights to bf16 (B^T layout) ----------
        short* qkvw = (short*)w; w += wqkv_n*2;
        short* projw= (short*)w; w += wproj_n*2;
        short* w1w  = (short*)w; w += wff_n*2;
        short* w2w  = (short*)w; w += wff_n*2;
        short* lmw  = (short*)w;

        pack_qkv<<<dim3(E_/64, 36, L_), 256, 0, stream>>>(Wq, Wk, Wv, qkvw);
        pack_t<<<dim3(E_/64, E_/64, L_), 256, 0, stream>>>(Wproj, projw, E_, E_, (size_t)E_*E_, (size_t)E_*E_);
        pack_t<<<dim3(E_/64, FF_/64, L_), 256, 0, stream>>>(W1, w1w, E_, FF_, (size_t)E_*FF_, (size_t)E_*FF_);
        pack_t<<<dim3(FF_/64, E_/64, L_), 256, 0, stream>>>(W2, w2w, FF_, E_, (size_t)E_*FF_, (size_t)E_*FF_);
        pack_t<<<dim3(E_/64, VPAD_/64, 1), 256, 0, stream>>>(Wlm, lmw, E_, V_, 0, 0);

        const int nQKV = 16*(2304/128), nF1 = 16*(FF_/128), nLM = 16*(VPAD_/128);
        const int nP = 16*(E_/128);    // 96 panels for N=768

        for (int l = 0; l < L_; l++) {
            ln_kernel<<<NTOK, 256, 0, stream>>>(x, ln1_g + (size_t)l*E_, ln1_b + (size_t)l*E_, hbuf);
            gemm3<3><<<nQKV, 256, 0, stream>>>(hbuf, qkvw + (size_t)l*2304*E_, nullptr,
                                               nullptr, qb, nullptr, E_, E_, 0, 2304, nQKV/8);
            attn2<<<gAT, 256, 0, stream>>>(qb, kb, vb, aob);
            gemm3_sk<2><<<nP*2, 256, 0, stream>>>(aob, projw + (size_t)l*E_*E_,
                                                  bproj + (size_t)l*E_, x, E_, E_);
            ln_kernel<<<NTOK, 256, 0, stream>>>(x, ln2_g + (size_t)l*E_, ln2_b + (size_t)l*E_, hbuf);
            gemm3<1><<<nF1, 256, 0, stream>>>(hbuf, w1w + (size_t)l*E_*FF_, b1 + (size_t)l*FF_,
                                              nullptr, midb, nullptr, E_, E_, FF_, FF_, nF1/8);
            gemm3_sk<4><<<nP*4, 256, 0, stream>>>(midb, w2w + (size_t)l*E_*FF_,
                                                  b2 + (size_t)l*E_, x, FF_, FF_);
        }
        ln_kernel<<<NTOK, 256, 0, stream>>>(x, lnf_g, lnf_b, hbuf);
        gemm3<0><<<nLM, 256, 0, stream>>>(hbuf, lmw, blm, nullptr, nullptr, out,
                                          E_, E_, V_, V_, nLM/8);
    } else {
        // ---------- fallback: round-3 path ----------
        dim3 gQKV(16, 18), gP(16, 6), gF1(16, 24), gLM(16, 393);
        for (int l = 0; l < L_; l++) {
            ln_kernel<<<NTOK, 256, 0, stream>>>(x, ln1_g + (size_t)l*E_, ln1_b + (size_t)l*E_, hbuf);
            gemm2<3,true><<<gQKV, 256, 0, stream>>>(hbuf,
                Wq + (size_t)l*HED, Wk + (size_t)l*HED, Wv + (size_t)l*HED,
                nullptr, nullptr, qb, nullptr, NTOK, 2304, E_, E_, 64, 0);
            attn2<<<gAT, 256, 0, stream>>>(qb, kb, vb, aob);
            gemm2<2,false><<<gP, 256, 0, stream>>>(aob,
                Wproj + (size_t)l*E_*E_, nullptr, nullptr, bproj + (size_t)l*E_,
                x, nullptr, nullptr, NTOK, E_, E_, E_, E_, 0);
            ln_kernel<<<NTOK, 256, 0, stream>>>(x, ln2_g + (size_t)l*E_, ln2_b + (size_t)l*E_, hbuf);
            gemm2<1,false><<<gF1, 256, 0, stream>>>(hbuf,
                W1 + (size_t)l*E_*FF_, nullptr, nullptr, b1 + (size_t)l*FF_,
                nullptr, midb, nullptr, NTOK, FF_, E_, E_, FF_, FF_);
            gemm2<2,false><<<gP, 256, 0, stream>>>(midb,
                W2 + (size_t)l*FF_*E_, nullptr, nullptr, b2 + (size_t)l*E_,
                x, nullptr, nullptr, NTOK, E_, FF_, FF_, E_, 0);
        }
        ln_kernel<<<NTOK, 256, 0, stream>>>(x, lnf_g, lnf_b, hbuf);
        gemm2<0,false><<<gLM, 256, 0, stream>>>(hbuf,
            Wlm, nullptr, nullptr, blm,
            nullptr, nullptr, out, NTOK, V_, E_, E_, V_, V_);
    }
}

// Round 7
// 2657.003 us; speedup vs baseline: 6.8671x; 1.0231x over previous
//
#include <hip/hip_runtime.h>
#include <hip/hip_bf16.h>
#include <stdint.h>

#define B_    2
#define T_    1024
#define V_    50257
#define VPAD_ 50304
#define E_    768
#define H_    12
#define L_    12
#define D_    64
#define FF_   3072
#define NTOK  (B_*T_)          // 2048
#define SCALE_ (1.0f/((float)E_*(float)E_))

typedef float f32x4 __attribute__((ext_vector_type(4)));
typedef __bf16 bf16x8 __attribute__((ext_vector_type(8)));
typedef short short8 __attribute__((ext_vector_type(8)));

__device__ __forceinline__ float bits2f(short s) {
    unsigned u = ((unsigned)(unsigned short)s) << 16;
    float f; __builtin_memcpy(&f, &u, 4); return f;
}
__device__ __forceinline__ short f2b(float f) {
    unsigned u; __builtin_memcpy(&u, &f, 4);
    unsigned r = (u + 0x7FFFu + ((u >> 16) & 1u)) >> 16;   // RNE
    return (short)r;
}

#define GLOAD16(gsrc, ldst) __builtin_amdgcn_global_load_lds( \
    (const __attribute__((address_space(1))) unsigned*)(gsrc), \
    (__attribute__((address_space(3))) unsigned*)(ldst), 16, 0, 0)

// ---------------- embedding ----------------
__global__ __launch_bounds__(256) void embed_kernel(
    const int* __restrict__ idx, const float* __restrict__ tok,
    const float* __restrict__ pos, float* __restrict__ x)
{
    int m = blockIdx.x, tid = threadIdx.x;
    int row = idx[m];
    int t = m & (T_-1);
    #pragma unroll
    for (int i = 0; i < 3; i++) {
        int e = tid + i*256;
        x[(size_t)m*E_ + e] = tok[(size_t)row*E_ + e] + pos[(size_t)t*E_ + e];
    }
}

// ---------------- layernorm (f32 in, bf16 out) ----------------
__device__ __forceinline__ float block_sum256(float v, float* red) {
    #pragma unroll
    for (int off = 32; off; off >>= 1) v += __shfl_xor(v, off, 64);
    int w = threadIdx.x >> 6;
    __syncthreads();
    if ((threadIdx.x & 63) == 0) red[w] = v;
    __syncthreads();
    return red[0] + red[1] + red[2] + red[3];
}

__global__ __launch_bounds__(256) void ln_kernel(
    const float* __restrict__ x, const float* __restrict__ g,
    const float* __restrict__ bb, short* __restrict__ out)
{
    __shared__ float red[4];
    int m = blockIdx.x, tid = threadIdx.x;
    const float* xr = x + (size_t)m*E_;
    float loc[3]; float s = 0.f;
    #pragma unroll
    for (int i = 0; i < 3; i++) { loc[i] = xr[tid + i*256]; s += loc[i]; }
    s = block_sum256(s, red);
    float mean = s * (1.0f/E_);
    float vs = 0.f;
    #pragma unroll
    for (int i = 0; i < 3; i++) { float d = loc[i] - mean; vs += d*d; }
    vs = block_sum256(vs, red);
    float rstd = rsqrtf(vs * (1.0f/E_) + 1e-5f);
    #pragma unroll
    for (int i = 0; i < 3; i++) {
        int e = tid + i*256;
        out[(size_t)m*E_ + e] = f2b((loc[i] - mean) * rstd * g[e] + bb[e]);
    }
}

// ---------------- weight packing (vectorized: f32x4 reads, short8 writes) ----------------
// src fp32 [srcK][srcN] -> dst bf16 [dstRows][srcK]; rows beyond srcN zero-filled.
__global__ __launch_bounds__(256) void pack_t(
    const float* __restrict__ src, short* __restrict__ dst,
    int srcK, int srcN, size_t sstride, size_t dstride)
{
    __shared__ float tile[64][65];
    int k0 = blockIdx.x*64, n0 = blockIdx.y*64, l = blockIdx.z;
    const float* s = src + (size_t)l*sstride;
    short* d = dst + (size_t)l*dstride;
    int tid = threadIdx.x;
    const bool vec = (srcN & 3) == 0;     // full blocks + aligned rows
    #pragma unroll
    for (int i = 0; i < 4; i++) {
        int r = (tid >> 4) + i*16;        // k-row
        int c = (tid & 15) * 4;           // n-col group
        const float* sp = s + (size_t)(k0+r)*srcN + n0 + c;
        if (vec) {
            f32x4 v = *(const f32x4*)sp;
            tile[r][c+0] = v.x; tile[r][c+1] = v.y; tile[r][c+2] = v.z; tile[r][c+3] = v.w;
        } else {
            #pragma unroll
            for (int j = 0; j < 4; j++)
                tile[r][c+j] = (n0 + c + j < srcN) ? sp[j] : 0.f;
        }
    }
    __syncthreads();
    #pragma unroll
    for (int i = 0; i < 2; i++) {
        int r2  = (tid >> 3) + i*32;      // dst row (src col)
        int grp = tid & 7;                // k chunk
        short8 o;
        #pragma unroll
        for (int j = 0; j < 8; j++) o[j] = f2b(tile[grp*8 + j][r2]);
        *(short8*)(d + (size_t)(n0+r2)*srcK + k0 + grp*8) = o;
    }
}

// QKV pack: Wq/Wk/Wv [L,H,E,D] fp32 -> dst bf16 [L][2304][768]
__global__ __launch_bounds__(256) void pack_qkv(
    const float* __restrict__ Wq, const float* __restrict__ Wk,
    const float* __restrict__ Wv, short* __restrict__ dst)
{
    __shared__ float tile[64][65];
    int e0 = blockIdx.x*64;
    int y = blockIdx.y, sel = y/12, h = y - sel*12;
    int l = blockIdx.z;
    const float* s = (sel == 0 ? Wq : (sel == 1 ? Wk : Wv)) + (((size_t)l*H_ + h)*E_)*D_;
    int tid = threadIdx.x;
    #pragma unroll
    for (int i = 0; i < 4; i++) {
        int r = (tid >> 4) + i*16;        // e-row
        int c = (tid & 15) * 4;           // d-col group
        f32x4 v = *(const f32x4*)(s + (size_t)(e0+r)*D_ + c);
        tile[r][c+0] = v.x; tile[r][c+1] = v.y; tile[r][c+2] = v.z; tile[r][c+3] = v.w;
    }
    __syncthreads();
    short* d_ = dst + (size_t)l*2304*E_;
    #pragma unroll
    for (int i = 0; i < 2; i++) {
        int r2  = (tid >> 3) + i*32;      // d
        int grp = tid & 7;                // e chunk
        short8 o;
        #pragma unroll
        for (int j = 0; j < 8; j++) o[j] = f2b(tile[grp*8 + j][r2]);
        *(short8*)(d_ + (size_t)(sel*768 + h*64 + r2)*E_ + e0 + grp*8) = o;
    }
}

// ---------------- fast bf16 GEMM: 2-phase double-buffered ----------------
// MODE 0: OutF = acc + bias (col < Nreal);  MODE 1: relu->bf16;  MODE 3: qkv scatter
template<int MODE>
__global__ __launch_bounds__(256) void gemm3(
    const short* __restrict__ A, const short* __restrict__ Bt,
    const float* __restrict__ bias,
    float* __restrict__ X, short* __restrict__ Out, float* __restrict__ OutF,
    int K, int lda, int ldc, int Nreal, int cpx)
{
    __shared__ __align__(16) short As[2][128*32];
    __shared__ __align__(16) short Bs[2][128*32];

    const int tid  = threadIdx.x;
    const int lane = tid & 63, wv = tid >> 6;
    const int wm = wv & 1, wn = wv >> 1;

    int bid = blockIdx.x;
    int g   = (bid & 7)*cpx + (bid >> 3);
    const int m0 = (g & 15) * 128;
    const int n0 = (g >> 4) * 128;

    f32x4 acc[4][4];
    #pragma unroll
    for (int i = 0; i < 4; i++)
        #pragma unroll
        for (int j = 0; j < 4; j++) acc[i][j] = (f32x4){0.f,0.f,0.f,0.f};

    const int srow0 = wv*32 + (lane >> 2);
    const int ssl   = lane & 3;

#define STAGE3(buf, kk) do {                                                  \
    _Pragma("unroll")                                                         \
    for (int i_ = 0; i_ < 2; i_++) {                                          \
        int row_ = srow0 + i_*16;                                             \
        GLOAD16(A  + (size_t)(m0 + row_)*lda + (kk) + ssl*8,                  \
                &As[buf][(wv*128 + i_*64)*8]);                                \
        GLOAD16(Bt + (size_t)(n0 + row_)*K   + (kk) + ssl*8,                  \
                &Bs[buf][(wv*128 + i_*64)*8]);                                \
    } } while(0)

    const int nt = K >> 5;
    STAGE3(0, 0);
    __syncthreads();

    for (int kt = 0; kt < nt; ++kt) {
        const int cur = kt & 1;
        if (kt + 1 < nt) STAGE3(cur ^ 1, (kt + 1) << 5);

        bf16x8 af[4], bf[4];
        #pragma unroll
        for (int mi = 0; mi < 4; mi++) {
            int row = wm*64 + mi*16 + (lane & 15);
            af[mi] = *(const bf16x8*)&As[cur][row*32 + (lane >> 4)*8];
        }
        #pragma unroll
        for (int ni = 0; ni < 4; ni++) {
            int col = wn*64 + ni*16 + (lane & 15);
            bf[ni] = *(const bf16x8*)&Bs[cur][col*32 + (lane >> 4)*8];
        }
        #pragma unroll
        for (int ni = 0; ni < 4; ni++)
            #pragma unroll
            for (int mi = 0; mi < 4; mi++)
                acc[mi][ni] = __builtin_amdgcn_mfma_f32_16x16x32_bf16(af[mi], bf[ni], acc[mi][ni], 0,0,0);
        __syncthreads();
    }
#undef STAGE3

    const int rb = (lane >> 4) << 2;
    const int cb = lane & 15;
    #pragma unroll
    for (int mi = 0; mi < 4; mi++) {
      #pragma unroll
      for (int ni = 0; ni < 4; ni++) {
        #pragma unroll
        for (int j = 0; j < 4; j++) {
            int row = m0 + wm*64 + mi*16 + rb + j;
            int col = n0 + wn*64 + ni*16 + cb;
            float v = acc[mi][ni][j];
            if (MODE == 0) {
                if (col < Nreal) OutF[(size_t)row*ldc + col] = v + bias[col];
            } else if (MODE == 1) {
                v += bias[col];
                v = v > 0.f ? v : 0.f;
                Out[(size_t)row*ldc + col] = f2b(v);
            } else {
                int nsel = col / 768;
                int c = col - nsel*768;
                int h = c >> 6, d = c & 63;
                int b = row >> 10, t = row & (T_-1);
                short* dst = Out + (size_t)nsel*((size_t)NTOK*E_);
                dst[(((size_t)(b*H_ + h)*T_ + t) << 6) + d] = f2b(v);
            }
        }
      }
    }
}

// ---------------- split-K GEMM (2-phase dbuf), accumulate into fp32 X ----------------
template<int SPLITS>
__global__ __launch_bounds__(256) void gemm3_sk(
    const short* __restrict__ A, const short* __restrict__ Bt,
    const float* __restrict__ bias, float* __restrict__ X,
    int K, int lda)
{
    __shared__ __align__(16) short As[2][128*32];
    __shared__ __align__(16) short Bs[2][128*32];

    const int tid  = threadIdx.x;
    const int lane = tid & 63, wv = tid >> 6;
    const int wm = wv & 1, wn = wv >> 1;

    const int panel = blockIdx.x / SPLITS;
    const int sp    = blockIdx.x % SPLITS;
    const int m0 = (panel & 15) * 128;
    const int n0 = (panel >> 4) * 128;
    const int Ks = K / SPLITS;
    const int kbeg = sp * Ks;

    f32x4 acc[4][4];
    #pragma unroll
    for (int i = 0; i < 4; i++)
        #pragma unroll
        for (int j = 0; j < 4; j++) acc[i][j] = (f32x4){0.f,0.f,0.f,0.f};

    const int srow0 = wv*32 + (lane >> 2);
    const int ssl   = lane & 3;

#define STAGESK(buf, kk) do {                                                 \
    _Pragma("unroll")                                                         \
    for (int i_ = 0; i_ < 2; i_++) {                                          \
        int row_ = srow0 + i_*16;                                             \
        GLOAD16(A  + (size_t)(m0 + row_)*lda + (kk) + ssl*8,                  \
                &As[buf][(wv*128 + i_*64)*8]);                                \
        GLOAD16(Bt + (size_t)(n0 + row_)*K   + (kk) + ssl*8,                  \
                &Bs[buf][(wv*128 + i_*64)*8]);                                \
    } } while(0)

    const int nt = Ks >> 5;
    STAGESK(0, kbeg);
    __syncthreads();

    for (int kt = 0; kt < nt; ++kt) {
        const int cur = kt & 1;
        if (kt + 1 < nt) STAGESK(cur ^ 1, kbeg + ((kt + 1) << 5));

        bf16x8 af[4], bf[4];
        #pragma unroll
        for (int mi = 0; mi < 4; mi++) {
            int row = wm*64 + mi*16 + (lane & 15);
            af[mi] = *(const bf16x8*)&As[cur][row*32 + (lane >> 4)*8];
        }
        #pragma unroll
        for (int ni = 0; ni < 4; ni++) {
            int col = wn*64 + ni*16 + (lane & 15);
            bf[ni] = *(const bf16x8*)&Bs[cur][col*32 + (lane >> 4)*8];
        }
        #pragma unroll
        for (int ni = 0; ni < 4; ni++)
            #pragma unroll
            for (int mi = 0; mi < 4; mi++)
                acc[mi][ni] = __builtin_amdgcn_mfma_f32_16x16x32_bf16(af[mi], bf[ni], acc[mi][ni], 0,0,0);
        __syncthreads();
    }
#undef STAGESK

    const int rb = (lane >> 4) << 2;
    const int cb = lane & 15;
    #pragma unroll
    for (int mi = 0; mi < 4; mi++) {
      #pragma unroll
      for (int ni = 0; ni < 4; ni++) {
        #pragma unroll
        for (int j = 0; j < 4; j++) {
            int row = m0 + wm*64 + mi*16 + rb + j;
            int col = n0 + wn*64 + ni*16 + cb;
            float v = acc[mi][ni][j];
            if (sp == 0) v += bias[col];
            atomicAdd(&X[(size_t)row*E_ + col], v);
        }
      }
    }
}

// ---------------- flash attention (faithful swap: "Q"=k-proj, "K"=q-proj) ----------------
// T14 async-stage: next tile's Q/V loaded to regs during current tile's compute.
__global__ __launch_bounds__(256) void attn2(
    const short* __restrict__ qg, const short* __restrict__ kg,
    const short* __restrict__ vg, short* __restrict__ ao)
{
    __shared__ __align__(16) short Kt[64*64];
    __shared__ __align__(16) short Qs[64*64];
    __shared__ __align__(16) short Vs[64*64];
    __shared__ __align__(16) short Ps[4][16*64];

    const int tid = threadIdx.x, lane = tid & 63, w = tid >> 6, g = lane >> 4;
    const int t0 = blockIdx.x * 64;
    const int bh = blockIdx.y;
    const size_t base = (size_t)bh * T_ * 64;

    #pragma unroll
    for (int is = 0; is < 2; is++) {
        int idx = is*256 + tid;
        int row = idx >> 3, sl = idx & 7;
        short8 v = *(const short8*)(kg + base + (size_t)(t0+row)*64 + sl*8);
        *(short8*)&Kt[row*64 + (sl ^ (row&7))*8] = v;
    }
    __syncthreads();

    bf16x8 akt[2];
    {
        int lt = w*16 + (lane & 15);
        #pragma unroll
        for (int c = 0; c < 2; c++)
            akt[c] = *(const bf16x8*)&Kt[lt*64 + ((c*4+g) ^ (lt&7))*8];
    }

    f32x4 o[4]; float m_run[4], l_run[4];
    #pragma unroll
    for (int i = 0; i < 4; i++) { o[i] = (f32x4){0,0,0,0}; m_run[i] = -1e30f; l_run[i] = 0.f; }

    // staging geometry
    const int qrow = tid >> 3, qsl = tid & 7;       // Q: rows 0..31 (+32 for chunk 1)
    const int vd0 = (tid & 31) * 2;
    const int vsh = tid >> 5;

    short8 qv[2];            // staged Q rows (2 chunks)
    unsigned vvr[8];         // staged V dwords

#define REGLOAD(s0_) do {                                                        \
    _Pragma("unroll")                                                            \
    for (int is_ = 0; is_ < 2; is_++)                                            \
        qv[is_] = *(const short8*)(qg + base + (size_t)((s0_) + qrow + is_*32)*64 + qsl*8); \
    _Pragma("unroll")                                                            \
    for (int i_ = 0; i_ < 8; i_++)                                               \
        vvr[i_] = *(const unsigned*)(vg + base + (size_t)((s0_) + vsh*8 + i_)*64 + vd0);    \
    } while(0)

    const int ntiles = (t0 >> 6) + 1;
    REGLOAD(0);

    for (int it = 0; it < ntiles; ++it) {
        __syncthreads();               // previous tile fully consumed
        // LDS write of staged tile
        #pragma unroll
        for (int is = 0; is < 2; is++) {
            int row = qrow + is*32;
            *(short8*)&Qs[row*64 + (qsl ^ (row&7))*8] = qv[is];
        }
        #pragma unroll
        for (int dp = 0; dp < 2; dp++) {
            int d = vd0 + dp;
            short tmp[8];
            #pragma unroll
            for (int i = 0; i < 8; i++) tmp[i] = (short)((vvr[i] >> (dp*16)) & 0xffffu);
            *(short8*)&Vs[d*64 + (vsh ^ (d&7))*8] = *(short8*)tmp;
        }
        if (it + 1 < ntiles) REGLOAD((it+1)*64);   // in flight under compute
        __syncthreads();

        const int s0 = it*64;
        // ---- QK^T ----
        f32x4 s4[4];
        #pragma unroll
        for (int j = 0; j < 4; j++) s4[j] = (f32x4){0,0,0,0};
        #pragma unroll
        for (int c = 0; c < 2; c++) {
            #pragma unroll
            for (int j = 0; j < 4; j++) {
                int sr = j*16 + (lane & 15);
                bf16x8 bq = *(const bf16x8*)&Qs[sr*64 + ((c*4+g) ^ (sr&7))*8];
                s4[j] = __builtin_amdgcn_mfma_f32_16x16x32_bf16(akt[c], bq, s4[j], 0,0,0);
            }
        }
        float p[4][4];
        const bool diag = (it == ntiles-1);
        #pragma unroll
        for (int j = 0; j < 4; j++) {
          #pragma unroll
          for (int r = 0; r < 4; r++) {
            float v = s4[j][r] * SCALE_;
            if (diag) {
                int tglob = t0 + w*16 + g*4 + r;
                int sglob = s0 + j*16 + (lane & 15);
                if (sglob > tglob) v = -1e30f;
            }
            p[j][r] = v;
          }
        }
        #pragma unroll
        for (int r = 0; r < 4; r++) {
            float mx = fmaxf(fmaxf(p[0][r], p[1][r]), fmaxf(p[2][r], p[3][r]));
            #pragma unroll
            for (int off = 1; off < 16; off <<= 1) mx = fmaxf(mx, __shfl_xor(mx, off, 64));
            float mnew  = fmaxf(m_run[r], mx);
            float alpha = __expf(m_run[r] - mnew);
            float rs = 0.f;
            #pragma unroll
            for (int j = 0; j < 4; j++) { p[j][r] = __expf(p[j][r] - mnew); rs += p[j][r]; }
            #pragma unroll
            for (int off = 1; off < 16; off <<= 1) rs += __shfl_xor(rs, off, 64);
            l_run[r] = l_run[r]*alpha + rs;
            m_run[r] = mnew;
            #pragma unroll
            for (int ni = 0; ni < 4; ni++) o[ni][r] *= alpha;
        }
        #pragma unroll
        for (int j = 0; j < 4; j++) {
          #pragma unroll
          for (int r = 0; r < 4; r++) {
            int tl = g*4 + r, sc = j*16 + (lane & 15);
            Ps[w][tl*64 + ((sc>>3) ^ (tl&7))*8 + (sc&7)] = f2b(p[j][r]);
          }
        }
        asm volatile("s_waitcnt lgkmcnt(0)" ::: "memory");
        __builtin_amdgcn_sched_barrier(0);
        // ---- PV ----
        #pragma unroll
        for (int c = 0; c < 2; c++) {
            int tl = lane & 15;
            bf16x8 pa = *(const bf16x8*)&Ps[w][tl*64 + ((c*4+g) ^ (tl&7))*8];
            #pragma unroll
            for (int ni = 0; ni < 4; ni++) {
                int d = ni*16 + (lane & 15);
                bf16x8 bv = *(const bf16x8*)&Vs[d*64 + ((c*4+g) ^ (d&7))*8];
                o[ni] = __builtin_amdgcn_mfma_f32_16x16x32_bf16(pa, bv, o[ni], 0,0,0);
            }
        }
    }
#undef REGLOAD

    const int b = bh / H_, h = bh - b*H_;
    #pragma unroll
    for (int ni = 0; ni < 4; ni++) {
      #pragma unroll
      for (int r = 0; r < 4; r++) {
        int t = t0 + w*16 + g*4 + r;
        int d = ni*16 + (lane & 15);
        ao[((size_t)(b*T_ + t))*E_ + h*64 + d] = f2b(o[ni][r] / l_run[r]);
      }
    }
}

// ---------------- fallback GEMM (fp32 B on the fly) ----------------
template<int MODE, bool QKV3>
__global__ __launch_bounds__(256) void gemm2(
    const short* __restrict__ A,
    const float* __restrict__ Bq, const float* __restrict__ Bk2, const float* __restrict__ Bv2,
    const float* __restrict__ bias,
    float* __restrict__ X, short* __restrict__ Out, float* __restrict__ OutF,
    int M, int Ntot, int K, int lda, int kstride, int ldc)
{
    __shared__ __align__(16) short As[128*32];
    __shared__ __align__(16) short Bs[128*32];

    const int tid  = threadIdx.x;
    const int lane = tid & 63, wave = tid >> 6;
    const int wm = wave & 1, wn = wave >> 1;
    const int m0 = blockIdx.x * 128;
    const int n0 = blockIdx.y * 128;
    const int g  = lane >> 4;

    const float* Bm = Bq;
    int nsel = 0, c0 = n0;
    if (QKV3) {
        nsel = n0 / 768;
        c0 = n0 - nsel*768;
        Bm = (nsel == 0) ? Bq : (nsel == 1 ? Bk2 : Bv2);
    }

    f32x4 acc[4][4];
    #pragma unroll
    for (int i = 0; i < 4; i++)
        #pragma unroll
        for (int j = 0; j < 4; j++) acc[i][j] = (f32x4){0.f,0.f,0.f,0.f};

    const int bn  = tid & 127;
    const int bkh = tid >> 7;
    const int cg  = c0 + bn;
    const bool bvalid = QKV3 ? true : (cg < Ntot);
    size_t bbase;
    if (QKV3) bbase = (size_t)(cg >> 6) * ((size_t)E_*D_) + (cg & 63);
    else      bbase = (size_t)cg;

    for (int k0 = 0; k0 < K; k0 += 32) {
        #pragma unroll
        for (int is = 0; is < 2; is++) {
            int idx = is*256 + tid;
            int row = idx >> 2, sl = idx & 3;
            short8 v = *(const short8*)(A + (size_t)(m0+row)*lda + k0 + sl*8);
            int sl2 = sl ^ ((row ^ (row>>2)) & 3);
            *(short8*)&As[row*32 + sl2*8] = v;
        }
        {
            float bv[16];
            #pragma unroll
            for (int i = 0; i < 16; i++) {
                int k = k0 + bkh*16 + i;
                bv[i] = bvalid ? Bm[bbase + (size_t)k*kstride] : 0.f;
            }
            short bh16[16];
            #pragma unroll
            for (int i = 0; i < 16; i++) {
                __bf16 h = (__bf16)bv[i];
                bh16[i] = __builtin_bit_cast(short, h);
            }
            #pragma unroll
            for (int q = 0; q < 2; q++) {
                int kb  = bkh*2 + q;
                int sl2 = kb ^ ((bn ^ (bn>>2)) & 3);
                *(short8*)&Bs[bn*32 + sl2*8] = *(short8*)&bh16[q*8];
            }
        }
        __syncthreads();

        bf16x8 af[4];
        #pragma unroll
        for (int mi = 0; mi < 4; mi++) {
            int row = wm*64 + mi*16 + (lane & 15);
            int sl2 = g ^ ((row ^ (row>>2)) & 3);
            af[mi] = *(const bf16x8*)&As[row*32 + sl2*8];
        }
        #pragma unroll
        for (int ni = 0; ni < 4; ni++) {
            int nn  = wn*64 + ni*16 + (lane & 15);
            int sl2 = g ^ ((nn ^ (nn>>2)) & 3);
            bf16x8 bfr = *(const bf16x8*)&Bs[nn*32 + sl2*8];
            #pragma unroll
            for (int mi = 0; mi < 4; mi++)
                acc[mi][ni] = __builtin_amdgcn_mfma_f32_16x16x32_bf16(af[mi], bfr, acc[mi][ni], 0,0,0);
        }
        __syncthreads();
    }

    const int rb = g << 2;
    const int cb = lane & 15;
    #pragma unroll
    for (int mi = 0; mi < 4; mi++) {
      #pragma unroll
      for (int ni = 0; ni < 4; ni++) {
        #pragma unroll
        for (int j = 0; j < 4; j++) {
            int row = m0 + wm*64 + mi*16 + rb + j;
            int col = n0 + wn*64 + ni*16 + cb;
            float v = acc[mi][ni][j];
            if (MODE == 0) {
                if (col < Ntot) OutF[(size_t)row*ldc + col] = v + bias[col];
            } else if (MODE == 1) {
                v += bias[col];
                v = v > 0.f ? v : 0.f;
                Out[(size_t)row*ldc + col] = f2b(v);
            } else if (MODE == 2) {
                X[(size_t)row*E_ + col] += v + bias[col];
            } else {
                int c = col - nsel*768;
                int h = c >> 6, d = c & 63;
                int b = row >> 10, t = row & (T_-1);
                short* dst = Out + (size_t)nsel*((size_t)NTOK*E_);
                dst[(((size_t)(b*H_ + h)*T_ + t) << 6) + d] = f2b(v);
            }
        }
      }
    }
}

// ---------------- host launch ----------------
extern "C" void kernel_launch(void* const* d_in, const int* in_sizes, int n_in,
                              void* d_out, int out_size, void* d_ws, size_t ws_size,
                              hipStream_t stream)
{
    (void)in_sizes; (void)n_in; (void)out_size;

    const int*   idx     = (const int*)  d_in[0];
    const float* tok_emb = (const float*)d_in[1];
    const float* pos_emb = (const float*)d_in[2];
    const float* Wk      = (const float*)d_in[3];
    const float* Wq      = (const float*)d_in[4];
    const float* Wv      = (const float*)d_in[5];
    const float* Wproj   = (const float*)d_in[6];
    const float* bproj   = (const float*)d_in[7];
    const float* ln1_g   = (const float*)d_in[8];
    const float* ln1_b   = (const float*)d_in[9];
    const float* W1      = (const float*)d_in[10];
    const float* b1      = (const float*)d_in[11];
    const float* W2      = (const float*)d_in[12];
    const float* b2      = (const float*)d_in[13];
    const float* ln2_g   = (const float*)d_in[14];
    const float* ln2_b   = (const float*)d_in[15];
    const float* lnf_g   = (const float*)d_in[16];
    const float* lnf_b   = (const float*)d_in[17];
    const float* Wlm     = (const float*)d_in[18];
    const float* blm     = (const float*)d_in[19];
    float* out = (float*)d_out;

    char* w = (char*)d_ws;
    float* x    = (float*)w; w += (size_t)NTOK*E_*4;
    short* hbuf = (short*)w; w += (size_t)NTOK*E_*2;
    short* qb   = (short*)w; w += (size_t)NTOK*E_*2;
    short* kb   = (short*)w; w += (size_t)NTOK*E_*2;
    short* vb   = (short*)w; w += (size_t)NTOK*E_*2;
    short* aob  = (short*)w; w += (size_t)NTOK*E_*2;
    short* midb = (short*)w; w += (size_t)NTOK*FF_*2;

    const size_t act_bytes = (size_t)(w - (char*)d_ws);
    const size_t wqkv_n = (size_t)L_*2304*E_;
    const size_t wproj_n = (size_t)L_*E_*E_;
    const size_t wff_n = (size_t)L_*E_*FF_;
    const size_t wlm_n = (size_t)VPAD_*E_;
    const size_t need = act_bytes + 2*(wqkv_n + wproj_n + 2*wff_n + wlm_n);

    const size_t HED = (size_t)H_*E_*D_;
    dim3 gAT(T_/64, B_*H_);

    embed_kernel<<<NTOK, 256, 0, stream>>>(idx, tok_emb, pos_emb, x);

    if (ws_size >= need) {
        // ---------- fast path: prepack weights to bf16 (B^T layout) ----------
        short* qkvw = (short*)w; w += wqkv_n*2;
        short* projw= (short*)w; w += wproj_n*2;
        short* w1w  = (short*)w; w += wff_n*2;
        short* w2w  = (short*)w; w += wff_n*2;
        short* lmw  = (short*)w;

        pack_qkv<<<dim3(E_/64, 36, L_), 256, 0, stream>>>(Wq, Wk, Wv, qkvw);
        pack_t<<<dim3(E_/64, E_/64, L_), 256, 0, stream>>>(Wproj, projw, E_, E_, (size_t)E_*E_, (size_t)E_*E_);
        pack_t<<<dim3(E_/64, FF_/64, L_), 256, 0, stream>>>(W1, w1w, E_, FF_, (size_t)E_*FF_, (size_t)E_*FF_);
        pack_t<<<dim3(FF_/64, E_/64, L_), 256, 0, stream>>>(W2, w2w, FF_, E_, (size_t)E_*FF_, (size_t)E_*FF_);
        pack_t<<<dim3(E_/64, VPAD_/64, 1), 256, 0, stream>>>(Wlm, lmw, E_, V_, 0, 0);

        const int nQKV = 16*(2304/128), nF1 = 16*(FF_/128), nLM = 16*(VPAD_/128);
        const int nP = 16*(E_/128);    // 96 panels for N=768

        for (int l = 0; l < L_; l++) {
            ln_kernel<<<NTOK, 256, 0, stream>>>(x, ln1_g + (size_t)l*E_, ln1_b + (size_t)l*E_, hbuf);
            gemm3<3><<<nQKV, 256, 0, stream>>>(hbuf, qkvw + (size_t)l*2304*E_, nullptr,
                                               nullptr, qb, nullptr, E_, E_, 0, 2304, nQKV/8);
            attn2<<<gAT, 256, 0, stream>>>(qb, kb, vb, aob);
            gemm3_sk<2><<<nP*2, 256, 0, stream>>>(aob, projw + (size_t)l*E_*E_,
                                                  bproj + (size_t)l*E_, x, E_, E_);
            ln_kernel<<<NTOK, 256, 0, stream>>>(x, ln2_g + (size_t)l*E_, ln2_b + (size_t)l*E_, hbuf);
            gemm3<1><<<nF1, 256, 0, stream>>>(hbuf, w1w + (size_t)l*E_*FF_, b1 + (size_t)l*FF_,
                                              nullptr, midb, nullptr, E_, E_, FF_, FF_, nF1/8);
            gemm3_sk<4><<<nP*4, 256, 0, stream>>>(midb, w2w + (size_t)l*E_*FF_,
                                                  b2 + (size_t)l*E_, x, FF_, FF_);
        }
        ln_kernel<<<NTOK, 256, 0, stream>>>(x, lnf_g, lnf_b, hbuf);
        gemm3<0><<<nLM, 256, 0, stream>>>(hbuf, lmw, blm, nullptr, nullptr, out,
                                          E_, E_, V_, V_, nLM/8);
    } else {
        // ---------- fallback: round-3 path ----------
        dim3 gQKV(16, 18), gP(16, 6), gF1(16, 24), gLM(16, 393);
        for (int l = 0; l < L_; l++) {
            ln_kernel<<<NTOK, 256, 0, stream>>>(x, ln1_g + (size_t)l*E_, ln1_b + (size_t)l*E_, hbuf);
            gemm2<3,true><<<gQKV, 256, 0, stream>>>(hbuf,
                Wq + (size_t)l*HED, Wk + (size_t)l*HED, Wv + (size_t)l*HED,
                nullptr, nullptr, qb, nullptr, NTOK, 2304, E_, E_, 64, 0);
            attn2<<<gAT, 256, 0, stream>>>(qb, kb, vb, aob);
            gemm2<2,false><<<gP, 256, 0, stream>>>(aob,
                Wproj + (size_t)l*E_*E_, nullptr, nullptr, bproj + (size_t)l*E_,
                x, nullptr, nullptr, NTOK, E_, E_, E_, E_, 0);
            ln_kernel<<<NTOK, 256, 0, stream>>>(x, ln2_g + (size_t)l*E_, ln2_b + (size_t)l*E_, hbuf);
            gemm2<1,false><<<gF1, 256, 0, stream>>>(hbuf,
                W1 + (size_t)l*E_*FF_, nullptr, nullptr, b1 + (size_t)l*FF_,
                nullptr, midb, nullptr, NTOK, FF_, E_, E_, FF_, FF_);
            gemm2<2,false><<<gP, 256, 0, stream>>>(midb,
                W2 + (size_t)l*FF_*E_, nullptr, nullptr, b2 + (size_t)l*E_,
                x, nullptr, nullptr, NTOK, E_, FF_, FF_, E_, 0);
        }
        ln_kernel<<<NTOK, 256, 0, stream>>>(x, lnf_g, lnf_b, hbuf);
        gemm2<0,false><<<gLM, 256, 0, stream>>>(hbuf,
            Wlm, nullptr, nullptr, blm,
            nullptr, nullptr, out, NTOK, V_, E_, E_, V_, V_);
    }
}

// Round 8
// 2462.629 us; speedup vs baseline: 7.4091x; 1.0789x over previous
//
#include <hip/hip_runtime.h>
#include <hip/hip_bf16.h>
#include <stdint.h>

#define B_    2
#define T_    1024
#define V_    50257
#define VPAD_ 50304
#define E_    768
#define H_    12
#define L_    12
#define D_    64
#define FF_   3072
#define NTOK  (B_*T_)          // 2048
#define SCALE_ (1.0f/((float)E_*(float)E_))

typedef float f32x4 __attribute__((ext_vector_type(4)));
typedef __bf16 bf16x8 __attribute__((ext_vector_type(8)));
typedef short short8 __attribute__((ext_vector_type(8)));

__device__ __forceinline__ float bits2f(short s) {
    unsigned u = ((unsigned)(unsigned short)s) << 16;
    float f; __builtin_memcpy(&f, &u, 4); return f;
}
__device__ __forceinline__ short f2b(float f) {
    unsigned u; __builtin_memcpy(&u, &f, 4);
    unsigned r = (u + 0x7FFFu + ((u >> 16) & 1u)) >> 16;   // RNE
    return (short)r;
}

#define GLOAD16(gsrc, ldst) __builtin_amdgcn_global_load_lds( \
    (const __attribute__((address_space(1))) unsigned*)(gsrc), \
    (__attribute__((address_space(3))) unsigned*)(ldst), 16, 0, 0)

// ---------------- embedding ----------------
__global__ __launch_bounds__(256) void embed_kernel(
    const int* __restrict__ idx, const float* __restrict__ tok,
    const float* __restrict__ pos, float* __restrict__ x)
{
    int m = blockIdx.x, tid = threadIdx.x;
    int row = idx[m];
    int t = m & (T_-1);
    #pragma unroll
    for (int i = 0; i < 3; i++) {
        int e = tid + i*256;
        x[(size_t)m*E_ + e] = tok[(size_t)row*E_ + e] + pos[(size_t)t*E_ + e];
    }
}

// ---------------- layernorm (f32 in, bf16 out) ----------------
__device__ __forceinline__ float block_sum256(float v, float* red) {
    #pragma unroll
    for (int off = 32; off; off >>= 1) v += __shfl_xor(v, off, 64);
    int w = threadIdx.x >> 6;
    __syncthreads();
    if ((threadIdx.x & 63) == 0) red[w] = v;
    __syncthreads();
    return red[0] + red[1] + red[2] + red[3];
}

__global__ __launch_bounds__(256) void ln_kernel(
    const float* __restrict__ x, const float* __restrict__ g,
    const float* __restrict__ bb, short* __restrict__ out)
{
    __shared__ float red[4];
    int m = blockIdx.x, tid = threadIdx.x;
    const float* xr = x + (size_t)m*E_;
    float loc[3]; float s = 0.f;
    #pragma unroll
    for (int i = 0; i < 3; i++) { loc[i] = xr[tid + i*256]; s += loc[i]; }
    s = block_sum256(s, red);
    float mean = s * (1.0f/E_);
    float vs = 0.f;
    #pragma unroll
    for (int i = 0; i < 3; i++) { float d = loc[i] - mean; vs += d*d; }
    vs = block_sum256(vs, red);
    float rstd = rsqrtf(vs * (1.0f/E_) + 1e-5f);
    #pragma unroll
    for (int i = 0; i < 3; i++) {
        int e = tid + i*256;
        out[(size_t)m*E_ + e] = f2b((loc[i] - mean) * rstd * g[e] + bb[e]);
    }
}

// ---------------- weight packing (vectorized) ----------------
__global__ __launch_bounds__(256) void pack_t(
    const float* __restrict__ src, short* __restrict__ dst,
    int srcK, int srcN, size_t sstride, size_t dstride)
{
    __shared__ float tile[64][65];
    int k0 = blockIdx.x*64, n0 = blockIdx.y*64, l = blockIdx.z;
    const float* s = src + (size_t)l*sstride;
    short* d = dst + (size_t)l*dstride;
    int tid = threadIdx.x;
    const bool vec = (srcN & 3) == 0;
    #pragma unroll
    for (int i = 0; i < 4; i++) {
        int r = (tid >> 4) + i*16;
        int c = (tid & 15) * 4;
        const float* sp = s + (size_t)(k0+r)*srcN + n0 + c;
        if (vec) {
            f32x4 v = *(const f32x4*)sp;
            tile[r][c+0] = v.x; tile[r][c+1] = v.y; tile[r][c+2] = v.z; tile[r][c+3] = v.w;
        } else {
            #pragma unroll
            for (int j = 0; j < 4; j++)
                tile[r][c+j] = (n0 + c + j < srcN) ? sp[j] : 0.f;
        }
    }
    __syncthreads();
    #pragma unroll
    for (int i = 0; i < 2; i++) {
        int r2  = (tid >> 3) + i*32;
        int grp = tid & 7;
        short8 o;
        #pragma unroll
        for (int j = 0; j < 8; j++) o[j] = f2b(tile[grp*8 + j][r2]);
        *(short8*)(d + (size_t)(n0+r2)*srcK + k0 + grp*8) = o;
    }
}

__global__ __launch_bounds__(256) void pack_qkv(
    const float* __restrict__ Wq, const float* __restrict__ Wk,
    const float* __restrict__ Wv, short* __restrict__ dst)
{
    __shared__ float tile[64][65];
    int e0 = blockIdx.x*64;
    int y = blockIdx.y, sel = y/12, h = y - sel*12;
    int l = blockIdx.z;
    const float* s = (sel == 0 ? Wq : (sel == 1 ? Wk : Wv)) + (((size_t)l*H_ + h)*E_)*D_;
    int tid = threadIdx.x;
    #pragma unroll
    for (int i = 0; i < 4; i++) {
        int r = (tid >> 4) + i*16;
        int c = (tid & 15) * 4;
        f32x4 v = *(const f32x4*)(s + (size_t)(e0+r)*D_ + c);
        tile[r][c+0] = v.x; tile[r][c+1] = v.y; tile[r][c+2] = v.z; tile[r][c+3] = v.w;
    }
    __syncthreads();
    short* d_ = dst + (size_t)l*2304*E_;
    #pragma unroll
    for (int i = 0; i < 2; i++) {
        int r2  = (tid >> 3) + i*32;
        int grp = tid & 7;
        short8 o;
        #pragma unroll
        for (int j = 0; j < 8; j++) o[j] = f2b(tile[grp*8 + j][r2]);
        *(short8*)(d_ + (size_t)(sel*768 + h*64 + r2)*E_ + e0 + grp*8) = o;
    }
}

// ---------------- fast bf16 GEMM: 3-buffer, counted-vmcnt pipeline (T4) ----------------
// MODE 0: OutF = acc + bias (col < Nreal);  MODE 1: relu->bf16;  MODE 3: qkv scatter
template<int MODE>
__global__ __launch_bounds__(256) void gemm3(
    const short* __restrict__ A, const short* __restrict__ Bt,
    const float* __restrict__ bias,
    float* __restrict__ X, short* __restrict__ Out, float* __restrict__ OutF,
    int K, int lda, int ldc, int Nreal, int cpx)
{
    __shared__ __align__(16) short As[3][128*32];
    __shared__ __align__(16) short Bs[3][128*32];

    const int tid  = threadIdx.x;
    const int lane = tid & 63, wv = tid >> 6;
    const int wm = wv & 1, wn = wv >> 1;

    int bid = blockIdx.x;
    int g   = (bid & 7)*cpx + (bid >> 3);
    const int m0 = (g & 15) * 128;
    const int n0 = (g >> 4) * 128;

    f32x4 acc[4][4];
    #pragma unroll
    for (int i = 0; i < 4; i++)
        #pragma unroll
        for (int j = 0; j < 4; j++) acc[i][j] = (f32x4){0.f,0.f,0.f,0.f};

    const int srow0 = wv*32 + (lane >> 2);
    const int ssl   = lane & 3;

#define STAGE3(buf, kk) do {                                                  \
    _Pragma("unroll")                                                         \
    for (int i_ = 0; i_ < 2; i_++) {                                          \
        int row_ = srow0 + i_*16;                                             \
        GLOAD16(A  + (size_t)(m0 + row_)*lda + (kk) + ssl*8,                  \
                &As[buf][(wv*128 + i_*64)*8]);                                \
        GLOAD16(Bt + (size_t)(n0 + row_)*K   + (kk) + ssl*8,                  \
                &Bs[buf][(wv*128 + i_*64)*8]);                                \
    } } while(0)

    const int nt = K >> 5;                 // always >= 2 here
    STAGE3(0, 0);
    if (nt > 1) STAGE3(1, 32);

    int cur = 0, nxt2 = 2;
    for (int kt = 0; kt < nt; ++kt) {
        if (kt + 1 < nt) asm volatile("s_waitcnt vmcnt(4)" ::: "memory");
        else             asm volatile("s_waitcnt vmcnt(0)" ::: "memory");
        __builtin_amdgcn_s_barrier();

        bf16x8 af[4], bf[4];
        #pragma unroll
        for (int mi = 0; mi < 4; mi++) {
            int row = wm*64 + mi*16 + (lane & 15);
            af[mi] = *(const bf16x8*)&As[cur][row*32 + (lane >> 4)*8];
        }
        #pragma unroll
        for (int ni = 0; ni < 4; ni++) {
            int col = wn*64 + ni*16 + (lane & 15);
            bf[ni] = *(const bf16x8*)&Bs[cur][col*32 + (lane >> 4)*8];
        }
        if (kt + 2 < nt) STAGE3(nxt2, (kt + 2) << 5);

        #pragma unroll
        for (int ni = 0; ni < 4; ni++)
            #pragma unroll
            for (int mi = 0; mi < 4; mi++)
                acc[mi][ni] = __builtin_amdgcn_mfma_f32_16x16x32_bf16(af[mi], bf[ni], acc[mi][ni], 0,0,0);

        cur  = (cur  == 2) ? 0 : cur + 1;
        nxt2 = (nxt2 == 2) ? 0 : nxt2 + 1;
    }
#undef STAGE3

    const int rb = (lane >> 4) << 2;
    const int cb = lane & 15;
    #pragma unroll
    for (int mi = 0; mi < 4; mi++) {
      #pragma unroll
      for (int ni = 0; ni < 4; ni++) {
        #pragma unroll
        for (int j = 0; j < 4; j++) {
            int row = m0 + wm*64 + mi*16 + rb + j;
            int col = n0 + wn*64 + ni*16 + cb;
            float v = acc[mi][ni][j];
            if (MODE == 0) {
                if (col < Nreal) OutF[(size_t)row*ldc + col] = v + bias[col];
            } else if (MODE == 1) {
                v += bias[col];
                v = v > 0.f ? v : 0.f;
                Out[(size_t)row*ldc + col] = f2b(v);
            } else {
                int nsel = col / 768;
                int c = col - nsel*768;
                int h = c >> 6, d = c & 63;
                int b = row >> 10, t = row & (T_-1);
                short* dst = Out + (size_t)nsel*((size_t)NTOK*E_);
                dst[(((size_t)(b*H_ + h)*T_ + t) << 6) + d] = f2b(v);
            }
        }
      }
    }
}

// ---------------- split-K GEMM (3-buffer counted-vmcnt), accumulate into fp32 X ----------------
template<int SPLITS>
__global__ __launch_bounds__(256) void gemm3_sk(
    const short* __restrict__ A, const short* __restrict__ Bt,
    const float* __restrict__ bias, float* __restrict__ X,
    int K, int lda)
{
    __shared__ __align__(16) short As[3][128*32];
    __shared__ __align__(16) short Bs[3][128*32];

    const int tid  = threadIdx.x;
    const int lane = tid & 63, wv = tid >> 6;
    const int wm = wv & 1, wn = wv >> 1;

    const int panel = blockIdx.x / SPLITS;
    const int sp    = blockIdx.x % SPLITS;
    const int m0 = (panel & 15) * 128;
    const int n0 = (panel >> 4) * 128;
    const int Ks = K / SPLITS;
    const int kbeg = sp * Ks;

    f32x4 acc[4][4];
    #pragma unroll
    for (int i = 0; i < 4; i++)
        #pragma unroll
        for (int j = 0; j < 4; j++) acc[i][j] = (f32x4){0.f,0.f,0.f,0.f};

    const int srow0 = wv*32 + (lane >> 2);
    const int ssl   = lane & 3;

#define STAGESK(buf, kk) do {                                                 \
    _Pragma("unroll")                                                         \
    for (int i_ = 0; i_ < 2; i_++) {                                          \
        int row_ = srow0 + i_*16;                                             \
        GLOAD16(A  + (size_t)(m0 + row_)*lda + (kk) + ssl*8,                  \
                &As[buf][(wv*128 + i_*64)*8]);                                \
        GLOAD16(Bt + (size_t)(n0 + row_)*K   + (kk) + ssl*8,                  \
                &Bs[buf][(wv*128 + i_*64)*8]);                                \
    } } while(0)

    const int nt = Ks >> 5;
    STAGESK(0, kbeg);
    if (nt > 1) STAGESK(1, kbeg + 32);

    int cur = 0, nxt2 = 2;
    for (int kt = 0; kt < nt; ++kt) {
        if (kt + 1 < nt) asm volatile("s_waitcnt vmcnt(4)" ::: "memory");
        else             asm volatile("s_waitcnt vmcnt(0)" ::: "memory");
        __builtin_amdgcn_s_barrier();

        bf16x8 af[4], bf[4];
        #pragma unroll
        for (int mi = 0; mi < 4; mi++) {
            int row = wm*64 + mi*16 + (lane & 15);
            af[mi] = *(const bf16x8*)&As[cur][row*32 + (lane >> 4)*8];
        }
        #pragma unroll
        for (int ni = 0; ni < 4; ni++) {
            int col = wn*64 + ni*16 + (lane & 15);
            bf[ni] = *(const bf16x8*)&Bs[cur][col*32 + (lane >> 4)*8];
        }
        if (kt + 2 < nt) STAGESK(nxt2, kbeg + ((kt + 2) << 5));

        #pragma unroll
        for (int ni = 0; ni < 4; ni++)
            #pragma unroll
            for (int mi = 0; mi < 4; mi++)
                acc[mi][ni] = __builtin_amdgcn_mfma_f32_16x16x32_bf16(af[mi], bf[ni], acc[mi][ni], 0,0,0);

        cur  = (cur  == 2) ? 0 : cur + 1;
        nxt2 = (nxt2 == 2) ? 0 : nxt2 + 1;
    }
#undef STAGESK

    const int rb = (lane >> 4) << 2;
    const int cb = lane & 15;
    #pragma unroll
    for (int mi = 0; mi < 4; mi++) {
      #pragma unroll
      for (int ni = 0; ni < 4; ni++) {
        #pragma unroll
        for (int j = 0; j < 4; j++) {
            int row = m0 + wm*64 + mi*16 + rb + j;
            int col = n0 + wn*64 + ni*16 + cb;
            float v = acc[mi][ni][j];
            if (sp == 0) v += bias[col];
            atomicAdd(&X[(size_t)row*E_ + col], v);
        }
      }
    }
}

// ---------------- flash attention (faithful swap: "Q"=k-proj, "K"=q-proj) ----------------
__global__ __launch_bounds__(256) void attn2(
    const short* __restrict__ qg, const short* __restrict__ kg,
    const short* __restrict__ vg, short* __restrict__ ao)
{
    __shared__ __align__(16) short Kt[64*64];
    __shared__ __align__(16) short Qs[64*64];
    __shared__ __align__(16) short Vs[64*64];
    __shared__ __align__(16) short Ps[4][16*64];

    const int tid = threadIdx.x, lane = tid & 63, w = tid >> 6, g = lane >> 4;
    const int t0 = blockIdx.x * 64;
    const int bh = blockIdx.y;
    const size_t base = (size_t)bh * T_ * 64;

    #pragma unroll
    for (int is = 0; is < 2; is++) {
        int idx = is*256 + tid;
        int row = idx >> 3, sl = idx & 7;
        short8 v = *(const short8*)(kg + base + (size_t)(t0+row)*64 + sl*8);
        *(short8*)&Kt[row*64 + (sl ^ (row&7))*8] = v;
    }
    __syncthreads();

    bf16x8 akt[2];
    {
        int lt = w*16 + (lane & 15);
        #pragma unroll
        for (int c = 0; c < 2; c++)
            akt[c] = *(const bf16x8*)&Kt[lt*64 + ((c*4+g) ^ (lt&7))*8];
    }

    f32x4 o[4]; float m_run[4], l_run[4];
    #pragma unroll
    for (int i = 0; i < 4; i++) { o[i] = (f32x4){0,0,0,0}; m_run[i] = -1e30f; l_run[i] = 0.f; }

    const int qrow = tid >> 3, qsl = tid & 7;
    const int vd0 = (tid & 31) * 2;
    const int vsh = tid >> 5;

    short8 qv[2];
    unsigned vvr[8];

#define REGLOAD(s0_) do {                                                        \
    _Pragma("unroll")                                                            \
    for (int is_ = 0; is_ < 2; is_++)                                            \
        qv[is_] = *(const short8*)(qg + base + (size_t)((s0_) + qrow + is_*32)*64 + qsl*8); \
    _Pragma("unroll")                                                            \
    for (int i_ = 0; i_ < 8; i_++)                                               \
        vvr[i_] = *(const unsigned*)(vg + base + (size_t)((s0_) + vsh*8 + i_)*64 + vd0);    \
    } while(0)

    const int ntiles = (t0 >> 6) + 1;
    REGLOAD(0);

    for (int it = 0; it < ntiles; ++it) {
        __syncthreads();
        #pragma unroll
        for (int is = 0; is < 2; is++) {
            int row = qrow + is*32;
            *(short8*)&Qs[row*64 + (qsl ^ (row&7))*8] = qv[is];
        }
        #pragma unroll
        for (int dp = 0; dp < 2; dp++) {
            int d = vd0 + dp;
            short tmp[8];
            #pragma unroll
            for (int i = 0; i < 8; i++) tmp[i] = (short)((vvr[i] >> (dp*16)) & 0xffffu);
            *(short8*)&Vs[d*64 + (vsh ^ (d&7))*8] = *(short8*)tmp;
        }
        if (it + 1 < ntiles) REGLOAD((it+1)*64);
        __syncthreads();

        const int s0 = it*64;
        f32x4 s4[4];
        #pragma unroll
        for (int j = 0; j < 4; j++) s4[j] = (f32x4){0,0,0,0};
        #pragma unroll
        for (int c = 0; c < 2; c++) {
            #pragma unroll
            for (int j = 0; j < 4; j++) {
                int sr = j*16 + (lane & 15);
                bf16x8 bq = *(const bf16x8*)&Qs[sr*64 + ((c*4+g) ^ (sr&7))*8];
                s4[j] = __builtin_amdgcn_mfma_f32_16x16x32_bf16(akt[c], bq, s4[j], 0,0,0);
            }
        }
        float p[4][4];
        const bool diag = (it == ntiles-1);
        #pragma unroll
        for (int j = 0; j < 4; j++) {
          #pragma unroll
          for (int r = 0; r < 4; r++) {
            float v = s4[j][r] * SCALE_;
            if (diag) {
                int tglob = t0 + w*16 + g*4 + r;
                int sglob = s0 + j*16 + (lane & 15);
                if (sglob > tglob) v = -1e30f;
            }
            p[j][r] = v;
          }
        }
        #pragma unroll
        for (int r = 0; r < 4; r++) {
            float mx = fmaxf(fmaxf(p[0][r], p[1][r]), fmaxf(p[2][r], p[3][r]));
            #pragma unroll
            for (int off = 1; off < 16; off <<= 1) mx = fmaxf(mx, __shfl_xor(mx, off, 64));
            float mnew  = fmaxf(m_run[r], mx);
            float alpha = __expf(m_run[r] - mnew);
            float rs = 0.f;
            #pragma unroll
            for (int j = 0; j < 4; j++) { p[j][r] = __expf(p[j][r] - mnew); rs += p[j][r]; }
            #pragma unroll
            for (int off = 1; off < 16; off <<= 1) rs += __shfl_xor(rs, off, 64);
            l_run[r] = l_run[r]*alpha + rs;
            m_run[r] = mnew;
            #pragma unroll
            for (int ni = 0; ni < 4; ni++) o[ni][r] *= alpha;
        }
        #pragma unroll
        for (int j = 0; j < 4; j++) {
          #pragma unroll
          for (int r = 0; r < 4; r++) {
            int tl = g*4 + r, sc = j*16 + (lane & 15);
            Ps[w][tl*64 + ((sc>>3) ^ (tl&7))*8 + (sc&7)] = f2b(p[j][r]);
          }
        }
        asm volatile("s_waitcnt lgkmcnt(0)" ::: "memory");
        __builtin_amdgcn_sched_barrier(0);
        #pragma unroll
        for (int c = 0; c < 2; c++) {
            int tl = lane & 15;
            bf16x8 pa = *(const bf16x8*)&Ps[w][tl*64 + ((c*4+g) ^ (tl&7))*8];
            #pragma unroll
            for (int ni = 0; ni < 4; ni++) {
                int d = ni*16 + (lane & 15);
                bf16x8 bv = *(const bf16x8*)&Vs[d*64 + ((c*4+g) ^ (d&7))*8];
                o[ni] = __builtin_amdgcn_mfma_f32_16x16x32_bf16(pa, bv, o[ni], 0,0,0);
            }
        }
    }
#undef REGLOAD

    const int b = bh / H_, h = bh - b*H_;
    #pragma unroll
    for (int ni = 0; ni < 4; ni++) {
      #pragma unroll
      for (int r = 0; r < 4; r++) {
        int t = t0 + w*16 + g*4 + r;
        int d = ni*16 + (lane & 15);
        ao[((size_t)(b*T_ + t))*E_ + h*64 + d] = f2b(o[ni][r] / l_run[r]);
      }
    }
}

// ---------------- fallback GEMM (fp32 B on the fly) ----------------
template<int MODE, bool QKV3>
__global__ __launch_bounds__(256) void gemm2(
    const short* __restrict__ A,
    const float* __restrict__ Bq, const float* __restrict__ Bk2, const float* __restrict__ Bv2,
    const float* __restrict__ bias,
    float* __restrict__ X, short* __restrict__ Out, float* __restrict__ OutF,
    int M, int Ntot, int K, int lda, int kstride, int ldc)
{
    __shared__ __align__(16) short As[128*32];
    __shared__ __align__(16) short Bs[128*32];

    const int tid  = threadIdx.x;
    const int lane = tid & 63, wave = tid >> 6;
    const int wm = wave & 1, wn = wave >> 1;
    const int m0 = blockIdx.x * 128;
    const int n0 = blockIdx.y * 128;
    const int g  = lane >> 4;

    const float* Bm = Bq;
    int nsel = 0, c0 = n0;
    if (QKV3) {
        nsel = n0 / 768;
        c0 = n0 - nsel*768;
        Bm = (nsel == 0) ? Bq : (nsel == 1 ? Bk2 : Bv2);
    }

    f32x4 acc[4][4];
    #pragma unroll
    for (int i = 0; i < 4; i++)
        #pragma unroll
        for (int j = 0; j < 4; j++) acc[i][j] = (f32x4){0.f,0.f,0.f,0.f};

    const int bn  = tid & 127;
    const int bkh = tid >> 7;
    const int cg  = c0 + bn;
    const bool bvalid = QKV3 ? true : (cg < Ntot);
    size_t bbase;
    if (QKV3) bbase = (size_t)(cg >> 6) * ((size_t)E_*D_) + (cg & 63);
    else      bbase = (size_t)cg;

    for (int k0 = 0; k0 < K; k0 += 32) {
        #pragma unroll
        for (int is = 0; is < 2; is++) {
            int idx = is*256 + tid;
            int row = idx >> 2, sl = idx & 3;
            short8 v = *(const short8*)(A + (size_t)(m0+row)*lda + k0 + sl*8);
            int sl2 = sl ^ ((row ^ (row>>2)) & 3);
            *(short8*)&As[row*32 + sl2*8] = v;
        }
        {
            float bv[16];
            #pragma unroll
            for (int i = 0; i < 16; i++) {
                int k = k0 + bkh*16 + i;
                bv[i] = bvalid ? Bm[bbase + (size_t)k*kstride] : 0.f;
            }
            short bh16[16];
            #pragma unroll
            for (int i = 0; i < 16; i++) {
                __bf16 h = (__bf16)bv[i];
                bh16[i] = __builtin_bit_cast(short, h);
            }
            #pragma unroll
            for (int q = 0; q < 2; q++) {
                int kb  = bkh*2 + q;
                int sl2 = kb ^ ((bn ^ (bn>>2)) & 3);
                *(short8*)&Bs[bn*32 + sl2*8] = *(short8*)&bh16[q*8];
            }
        }
        __syncthreads();

        bf16x8 af[4];
        #pragma unroll
        for (int mi = 0; mi < 4; mi++) {
            int row = wm*64 + mi*16 + (lane & 15);
            int sl2 = g ^ ((row ^ (row>>2)) & 3);
            af[mi] = *(const bf16x8*)&As[row*32 + sl2*8];
        }
        #pragma unroll
        for (int ni = 0; ni < 4; ni++) {
            int nn  = wn*64 + ni*16 + (lane & 15);
            int sl2 = g ^ ((nn ^ (nn>>2)) & 3);
            bf16x8 bfr = *(const bf16x8*)&Bs[nn*32 + sl2*8];
            #pragma unroll
            for (int mi = 0; mi < 4; mi++)
                acc[mi][ni] = __builtin_amdgcn_mfma_f32_16x16x32_bf16(af[mi], bfr, acc[mi][ni], 0,0,0);
        }
        __syncthreads();
    }

    const int rb = g << 2;
    const int cb = lane & 15;
    #pragma unroll
    for (int mi = 0; mi < 4; mi++) {
      #pragma unroll
      for (int ni = 0; ni < 4; ni++) {
        #pragma unroll
        for (int j = 0; j < 4; j++) {
            int row = m0 + wm*64 + mi*16 + rb + j;
            int col = n0 + wn*64 + ni*16 + cb;
            float v = acc[mi][ni][j];
            if (MODE == 0) {
                if (col < Ntot) OutF[(size_t)row*ldc + col] = v + bias[col];
            } else if (MODE == 1) {
                v += bias[col];
                v = v > 0.f ? v : 0.f;
                Out[(size_t)row*ldc + col] = f2b(v);
            } else if (MODE == 2) {
                X[(size_t)row*E_ + col] += v + bias[col];
            } else {
                int c = col - nsel*768;
                int h = c >> 6, d = c & 63;
                int b = row >> 10, t = row & (T_-1);
                short* dst = Out + (size_t)nsel*((size_t)NTOK*E_);
                dst[(((size_t)(b*H_ + h)*T_ + t) << 6) + d] = f2b(v);
            }
        }
      }
    }
}

// ---------------- host launch ----------------
extern "C" void kernel_launch(void* const* d_in, const int* in_sizes, int n_in,
                              void* d_out, int out_size, void* d_ws, size_t ws_size,
                              hipStream_t stream)
{
    (void)in_sizes; (void)n_in; (void)out_size;

    const int*   idx     = (const int*)  d_in[0];
    const float* tok_emb = (const float*)d_in[1];
    const float* pos_emb = (const float*)d_in[2];
    const float* Wk      = (const float*)d_in[3];
    const float* Wq      = (const float*)d_in[4];
    const float* Wv      = (const float*)d_in[5];
    const float* Wproj   = (const float*)d_in[6];
    const float* bproj   = (const float*)d_in[7];
    const float* ln1_g   = (const float*)d_in[8];
    const float* ln1_b   = (const float*)d_in[9];
    const float* W1      = (const float*)d_in[10];
    const float* b1      = (const float*)d_in[11];
    const float* W2      = (const float*)d_in[12];
    const float* b2      = (const float*)d_in[13];
    const float* ln2_g   = (const float*)d_in[14];
    const float* ln2_b   = (const float*)d_in[15];
    const float* lnf_g   = (const float*)d_in[16];
    const float* lnf_b   = (const float*)d_in[17];
    const float* Wlm     = (const float*)d_in[18];
    const float* blm     = (const float*)d_in[19];
    float* out = (float*)d_out;

    char* w = (char*)d_ws;
    float* x    = (float*)w; w += (size_t)NTOK*E_*4;
    short* hbuf = (short*)w; w += (size_t)NTOK*E_*2;
    short* qb   = (short*)w; w += (size_t)NTOK*E_*2;
    short* kb   = (short*)w; w += (size_t)NTOK*E_*2;
    short* vb   = (short*)w; w += (size_t)NTOK*E_*2;
    short* aob  = (short*)w; w += (size_t)NTOK*E_*2;
    short* midb = (short*)w; w += (size_t)NTOK*FF_*2;

    const size_t act_bytes = (size_t)(w - (char*)d_ws);
    const size_t wqkv_n = (size_t)L_*2304*E_;
    const size_t wproj_n = (size_t)L_*E_*E_;
    const size_t wff_n = (size_t)L_*E_*FF_;
    const size_t wlm_n = (size_t)VPAD_*E_;
    const size_t need = act_bytes + 2*(wqkv_n + wproj_n + 2*wff_n + wlm_n);

    const size_t HED = (size_t)H_*E_*D_;
    dim3 gAT(T_/64, B_*H_);

    embed_kernel<<<NTOK, 256, 0, stream>>>(idx, tok_emb, pos_emb, x);

    if (ws_size >= need) {
        // ---------- fast path: prepack weights to bf16 (B^T layout) ----------
        short* qkvw = (short*)w; w += wqkv_n*2;
        short* projw= (short*)w; w += wproj_n*2;
        short* w1w  = (short*)w; w += wff_n*2;
        short* w2w  = (short*)w; w += wff_n*2;
        short* lmw  = (short*)w;

        pack_qkv<<<dim3(E_/64, 36, L_), 256, 0, stream>>>(Wq, Wk, Wv, qkvw);
        pack_t<<<dim3(E_/64, E_/64, L_), 256, 0, stream>>>(Wproj, projw, E_, E_, (size_t)E_*E_, (size_t)E_*E_);
        pack_t<<<dim3(E_/64, FF_/64, L_), 256, 0, stream>>>(W1, w1w, E_, FF_, (size_t)E_*FF_, (size_t)E_*FF_);
        pack_t<<<dim3(FF_/64, E_/64, L_), 256, 0, stream>>>(W2, w2w, FF_, E_, (size_t)E_*FF_, (size_t)E_*FF_);
        pack_t<<<dim3(E_/64, VPAD_/64, 1), 256, 0, stream>>>(Wlm, lmw, E_, V_, 0, 0);

        const int nQKV = 16*(2304/128), nF1 = 16*(FF_/128), nLM = 16*(VPAD_/128);
        const int nP = 16*(E_/128);    // 96 panels for N=768

        for (int l = 0; l < L_; l++) {
            ln_kernel<<<NTOK, 256, 0, stream>>>(x, ln1_g + (size_t)l*E_, ln1_b + (size_t)l*E_, hbuf);
            gemm3<3><<<nQKV, 256, 0, stream>>>(hbuf, qkvw + (size_t)l*2304*E_, nullptr,
                                               nullptr, qb, nullptr, E_, E_, 0, 2304, nQKV/8);
            attn2<<<gAT, 256, 0, stream>>>(qb, kb, vb, aob);
            gemm3_sk<2><<<nP*2, 256, 0, stream>>>(aob, projw + (size_t)l*E_*E_,
                                                  bproj + (size_t)l*E_, x, E_, E_);
            ln_kernel<<<NTOK, 256, 0, stream>>>(x, ln2_g + (size_t)l*E_, ln2_b + (size_t)l*E_, hbuf);
            gemm3<1><<<nF1, 256, 0, stream>>>(hbuf, w1w + (size_t)l*E_*FF_, b1 + (size_t)l*FF_,
                                              nullptr, midb, nullptr, E_, E_, FF_, FF_, nF1/8);
            gemm3_sk<4><<<nP*4, 256, 0, stream>>>(midb, w2w + (size_t)l*E_*FF_,
                                                  b2 + (size_t)l*E_, x, FF_, FF_);
        }
        ln_kernel<<<NTOK, 256, 0, stream>>>(x, lnf_g, lnf_b, hbuf);
        gemm3<0><<<nLM, 256, 0, stream>>>(hbuf, lmw, blm, nullptr, nullptr, out,
                                          E_, E_, V_, V_, nLM/8);
    } else {
        // ---------- fallback: round-3 path ----------
        dim3 gQKV(16, 18), gP(16, 6), gF1(16, 24), gLM(16, 393);
        for (int l = 0; l < L_; l++) {
            ln_kernel<<<NTOK, 256, 0, stream>>>(x, ln1_g + (size_t)l*E_, ln1_b + (size_t)l*E_, hbuf);
            gemm2<3,true><<<gQKV, 256, 0, stream>>>(hbuf,
                Wq + (size_t)l*HED, Wk + (size_t)l*HED, Wv + (size_t)l*HED,
                nullptr, nullptr, qb, nullptr, NTOK, 2304, E_, E_, 64, 0);
            attn2<<<gAT, 256, 0, stream>>>(qb, kb, vb, aob);
            gemm2<2,false><<<gP, 256, 0, stream>>>(aob,
                Wproj + (size_t)l*E_*E_, nullptr, nullptr, bproj + (size_t)l*E_,
                x, nullptr, nullptr, NTOK, E_, E_, E_, E_, 0);
            ln_kernel<<<NTOK, 256, 0, stream>>>(x, ln2_g + (size_t)l*E_, ln2_b + (size_t)l*E_, hbuf);
            gemm2<1,false><<<gF1, 256, 0, stream>>>(hbuf,
                W1 + (size_t)l*E_*FF_, nullptr, nullptr, b1 + (size_t)l*FF_,
                nullptr, midb, nullptr, NTOK, FF_, E_, E_, FF_, FF_);
            gemm2<2,false><<<gP, 256, 0, stream>>>(midb,
                W2 + (size_t)l*FF_*E_, nullptr, nullptr, b2 + (size_t)l*E_,
                x, nullptr, nullptr, NTOK, E_, FF_, FF_, E_, 0);
        }
        ln_kernel<<<NTOK, 256, 0, stream>>>(x, lnf_g, lnf_b, hbuf);
        gemm2<0,false><<<gLM, 256, 0, stream>>>(hbuf,
            Wlm, nullptr, nullptr, blm,
            nullptr, nullptr, out, NTOK, V_, E_, E_, V_, V_);
    }
}

// Round 9
// 1932.063 us; speedup vs baseline: 9.4437x; 1.2746x over previous
//
#include <hip/hip_runtime.h>
#include <hip/hip_bf16.h>
#include <stdint.h>

#define B_    2
#define T_    1024
#define V_    50257
#define VPAD_ 50304
#define E_    768
#define H_    12
#define L_    12
#define D_    64
#define FF_   3072
#define NTOK  (B_*T_)          // 2048
#define SCALE_ (1.0f/((float)E_*(float)E_))

typedef float f32x4 __attribute__((ext_vector_type(4)));
typedef __bf16 bf16x8 __attribute__((ext_vector_type(8)));
typedef short short8 __attribute__((ext_vector_type(8)));

__device__ __forceinline__ float bits2f(short s) {
    unsigned u = ((unsigned)(unsigned short)s) << 16;
    float f; __builtin_memcpy(&f, &u, 4); return f;
}
__device__ __forceinline__ short f2b(float f) {
    unsigned u; __builtin_memcpy(&u, &f, 4);
    unsigned r = (u + 0x7FFFu + ((u >> 16) & 1u)) >> 16;   // RNE
    return (short)r;
}

#define GLOAD16(gsrc, ldst) __builtin_amdgcn_global_load_lds( \
    (const __attribute__((address_space(1))) unsigned*)(gsrc), \
    (__attribute__((address_space(3))) unsigned*)(ldst), 16, 0, 0)

// ---------------- embedding ----------------
__global__ __launch_bounds__(256) void embed_kernel(
    const int* __restrict__ idx, const float* __restrict__ tok,
    const float* __restrict__ pos, float* __restrict__ x)
{
    int m = blockIdx.x, tid = threadIdx.x;
    int row = idx[m];
    int t = m & (T_-1);
    #pragma unroll
    for (int i = 0; i < 3; i++) {
        int e = tid + i*256;
        x[(size_t)m*E_ + e] = tok[(size_t)row*E_ + e] + pos[(size_t)t*E_ + e];
    }
}

// ---------------- layernorm helpers ----------------
__device__ __forceinline__ float block_sum256(float v, float* red) {
    #pragma unroll
    for (int off = 32; off; off >>= 1) v += __shfl_xor(v, off, 64);
    int w = threadIdx.x >> 6;
    __syncthreads();
    if ((threadIdx.x & 63) == 0) red[w] = v;
    __syncthreads();
    return red[0] + red[1] + red[2] + red[3];
}

// plain LN (fallback path)
__global__ __launch_bounds__(256) void ln_kernel(
    const float* __restrict__ x, const float* __restrict__ g,
    const float* __restrict__ bb, short* __restrict__ out)
{
    __shared__ float red[4];
    int m = blockIdx.x, tid = threadIdx.x;
    const float* xr = x + (size_t)m*E_;
    float loc[3]; float s = 0.f;
    #pragma unroll
    for (int i = 0; i < 3; i++) { loc[i] = xr[tid + i*256]; s += loc[i]; }
    s = block_sum256(s, red);
    float mean = s * (1.0f/E_);
    float vs = 0.f;
    #pragma unroll
    for (int i = 0; i < 3; i++) { float d = loc[i] - mean; vs += d*d; }
    vs = block_sum256(vs, red);
    float rstd = rsqrtf(vs * (1.0f/E_) + 1e-5f);
    #pragma unroll
    for (int i = 0; i < 3; i++) {
        int e = tid + i*256;
        out[(size_t)m*E_ + e] = f2b((loc[i] - mean) * rstd * g[e] + bb[e]);
    }
}

// fused residual-reduce (+bias) + LN.  NS = number of split-K partial slices (0 = none).
// x[m] += sum_sp pb[sp][m] + bias; then out = LN(x[m])*g + b; x written back.
template<int NS>
__global__ __launch_bounds__(256) void ln_red(
    float* __restrict__ x, const float* __restrict__ pb,
    const float* __restrict__ bias,
    const float* __restrict__ g, const float* __restrict__ bb,
    short* __restrict__ out)
{
    __shared__ float red[4];
    int m = blockIdx.x, tid = threadIdx.x;
    float* xr = x + (size_t)m*E_;
    float loc[3]; float s = 0.f;
    #pragma unroll
    for (int i = 0; i < 3; i++) {
        int e = tid + i*256;
        float v = xr[e];
        if (NS > 0) {
            #pragma unroll
            for (int sp = 0; sp < NS; sp++)
                v += pb[((size_t)sp*NTOK + m)*E_ + e];
            v += bias[e];
            xr[e] = v;
        }
        loc[i] = v; s += v;
    }
    s = block_sum256(s, red);
    float mean = s * (1.0f/E_);
    float vs = 0.f;
    #pragma unroll
    for (int i = 0; i < 3; i++) { float d = loc[i] - mean; vs += d*d; }
    vs = block_sum256(vs, red);
    float rstd = rsqrtf(vs * (1.0f/E_) + 1e-5f);
    #pragma unroll
    for (int i = 0; i < 3; i++) {
        int e = tid + i*256;
        out[(size_t)m*E_ + e] = f2b((loc[i] - mean) * rstd * g[e] + bb[e]);
    }
}

// ---------------- weight packing (vectorized) ----------------
__global__ __launch_bounds__(256) void pack_t(
    const float* __restrict__ src, short* __restrict__ dst,
    int srcK, int srcN, size_t sstride, size_t dstride)
{
    __shared__ float tile[64][65];
    int k0 = blockIdx.x*64, n0 = blockIdx.y*64, l = blockIdx.z;
    const float* s = src + (size_t)l*sstride;
    short* d = dst + (size_t)l*dstride;
    int tid = threadIdx.x;
    const bool vec = (srcN & 3) == 0;
    #pragma unroll
    for (int i = 0; i < 4; i++) {
        int r = (tid >> 4) + i*16;
        int c = (tid & 15) * 4;
        const float* sp = s + (size_t)(k0+r)*srcN + n0 + c;
        if (vec) {
            f32x4 v = *(const f32x4*)sp;
            tile[r][c+0] = v.x; tile[r][c+1] = v.y; tile[r][c+2] = v.z; tile[r][c+3] = v.w;
        } else {
            #pragma unroll
            for (int j = 0; j < 4; j++)
                tile[r][c+j] = (n0 + c + j < srcN) ? sp[j] : 0.f;
        }
    }
    __syncthreads();
    #pragma unroll
    for (int i = 0; i < 2; i++) {
        int r2  = (tid >> 3) + i*32;
        int grp = tid & 7;
        short8 o;
        #pragma unroll
        for (int j = 0; j < 8; j++) o[j] = f2b(tile[grp*8 + j][r2]);
        *(short8*)(d + (size_t)(n0+r2)*srcK + k0 + grp*8) = o;
    }
}

__global__ __launch_bounds__(256) void pack_qkv(
    const float* __restrict__ Wq, const float* __restrict__ Wk,
    const float* __restrict__ Wv, short* __restrict__ dst)
{
    __shared__ float tile[64][65];
    int e0 = blockIdx.x*64;
    int y = blockIdx.y, sel = y/12, h = y - sel*12;
    int l = blockIdx.z;
    const float* s = (sel == 0 ? Wq : (sel == 1 ? Wk : Wv)) + (((size_t)l*H_ + h)*E_)*D_;
    int tid = threadIdx.x;
    #pragma unroll
    for (int i = 0; i < 4; i++) {
        int r = (tid >> 4) + i*16;
        int c = (tid & 15) * 4;
        f32x4 v = *(const f32x4*)(s + (size_t)(e0+r)*D_ + c);
        tile[r][c+0] = v.x; tile[r][c+1] = v.y; tile[r][c+2] = v.z; tile[r][c+3] = v.w;
    }
    __syncthreads();
    short* d_ = dst + (size_t)l*2304*E_;
    #pragma unroll
    for (int i = 0; i < 2; i++) {
        int r2  = (tid >> 3) + i*32;
        int grp = tid & 7;
        short8 o;
        #pragma unroll
        for (int j = 0; j < 8; j++) o[j] = f2b(tile[grp*8 + j][r2]);
        *(short8*)(d_ + (size_t)(sel*768 + h*64 + r2)*E_ + e0 + grp*8) = o;
    }
}

// ---------------- fast bf16 GEMM: 3-buffer, counted-vmcnt pipeline (T4) ----------------
// MODE 0: OutF = acc + bias (col < Nreal);  MODE 1: relu->bf16;  MODE 3: qkv scatter
template<int MODE>
__global__ __launch_bounds__(256) void gemm3(
    const short* __restrict__ A, const short* __restrict__ Bt,
    const float* __restrict__ bias,
    float* __restrict__ X, short* __restrict__ Out, float* __restrict__ OutF,
    int K, int lda, int ldc, int Nreal, int cpx)
{
    __shared__ __align__(16) short As[3][128*32];
    __shared__ __align__(16) short Bs[3][128*32];

    const int tid  = threadIdx.x;
    const int lane = tid & 63, wv = tid >> 6;
    const int wm = wv & 1, wn = wv >> 1;

    int bid = blockIdx.x;
    int g   = (bid & 7)*cpx + (bid >> 3);
    const int m0 = (g & 15) * 128;
    const int n0 = (g >> 4) * 128;

    f32x4 acc[4][4];
    #pragma unroll
    for (int i = 0; i < 4; i++)
        #pragma unroll
        for (int j = 0; j < 4; j++) acc[i][j] = (f32x4){0.f,0.f,0.f,0.f};

    const int srow0 = wv*32 + (lane >> 2);
    const int ssl   = lane & 3;

#define STAGE3(buf, kk) do {                                                  \
    _Pragma("unroll")                                                         \
    for (int i_ = 0; i_ < 2; i_++) {                                          \
        int row_ = srow0 + i_*16;                                             \
        GLOAD16(A  + (size_t)(m0 + row_)*lda + (kk) + ssl*8,                  \
                &As[buf][(wv*128 + i_*64)*8]);                                \
        GLOAD16(Bt + (size_t)(n0 + row_)*K   + (kk) + ssl*8,                  \
                &Bs[buf][(wv*128 + i_*64)*8]);                                \
    } } while(0)

    const int nt = K >> 5;                 // always >= 2 here
    STAGE3(0, 0);
    if (nt > 1) STAGE3(1, 32);

    int cur = 0, nxt2 = 2;
    for (int kt = 0; kt < nt; ++kt) {
        if (kt + 1 < nt) asm volatile("s_waitcnt vmcnt(4)" ::: "memory");
        else             asm volatile("s_waitcnt vmcnt(0)" ::: "memory");
        __builtin_amdgcn_s_barrier();

        bf16x8 af[4], bf[4];
        #pragma unroll
        for (int mi = 0; mi < 4; mi++) {
            int row = wm*64 + mi*16 + (lane & 15);
            af[mi] = *(const bf16x8*)&As[cur][row*32 + (lane >> 4)*8];
        }
        #pragma unroll
        for (int ni = 0; ni < 4; ni++) {
            int col = wn*64 + ni*16 + (lane & 15);
            bf[ni] = *(const bf16x8*)&Bs[cur][col*32 + (lane >> 4)*8];
        }
        if (kt + 2 < nt) STAGE3(nxt2, (kt + 2) << 5);

        #pragma unroll
        for (int ni = 0; ni < 4; ni++)
            #pragma unroll
            for (int mi = 0; mi < 4; mi++)
                acc[mi][ni] = __builtin_amdgcn_mfma_f32_16x16x32_bf16(af[mi], bf[ni], acc[mi][ni], 0,0,0);

        cur  = (cur  == 2) ? 0 : cur + 1;
        nxt2 = (nxt2 == 2) ? 0 : nxt2 + 1;
    }
#undef STAGE3

    const int rb = (lane >> 4) << 2;
    const int cb = lane & 15;
    #pragma unroll
    for (int mi = 0; mi < 4; mi++) {
      #pragma unroll
      for (int ni = 0; ni < 4; ni++) {
        #pragma unroll
        for (int j = 0; j < 4; j++) {
            int row = m0 + wm*64 + mi*16 + rb + j;
            int col = n0 + wn*64 + ni*16 + cb;
            float v = acc[mi][ni][j];
            if (MODE == 0) {
                if (col < Nreal) OutF[(size_t)row*ldc + col] = v + bias[col];
            } else if (MODE == 1) {
                v += bias[col];
                v = v > 0.f ? v : 0.f;
                Out[(size_t)row*ldc + col] = f2b(v);
            } else {
                int nsel = col / 768;
                int c = col - nsel*768;
                int h = c >> 6, d = c & 63;
                int b = row >> 10, t = row & (T_-1);
                short* dst = Out + (size_t)nsel*((size_t)NTOK*E_);
                dst[(((size_t)(b*H_ + h)*T_ + t) << 6) + d] = f2b(v);
            }
        }
      }
    }
}

// ---------------- split-K GEMM (3-buffer counted-vmcnt) ----------------
// ATOMIC=true: bias(sp0)+atomicAdd into X.  ATOMIC=false: plain stores into PB[sp] (no bias).
template<int SPLITS, bool ATOMIC>
__global__ __launch_bounds__(256) void gemm3_sk(
    const short* __restrict__ A, const short* __restrict__ Bt,
    const float* __restrict__ bias, float* __restrict__ X, float* __restrict__ PB,
    int K, int lda)
{
    __shared__ __align__(16) short As[3][128*32];
    __shared__ __align__(16) short Bs[3][128*32];

    const int tid  = threadIdx.x;
    const int lane = tid & 63, wv = tid >> 6;
    const int wm = wv & 1, wn = wv >> 1;

    const int panel = blockIdx.x / SPLITS;
    const int sp    = blockIdx.x % SPLITS;
    const int m0 = (panel & 15) * 128;
    const int n0 = (panel >> 4) * 128;
    const int Ks = K / SPLITS;
    const int kbeg = sp * Ks;

    f32x4 acc[4][4];
    #pragma unroll
    for (int i = 0; i < 4; i++)
        #pragma unroll
        for (int j = 0; j < 4; j++) acc[i][j] = (f32x4){0.f,0.f,0.f,0.f};

    const int srow0 = wv*32 + (lane >> 2);
    const int ssl   = lane & 3;

#define STAGESK(buf, kk) do {                                                 \
    _Pragma("unroll")                                                         \
    for (int i_ = 0; i_ < 2; i_++) {                                          \
        int row_ = srow0 + i_*16;                                             \
        GLOAD16(A  + (size_t)(m0 + row_)*lda + (kk) + ssl*8,                  \
                &As[buf][(wv*128 + i_*64)*8]);                                \
        GLOAD16(Bt + (size_t)(n0 + row_)*K   + (kk) + ssl*8,                  \
                &Bs[buf][(wv*128 + i_*64)*8]);                                \
    } } while(0)

    const int nt = Ks >> 5;
    STAGESK(0, kbeg);
    if (nt > 1) STAGESK(1, kbeg + 32);

    int cur = 0, nxt2 = 2;
    for (int kt = 0; kt < nt; ++kt) {
        if (kt + 1 < nt) asm volatile("s_waitcnt vmcnt(4)" ::: "memory");
        else             asm volatile("s_waitcnt vmcnt(0)" ::: "memory");
        __builtin_amdgcn_s_barrier();

        bf16x8 af[4], bf[4];
        #pragma unroll
        for (int mi = 0; mi < 4; mi++) {
            int row = wm*64 + mi*16 + (lane & 15);
            af[mi] = *(const bf16x8*)&As[cur][row*32 + (lane >> 4)*8];
        }
        #pragma unroll
        for (int ni = 0; ni < 4; ni++) {
            int col = wn*64 + ni*16 + (lane & 15);
            bf[ni] = *(const bf16x8*)&Bs[cur][col*32 + (lane >> 4)*8];
        }
        if (kt + 2 < nt) STAGESK(nxt2, kbeg + ((kt + 2) << 5));

        #pragma unroll
        for (int ni = 0; ni < 4; ni++)
            #pragma unroll
            for (int mi = 0; mi < 4; mi++)
                acc[mi][ni] = __builtin_amdgcn_mfma_f32_16x16x32_bf16(af[mi], bf[ni], acc[mi][ni], 0,0,0);

        cur  = (cur  == 2) ? 0 : cur + 1;
        nxt2 = (nxt2 == 2) ? 0 : nxt2 + 1;
    }
#undef STAGESK

    const int rb = (lane >> 4) << 2;
    const int cb = lane & 15;
    #pragma unroll
    for (int mi = 0; mi < 4; mi++) {
      #pragma unroll
      for (int ni = 0; ni < 4; ni++) {
        #pragma unroll
        for (int j = 0; j < 4; j++) {
            int row = m0 + wm*64 + mi*16 + rb + j;
            int col = n0 + wn*64 + ni*16 + cb;
            float v = acc[mi][ni][j];
            if (ATOMIC) {
                if (sp == 0) v += bias[col];
                atomicAdd(&X[(size_t)row*E_ + col], v);
            } else {
                PB[((size_t)sp*NTOK + row)*E_ + col] = v;
            }
        }
      }
    }
}

// ---------------- flash attention (faithful swap: "Q"=k-proj, "K"=q-proj) ----------------
__global__ __launch_bounds__(256) void attn2(
    const short* __restrict__ qg, const short* __restrict__ kg,
    const short* __restrict__ vg, short* __restrict__ ao)
{
    __shared__ __align__(16) short Kt[64*64];
    __shared__ __align__(16) short Qs[64*64];
    __shared__ __align__(16) short Vs[64*64];
    __shared__ __align__(16) short Ps[4][16*64];

    const int tid = threadIdx.x, lane = tid & 63, w = tid >> 6, g = lane >> 4;
    const int t0 = blockIdx.x * 64;
    const int bh = blockIdx.y;
    const size_t base = (size_t)bh * T_ * 64;

    #pragma unroll
    for (int is = 0; is < 2; is++) {
        int idx = is*256 + tid;
        int row = idx >> 3, sl = idx & 7;
        short8 v = *(const short8*)(kg + base + (size_t)(t0+row)*64 + sl*8);
        *(short8*)&Kt[row*64 + (sl ^ (row&7))*8] = v;
    }
    __syncthreads();

    bf16x8 akt[2];
    {
        int lt = w*16 + (lane & 15);
        #pragma unroll
        for (int c = 0; c < 2; c++)
            akt[c] = *(const bf16x8*)&Kt[lt*64 + ((c*4+g) ^ (lt&7))*8];
    }

    f32x4 o[4]; float m_run[4], l_run[4];
    #pragma unroll
    for (int i = 0; i < 4; i++) { o[i] = (f32x4){0,0,0,0}; m_run[i] = -1e30f; l_run[i] = 0.f; }

    const int qrow = tid >> 3, qsl = tid & 7;
    const int vd0 = (tid & 31) * 2;
    const int vsh = tid >> 5;

    short8 qv[2];
    unsigned vvr[8];

#define REGLOAD(s0_) do {                                                        \
    _Pragma("unroll")                                                            \
    for (int is_ = 0; is_ < 2; is_++)                                            \
        qv[is_] = *(const short8*)(qg + base + (size_t)((s0_) + qrow + is_*32)*64 + qsl*8); \
    _Pragma("unroll")                                                            \
    for (int i_ = 0; i_ < 8; i_++)                                               \
        vvr[i_] = *(const unsigned*)(vg + base + (size_t)((s0_) + vsh*8 + i_)*64 + vd0);    \
    } while(0)

    const int ntiles = (t0 >> 6) + 1;
    REGLOAD(0);

    for (int it = 0; it < ntiles; ++it) {
        __syncthreads();
        #pragma unroll
        for (int is = 0; is < 2; is++) {
            int row = qrow + is*32;
            *(short8*)&Qs[row*64 + (qsl ^ (row&7))*8] = qv[is];
        }
        #pragma unroll
        for (int dp = 0; dp < 2; dp++) {
            int d = vd0 + dp;
            short tmp[8];
            #pragma unroll
            for (int i = 0; i < 8; i++) tmp[i] = (short)((vvr[i] >> (dp*16)) & 0xffffu);
            *(short8*)&Vs[d*64 + (vsh ^ (d&7))*8] = *(short8*)tmp;
        }
        if (it + 1 < ntiles) REGLOAD((it+1)*64);
        __syncthreads();

        const int s0 = it*64;
        f32x4 s4[4];
        #pragma unroll
        for (int j = 0; j < 4; j++) s4[j] = (f32x4){0,0,0,0};
        #pragma unroll
        for (int c = 0; c < 2; c++) {
            #pragma unroll
            for (int j = 0; j < 4; j++) {
                int sr = j*16 + (lane & 15);
                bf16x8 bq = *(const bf16x8*)&Qs[sr*64 + ((c*4+g) ^ (sr&7))*8];
                s4[j] = __builtin_amdgcn_mfma_f32_16x16x32_bf16(akt[c], bq, s4[j], 0,0,0);
            }
        }
        float p[4][4];
        const bool diag = (it == ntiles-1);
        #pragma unroll
        for (int j = 0; j < 4; j++) {
          #pragma unroll
          for (int r = 0; r < 4; r++) {
            float v = s4[j][r] * SCALE_;
            if (diag) {
                int tglob = t0 + w*16 + g*4 + r;
                int sglob = s0 + j*16 + (lane & 15);
                if (sglob > tglob) v = -1e30f;
            }
            p[j][r] = v;
          }
        }
        #pragma unroll
        for (int r = 0; r < 4; r++) {
            float mx = fmaxf(fmaxf(p[0][r], p[1][r]), fmaxf(p[2][r], p[3][r]));
            #pragma unroll
            for (int off = 1; off < 16; off <<= 1) mx = fmaxf(mx, __shfl_xor(mx, off, 64));
            float mnew  = fmaxf(m_run[r], mx);
            float alpha = __expf(m_run[r] - mnew);
            float rs = 0.f;
            #pragma unroll
            for (int j = 0; j < 4; j++) { p[j][r] = __expf(p[j][r] - mnew); rs += p[j][r]; }
            #pragma unroll
            for (int off = 1; off < 16; off <<= 1) rs += __shfl_xor(rs, off, 64);
            l_run[r] = l_run[r]*alpha + rs;
            m_run[r] = mnew;
            #pragma unroll
            for (int ni = 0; ni < 4; ni++) o[ni][r] *= alpha;
        }
        #pragma unroll
        for (int j = 0; j < 4; j++) {
          #pragma unroll
          for (int r = 0; r < 4; r++) {
            int tl = g*4 + r, sc = j*16 + (lane & 15);
            Ps[w][tl*64 + ((sc>>3) ^ (tl&7))*8 + (sc&7)] = f2b(p[j][r]);
          }
        }
        asm volatile("s_waitcnt lgkmcnt(0)" ::: "memory");
        __builtin_amdgcn_sched_barrier(0);
        #pragma unroll
        for (int c = 0; c < 2; c++) {
            int tl = lane & 15;
            bf16x8 pa = *(const bf16x8*)&Ps[w][tl*64 + ((c*4+g) ^ (tl&7))*8];
            #pragma unroll
            for (int ni = 0; ni < 4; ni++) {
                int d = ni*16 + (lane & 15);
                bf16x8 bv = *(const bf16x8*)&Vs[d*64 + ((c*4+g) ^ (d&7))*8];
                o[ni] = __builtin_amdgcn_mfma_f32_16x16x32_bf16(pa, bv, o[ni], 0,0,0);
            }
        }
    }
#undef REGLOAD

    const int b = bh / H_, h = bh - b*H_;
    #pragma unroll
    for (int ni = 0; ni < 4; ni++) {
      #pragma unroll
      for (int r = 0; r < 4; r++) {
        int t = t0 + w*16 + g*4 + r;
        int d = ni*16 + (lane & 15);
        ao[((size_t)(b*T_ + t))*E_ + h*64 + d] = f2b(o[ni][r] / l_run[r]);
      }
    }
}

// ---------------- fallback GEMM (fp32 B on the fly) ----------------
template<int MODE, bool QKV3>
__global__ __launch_bounds__(256) void gemm2(
    const short* __restrict__ A,
    const float* __restrict__ Bq, const float* __restrict__ Bk2, const float* __restrict__ Bv2,
    const float* __restrict__ bias,
    float* __restrict__ X, short* __restrict__ Out, float* __restrict__ OutF,
    int M, int Ntot, int K, int lda, int kstride, int ldc)
{
    __shared__ __align__(16) short As[128*32];
    __shared__ __align__(16) short Bs[128*32];

    const int tid  = threadIdx.x;
    const int lane = tid & 63, wave = tid >> 6;
    const int wm = wave & 1, wn = wave >> 1;
    const int m0 = blockIdx.x * 128;
    const int n0 = blockIdx.y * 128;
    const int g  = lane >> 4;

    const float* Bm = Bq;
    int nsel = 0, c0 = n0;
    if (QKV3) {
        nsel = n0 / 768;
        c0 = n0 - nsel*768;
        Bm = (nsel == 0) ? Bq : (nsel == 1 ? Bk2 : Bv2);
    }

    f32x4 acc[4][4];
    #pragma unroll
    for (int i = 0; i < 4; i++)
        #pragma unroll
        for (int j = 0; j < 4; j++) acc[i][j] = (f32x4){0.f,0.f,0.f,0.f};

    const int bn  = tid & 127;
    const int bkh = tid >> 7;
    const int cg  = c0 + bn;
    const bool bvalid = QKV3 ? true : (cg < Ntot);
    size_t bbase;
    if (QKV3) bbase = (size_t)(cg >> 6) * ((size_t)E_*D_) + (cg & 63);
    else      bbase = (size_t)cg;

    for (int k0 = 0; k0 < K; k0 += 32) {
        #pragma unroll
        for (int is = 0; is < 2; is++) {
            int idx = is*256 + tid;
            int row = idx >> 2, sl = idx & 3;
            short8 v = *(const short8*)(A + (size_t)(m0+row)*lda + k0 + sl*8);
            int sl2 = sl ^ ((row ^ (row>>2)) & 3);
            *(short8*)&As[row*32 + sl2*8] = v;
        }
        {
            float bv[16];
            #pragma unroll
            for (int i = 0; i < 16; i++) {
                int k = k0 + bkh*16 + i;
                bv[i] = bvalid ? Bm[bbase + (size_t)k*kstride] : 0.f;
            }
            short bh16[16];
            #pragma unroll
            for (int i = 0; i < 16; i++) {
                __bf16 h = (__bf16)bv[i];
                bh16[i] = __builtin_bit_cast(short, h);
            }
            #pragma unroll
            for (int q = 0; q < 2; q++) {
                int kb  = bkh*2 + q;
                int sl2 = kb ^ ((bn ^ (bn>>2)) & 3);
                *(short8*)&Bs[bn*32 + sl2*8] = *(short8*)&bh16[q*8];
            }
        }
        __syncthreads();

        bf16x8 af[4];
        #pragma unroll
        for (int mi = 0; mi < 4; mi++) {
            int row = wm*64 + mi*16 + (lane & 15);
            int sl2 = g ^ ((row ^ (row>>2)) & 3);
            af[mi] = *(const bf16x8*)&As[row*32 + sl2*8];
        }
        #pragma unroll
        for (int ni = 0; ni < 4; ni++) {
            int nn  = wn*64 + ni*16 + (lane & 15);
            int sl2 = g ^ ((nn ^ (nn>>2)) & 3);
            bf16x8 bfr = *(const bf16x8*)&Bs[nn*32 + sl2*8];
            #pragma unroll
            for (int mi = 0; mi < 4; mi++)
                acc[mi][ni] = __builtin_amdgcn_mfma_f32_16x16x32_bf16(af[mi], bfr, acc[mi][ni], 0,0,0);
        }
        __syncthreads();
    }

    const int rb = g << 2;
    const int cb = lane & 15;
    #pragma unroll
    for (int mi = 0; mi < 4; mi++) {
      #pragma unroll
      for (int ni = 0; ni < 4; ni++) {
        #pragma unroll
        for (int j = 0; j < 4; j++) {
            int row = m0 + wm*64 + mi*16 + rb + j;
            int col = n0 + wn*64 + ni*16 + cb;
            float v = acc[mi][ni][j];
            if (MODE == 0) {
                if (col < Ntot) OutF[(size_t)row*ldc + col] = v + bias[col];
            } else if (MODE == 1) {
                v += bias[col];
                v = v > 0.f ? v : 0.f;
                Out[(size_t)row*ldc + col] = f2b(v);
            } else if (MODE == 2) {
                X[(size_t)row*E_ + col] += v + bias[col];
            } else {
                int c = col - nsel*768;
                int h = c >> 6, d = c & 63;
                int b = row >> 10, t = row & (T_-1);
                short* dst = Out + (size_t)nsel*((size_t)NTOK*E_);
                dst[(((size_t)(b*H_ + h)*T_ + t) << 6) + d] = f2b(v);
            }
        }
      }
    }
}

// ---------------- host launch ----------------
extern "C" void kernel_launch(void* const* d_in, const int* in_sizes, int n_in,
                              void* d_out, int out_size, void* d_ws, size_t ws_size,
                              hipStream_t stream)
{
    (void)in_sizes; (void)n_in; (void)out_size;

    const int*   idx     = (const int*)  d_in[0];
    const float* tok_emb = (const float*)d_in[1];
    const float* pos_emb = (const float*)d_in[2];
    const float* Wk      = (const float*)d_in[3];
    const float* Wq      = (const float*)d_in[4];
    const float* Wv      = (const float*)d_in[5];
    const float* Wproj   = (const float*)d_in[6];
    const float* bproj   = (const float*)d_in[7];
    const float* ln1_g   = (const float*)d_in[8];
    const float* ln1_b   = (const float*)d_in[9];
    const float* W1      = (const float*)d_in[10];
    const float* b1      = (const float*)d_in[11];
    const float* W2      = (const float*)d_in[12];
    const float* b2      = (const float*)d_in[13];
    const float* ln2_g   = (const float*)d_in[14];
    const float* ln2_b   = (const float*)d_in[15];
    const float* lnf_g   = (const float*)d_in[16];
    const float* lnf_b   = (const float*)d_in[17];
    const float* Wlm     = (const float*)d_in[18];
    const float* blm     = (const float*)d_in[19];
    float* out = (float*)d_out;

    char* w = (char*)d_ws;
    float* x    = (float*)w; w += (size_t)NTOK*E_*4;
    short* hbuf = (short*)w; w += (size_t)NTOK*E_*2;
    short* qb   = (short*)w; w += (size_t)NTOK*E_*2;
    short* kb   = (short*)w; w += (size_t)NTOK*E_*2;
    short* vb   = (short*)w; w += (size_t)NTOK*E_*2;
    short* aob  = (short*)w; w += (size_t)NTOK*E_*2;
    short* midb = (short*)w; w += (size_t)NTOK*FF_*2;
    float* pbuf = (float*)w; w += (size_t)4*NTOK*E_*4;   // split-K partials (4 slices max)

    const size_t act_bytes = (size_t)(w - (char*)d_ws);
    const size_t wqkv_n = (size_t)L_*2304*E_;
    const size_t wproj_n = (size_t)L_*E_*E_;
    const size_t wff_n = (size_t)L_*E_*FF_;
    const size_t wlm_n = (size_t)VPAD_*E_;
    const size_t need = act_bytes + 2*(wqkv_n + wproj_n + 2*wff_n + wlm_n);

    const size_t HED = (size_t)H_*E_*D_;
    dim3 gAT(T_/64, B_*H_);

    embed_kernel<<<NTOK, 256, 0, stream>>>(idx, tok_emb, pos_emb, x);

    if (ws_size >= need) {
        // ---------- fast path: prepack weights to bf16 (B^T layout) ----------
        short* qkvw = (short*)w; w += wqkv_n*2;
        short* projw= (short*)w; w += wproj_n*2;
        short* w1w  = (short*)w; w += wff_n*2;
        short* w2w  = (short*)w; w += wff_n*2;
        short* lmw  = (short*)w;

        pack_qkv<<<dim3(E_/64, 36, L_), 256, 0, stream>>>(Wq, Wk, Wv, qkvw);
        pack_t<<<dim3(E_/64, E_/64, L_), 256, 0, stream>>>(Wproj, projw, E_, E_, (size_t)E_*E_, (size_t)E_*E_);
        pack_t<<<dim3(E_/64, FF_/64, L_), 256, 0, stream>>>(W1, w1w, E_, FF_, (size_t)E_*FF_, (size_t)E_*FF_);
        pack_t<<<dim3(FF_/64, E_/64, L_), 256, 0, stream>>>(W2, w2w, FF_, E_, (size_t)E_*FF_, (size_t)E_*FF_);
        pack_t<<<dim3(E_/64, VPAD_/64, 1), 256, 0, stream>>>(Wlm, lmw, E_, V_, 0, 0);

        const int nQKV = 16*(2304/128), nF1 = 16*(FF_/128), nLM = 16*(VPAD_/128);
        const int nP = 16*(E_/128);    // 96 panels for N=768

        for (int l = 0; l < L_; l++) {
            // ln1: absorbs previous layer's FFN2 partials (4 slices)
            if (l == 0)
                ln_red<0><<<NTOK, 256, 0, stream>>>(x, nullptr, nullptr,
                    ln1_g + (size_t)l*E_, ln1_b + (size_t)l*E_, hbuf);
            else
                ln_red<4><<<NTOK, 256, 0, stream>>>(x, pbuf, b2 + (size_t)(l-1)*E_,
                    ln1_g + (size_t)l*E_, ln1_b + (size_t)l*E_, hbuf);

            gemm3<3><<<nQKV, 256, 0, stream>>>(hbuf, qkvw + (size_t)l*2304*E_, nullptr,
                                               nullptr, qb, nullptr, E_, E_, 0, 2304, nQKV/8);
            attn2<<<gAT, 256, 0, stream>>>(qb, kb, vb, aob);

            gemm3_sk<2,false><<<nP*2, 256, 0, stream>>>(aob, projw + (size_t)l*E_*E_,
                                                        nullptr, nullptr, pbuf, E_, E_);
            // ln2: absorbs proj partials (2 slices)
            ln_red<2><<<NTOK, 256, 0, stream>>>(x, pbuf, bproj + (size_t)l*E_,
                ln2_g + (size_t)l*E_, ln2_b + (size_t)l*E_, hbuf);

            gemm3<1><<<nF1, 256, 0, stream>>>(hbuf, w1w + (size_t)l*E_*FF_, b1 + (size_t)l*FF_,
                                              nullptr, midb, nullptr, E_, E_, FF_, FF_, nF1/8);
            gemm3_sk<4,false><<<nP*4, 256, 0, stream>>>(midb, w2w + (size_t)l*E_*FF_,
                                                        nullptr, nullptr, pbuf, FF_, FF_);
        }
        // lnf: absorbs last layer's FFN2 partials
        ln_red<4><<<NTOK, 256, 0, stream>>>(x, pbuf, b2 + (size_t)(L_-1)*E_, lnf_g, lnf_b, hbuf);
        gemm3<0><<<nLM, 256, 0, stream>>>(hbuf, lmw, blm, nullptr, nullptr, out,
                                          E_, E_, V_, V_, nLM/8);
    } else {
        // ---------- fallback: round-3 path ----------
        dim3 gQKV(16, 18), gP(16, 6), gF1(16, 24), gLM(16, 393);
        for (int l = 0; l < L_; l++) {
            ln_kernel<<<NTOK, 256, 0, stream>>>(x, ln1_g + (size_t)l*E_, ln1_b + (size_t)l*E_, hbuf);
            gemm2<3,true><<<gQKV, 256, 0, stream>>>(hbuf,
                Wq + (size_t)l*HED, Wk + (size_t)l*HED, Wv + (size_t)l*HED,
                nullptr, nullptr, qb, nullptr, NTOK, 2304, E_, E_, 64, 0);
            attn2<<<gAT, 256, 0, stream>>>(qb, kb, vb, aob);
            gemm2<2,false><<<gP, 256, 0, stream>>>(aob,
                Wproj + (size_t)l*E_*E_, nullptr, nullptr, bproj + (size_t)l*E_,
                x, nullptr, nullptr, NTOK, E_, E_, E_, E_, 0);
            ln_kernel<<<NTOK, 256, 0, stream>>>(x, ln2_g + (size_t)l*E_, ln2_b + (size_t)l*E_, hbuf);
            gemm2<1,false><<<gF1, 256, 0, stream>>>(hbuf,
                W1 + (size_t)l*E_*FF_, nullptr, nullptr, b1 + (size_t)l*FF_,
                nullptr, midb, nullptr, NTOK, FF_, E_, E_, FF_, FF_);
            gemm2<2,false><<<gP, 256, 0, stream>>>(midb,
                W2 + (size_t)l*FF_*E_, nullptr, nullptr, b2 + (size_t)l*E_,
                x, nullptr, nullptr, NTOK, E_, FF_, FF_, E_, 0);
        }
        ln_kernel<<<NTOK, 256, 0, stream>>>(x, lnf_g, lnf_b, hbuf);
        gemm2<0,false><<<gLM, 256, 0, stream>>>(hbuf,
            Wlm, nullptr, nullptr, blm,
            nullptr, nullptr, out, NTOK, V_, E_, E_, V_, V_);
    }
}

// Round 10
// 1913.563 us; speedup vs baseline: 9.5350x; 1.0097x over previous
//
#include <hip/hip_runtime.h>
#include <hip/hip_bf16.h>
#include <stdint.h>

#define B_    2
#define T_    1024
#define V_    50257
#define VPAD_ 50304
#define VPAD2_ 50432          // 197*256 for the 256-wide LM tile
#define E_    768
#define H_    12
#define L_    12
#define D_    64
#define FF_   3072
#define NTOK  (B_*T_)          // 2048
#define SCALE_ (1.0f/((float)E_*(float)E_))

typedef float f32x4 __attribute__((ext_vector_type(4)));
typedef __bf16 bf16x8 __attribute__((ext_vector_type(8)));
typedef short short8 __attribute__((ext_vector_type(8)));

__device__ __forceinline__ float bits2f(short s) {
    unsigned u = ((unsigned)(unsigned short)s) << 16;
    float f; __builtin_memcpy(&f, &u, 4); return f;
}
__device__ __forceinline__ short f2b(float f) {
    unsigned u; __builtin_memcpy(&u, &f, 4);
    unsigned r = (u + 0x7FFFu + ((u >> 16) & 1u)) >> 16;   // RNE
    return (short)r;
}

#define GLOAD16(gsrc, ldst) __builtin_amdgcn_global_load_lds( \
    (const __attribute__((address_space(1))) unsigned*)(gsrc), \
    (__attribute__((address_space(3))) unsigned*)(ldst), 16, 0, 0)

// ---------------- embedding ----------------
__global__ __launch_bounds__(256) void embed_kernel(
    const int* __restrict__ idx, const float* __restrict__ tok,
    const float* __restrict__ pos, float* __restrict__ x)
{
    int m = blockIdx.x, tid = threadIdx.x;
    int row = idx[m];
    int t = m & (T_-1);
    #pragma unroll
    for (int i = 0; i < 3; i++) {
        int e = tid + i*256;
        x[(size_t)m*E_ + e] = tok[(size_t)row*E_ + e] + pos[(size_t)t*E_ + e];
    }
}

// ---------------- layernorm helpers ----------------
__device__ __forceinline__ float block_sum256(float v, float* red) {
    #pragma unroll
    for (int off = 32; off; off >>= 1) v += __shfl_xor(v, off, 64);
    int w = threadIdx.x >> 6;
    __syncthreads();
    if ((threadIdx.x & 63) == 0) red[w] = v;
    __syncthreads();
    return red[0] + red[1] + red[2] + red[3];
}

// plain LN (fallback path)
__global__ __launch_bounds__(256) void ln_kernel(
    const float* __restrict__ x, const float* __restrict__ g,
    const float* __restrict__ bb, short* __restrict__ out)
{
    __shared__ float red[4];
    int m = blockIdx.x, tid = threadIdx.x;
    const float* xr = x + (size_t)m*E_;
    float loc[3]; float s = 0.f;
    #pragma unroll
    for (int i = 0; i < 3; i++) { loc[i] = xr[tid + i*256]; s += loc[i]; }
    s = block_sum256(s, red);
    float mean = s * (1.0f/E_);
    float vs = 0.f;
    #pragma unroll
    for (int i = 0; i < 3; i++) { float d = loc[i] - mean; vs += d*d; }
    vs = block_sum256(vs, red);
    float rstd = rsqrtf(vs * (1.0f/E_) + 1e-5f);
    #pragma unroll
    for (int i = 0; i < 3; i++) {
        int e = tid + i*256;
        out[(size_t)m*E_ + e] = f2b((loc[i] - mean) * rstd * g[e] + bb[e]);
    }
}

// fused residual-reduce (+bias) + LN.  NS = number of split-K partial slices (0 = none).
template<int NS>
__global__ __launch_bounds__(256) void ln_red(
    float* __restrict__ x, const float* __restrict__ pb,
    const float* __restrict__ bias,
    const float* __restrict__ g, const float* __restrict__ bb,
    short* __restrict__ out)
{
    __shared__ float red[4];
    int m = blockIdx.x, tid = threadIdx.x;
    float* xr = x + (size_t)m*E_;
    float loc[3]; float s = 0.f;
    #pragma unroll
    for (int i = 0; i < 3; i++) {
        int e = tid + i*256;
        float v = xr[e];
        if (NS > 0) {
            #pragma unroll
            for (int sp = 0; sp < NS; sp++)
                v += pb[((size_t)sp*NTOK + m)*E_ + e];
            v += bias[e];
            xr[e] = v;
        }
        loc[i] = v; s += v;
    }
    s = block_sum256(s, red);
    float mean = s * (1.0f/E_);
    float vs = 0.f;
    #pragma unroll
    for (int i = 0; i < 3; i++) { float d = loc[i] - mean; vs += d*d; }
    vs = block_sum256(vs, red);
    float rstd = rsqrtf(vs * (1.0f/E_) + 1e-5f);
    #pragma unroll
    for (int i = 0; i < 3; i++) {
        int e = tid + i*256;
        out[(size_t)m*E_ + e] = f2b((loc[i] - mean) * rstd * g[e] + bb[e]);
    }
}

// ---------------- weight packing (vectorized) ----------------
__global__ __launch_bounds__(256) void pack_t(
    const float* __restrict__ src, short* __restrict__ dst,
    int srcK, int srcN, size_t sstride, size_t dstride)
{
    __shared__ float tile[64][65];
    int k0 = blockIdx.x*64, n0 = blockIdx.y*64, l = blockIdx.z;
    const float* s = src + (size_t)l*sstride;
    short* d = dst + (size_t)l*dstride;
    int tid = threadIdx.x;
    const bool vec = (srcN & 3) == 0;
    #pragma unroll
    for (int i = 0; i < 4; i++) {
        int r = (tid >> 4) + i*16;
        int c = (tid & 15) * 4;
        const float* sp = s + (size_t)(k0+r)*srcN + n0 + c;
        if (vec) {
            f32x4 v = *(const f32x4*)sp;
            tile[r][c+0] = v.x; tile[r][c+1] = v.y; tile[r][c+2] = v.z; tile[r][c+3] = v.w;
        } else {
            #pragma unroll
            for (int j = 0; j < 4; j++)
                tile[r][c+j] = (n0 + c + j < srcN) ? sp[j] : 0.f;
        }
    }
    __syncthreads();
    #pragma unroll
    for (int i = 0; i < 2; i++) {
        int r2  = (tid >> 3) + i*32;
        int grp = tid & 7;
        short8 o;
        #pragma unroll
        for (int j = 0; j < 8; j++) o[j] = f2b(tile[grp*8 + j][r2]);
        *(short8*)(d + (size_t)(n0+r2)*srcK + k0 + grp*8) = o;
    }
}

__global__ __launch_bounds__(256) void pack_qkv(
    const float* __restrict__ Wq, const float* __restrict__ Wk,
    const float* __restrict__ Wv, short* __restrict__ dst)
{
    __shared__ float tile[64][65];
    int e0 = blockIdx.x*64;
    int y = blockIdx.y, sel = y/12, h = y - sel*12;
    int l = blockIdx.z;
    const float* s = (sel == 0 ? Wq : (sel == 1 ? Wk : Wv)) + (((size_t)l*H_ + h)*E_)*D_;
    int tid = threadIdx.x;
    #pragma unroll
    for (int i = 0; i < 4; i++) {
        int r = (tid >> 4) + i*16;
        int c = (tid & 15) * 4;
        f32x4 v = *(const f32x4*)(s + (size_t)(e0+r)*D_ + c);
        tile[r][c+0] = v.x; tile[r][c+1] = v.y; tile[r][c+2] = v.z; tile[r][c+3] = v.w;
    }
    __syncthreads();
    short* d_ = dst + (size_t)l*2304*E_;
    #pragma unroll
    for (int i = 0; i < 2; i++) {
        int r2  = (tid >> 3) + i*32;
        int grp = tid & 7;
        short8 o;
        #pragma unroll
        for (int j = 0; j < 8; j++) o[j] = f2b(tile[grp*8 + j][r2]);
        *(short8*)(d_ + (size_t)(sel*768 + h*64 + r2)*E_ + e0 + grp*8) = o;
    }
}

// ---------------- fast bf16 GEMM: 3-buffer, counted-vmcnt pipeline (T4) ----------------
// MODE 0: OutF = acc + bias (col < Nreal);  MODE 1: relu->bf16;  MODE 3: qkv scatter
template<int MODE>
__global__ __launch_bounds__(256) void gemm3(
    const short* __restrict__ A, const short* __restrict__ Bt,
    const float* __restrict__ bias,
    float* __restrict__ X, short* __restrict__ Out, float* __restrict__ OutF,
    int K, int lda, int ldc, int Nreal, int cpx)
{
    __shared__ __align__(16) short As[3][128*32];
    __shared__ __align__(16) short Bs[3][128*32];

    const int tid  = threadIdx.x;
    const int lane = tid & 63, wv = tid >> 6;
    const int wm = wv & 1, wn = wv >> 1;

    int bid = blockIdx.x;
    int g   = (bid & 7)*cpx + (bid >> 3);
    const int m0 = (g & 15) * 128;
    const int n0 = (g >> 4) * 128;

    f32x4 acc[4][4];
    #pragma unroll
    for (int i = 0; i < 4; i++)
        #pragma unroll
        for (int j = 0; j < 4; j++) acc[i][j] = (f32x4){0.f,0.f,0.f,0.f};

    const int srow0 = wv*32 + (lane >> 2);
    const int ssl   = lane & 3;

#define STAGE3(buf, kk) do {                                                  \
    _Pragma("unroll")                                                         \
    for (int i_ = 0; i_ < 2; i_++) {                                          \
        int row_ = srow0 + i_*16;                                             \
        GLOAD16(A  + (size_t)(m0 + row_)*lda + (kk) + ssl*8,                  \
                &As[buf][(wv*128 + i_*64)*8]);                                \
        GLOAD16(Bt + (size_t)(n0 + row_)*K   + (kk) + ssl*8,                  \
                &Bs[buf][(wv*128 + i_*64)*8]);                                \
    } } while(0)

    const int nt = K >> 5;                 // always >= 2 here
    STAGE3(0, 0);
    if (nt > 1) STAGE3(1, 32);

    int cur = 0, nxt2 = 2;
    for (int kt = 0; kt < nt; ++kt) {
        if (kt + 1 < nt) asm volatile("s_waitcnt vmcnt(4)" ::: "memory");
        else             asm volatile("s_waitcnt vmcnt(0)" ::: "memory");
        __builtin_amdgcn_s_barrier();

        bf16x8 af[4], bf[4];
        #pragma unroll
        for (int mi = 0; mi < 4; mi++) {
            int row = wm*64 + mi*16 + (lane & 15);
            af[mi] = *(const bf16x8*)&As[cur][row*32 + (lane >> 4)*8];
        }
        #pragma unroll
        for (int ni = 0; ni < 4; ni++) {
            int col = wn*64 + ni*16 + (lane & 15);
            bf[ni] = *(const bf16x8*)&Bs[cur][col*32 + (lane >> 4)*8];
        }
        if (kt + 2 < nt) STAGE3(nxt2, (kt + 2) << 5);

        #pragma unroll
        for (int ni = 0; ni < 4; ni++)
            #pragma unroll
            for (int mi = 0; mi < 4; mi++)
                acc[mi][ni] = __builtin_amdgcn_mfma_f32_16x16x32_bf16(af[mi], bf[ni], acc[mi][ni], 0,0,0);

        cur  = (cur  == 2) ? 0 : cur + 1;
        nxt2 = (nxt2 == 2) ? 0 : nxt2 + 1;
    }
#undef STAGE3

    const int rb = (lane >> 4) << 2;
    const int cb = lane & 15;
    #pragma unroll
    for (int mi = 0; mi < 4; mi++) {
      #pragma unroll
      for (int ni = 0; ni < 4; ni++) {
        #pragma unroll
        for (int j = 0; j < 4; j++) {
            int row = m0 + wm*64 + mi*16 + rb + j;
            int col = n0 + wn*64 + ni*16 + cb;
            float v = acc[mi][ni][j];
            if (MODE == 0) {
                if (col < Nreal) OutF[(size_t)row*ldc + col] = v + bias[col];
            } else if (MODE == 1) {
                v += bias[col];
                v = v > 0.f ? v : 0.f;
                Out[(size_t)row*ldc + col] = f2b(v);
            } else {
                int nsel = col / 768;
                int c = col - nsel*768;
                int h = c >> 6, d = c & 63;
                int b = row >> 10, t = row & (T_-1);
                short* dst = Out + (size_t)nsel*((size_t)NTOK*E_);
                dst[(((size_t)(b*H_ + h)*T_ + t) << 6) + d] = f2b(v);
            }
        }
      }
    }
}

// ---------------- LM-head GEMM: 256x256 tile, 512 thr / 8 waves, 3-buf counted-vmcnt ----------------
// OutF[row*ldc+col] = acc + bias[col]  (col < Nreal).  Grid: 8 x (Npad/256) panels, XCD-swizzled.
__global__ __launch_bounds__(512) void gemm_lm(
    const short* __restrict__ A, const short* __restrict__ Bt,
    const float* __restrict__ bias, float* __restrict__ OutF,
    int K, int lda, int ldc, int Nreal, int cpx)
{
    __shared__ __align__(16) short As[3][256*32];
    __shared__ __align__(16) short Bs[3][256*32];

    const int tid  = threadIdx.x;
    const int lane = tid & 63, wv = tid >> 6;   // 8 waves
    const int wm = wv & 1, wn = wv >> 1;        // 2 x 4

    int bid = blockIdx.x;
    int g   = (bid & 7)*cpx + (bid >> 3);       // bijective: grid %8 == 0
    const int m0 = (g & 7) * 256;
    const int n0 = (g >> 3) * 256;

    f32x4 acc[8][4];
    #pragma unroll
    for (int i = 0; i < 8; i++)
        #pragma unroll
        for (int j = 0; j < 4; j++) acc[i][j] = (f32x4){0.f,0.f,0.f,0.f};

    // staging: 1024 16B-chunks per matrix; wave wv, lane l, iter i -> chunk i*512 + wv*64 + l
    const int srow0 = wv*16 + (lane >> 2);      // + i*128
    const int ssl   = lane & 3;

#define STAGELM(buf, kk) do {                                                 \
    _Pragma("unroll")                                                         \
    for (int i_ = 0; i_ < 2; i_++) {                                          \
        int row_ = srow0 + i_*128;                                            \
        GLOAD16(A  + (size_t)(m0 + row_)*lda + (kk) + ssl*8,                  \
                &As[buf][(i_*512 + wv*64)*8]);                                \
        GLOAD16(Bt + (size_t)(n0 + row_)*K   + (kk) + ssl*8,                  \
                &Bs[buf][(i_*512 + wv*64)*8]);                                \
    } } while(0)

    const int nt = K >> 5;
    STAGELM(0, 0);
    if (nt > 1) STAGELM(1, 32);

    int cur = 0, nxt2 = 2;
    for (int kt = 0; kt < nt; ++kt) {
        if (kt + 1 < nt) asm volatile("s_waitcnt vmcnt(4)" ::: "memory");
        else             asm volatile("s_waitcnt vmcnt(0)" ::: "memory");
        __builtin_amdgcn_s_barrier();

        bf16x8 af[8], bf[4];
        #pragma unroll
        for (int mi = 0; mi < 8; mi++) {
            int row = wm*128 + mi*16 + (lane & 15);
            af[mi] = *(const bf16x8*)&As[cur][row*32 + (lane >> 4)*8];
        }
        #pragma unroll
        for (int ni = 0; ni < 4; ni++) {
            int col = wn*64 + ni*16 + (lane & 15);
            bf[ni] = *(const bf16x8*)&Bs[cur][col*32 + (lane >> 4)*8];
        }
        if (kt + 2 < nt) STAGELM(nxt2, (kt + 2) << 5);

        #pragma unroll
        for (int ni = 0; ni < 4; ni++)
            #pragma unroll
            for (int mi = 0; mi < 8; mi++)
                acc[mi][ni] = __builtin_amdgcn_mfma_f32_16x16x32_bf16(af[mi], bf[ni], acc[mi][ni], 0,0,0);

        cur  = (cur  == 2) ? 0 : cur + 1;
        nxt2 = (nxt2 == 2) ? 0 : nxt2 + 1;
    }
#undef STAGELM

    const int rb = (lane >> 4) << 2;
    const int cb = lane & 15;
    #pragma unroll
    for (int mi = 0; mi < 8; mi++) {
      #pragma unroll
      for (int ni = 0; ni < 4; ni++) {
        #pragma unroll
        for (int j = 0; j < 4; j++) {
            int row = m0 + wm*128 + mi*16 + rb + j;
            int col = n0 + wn*64 + ni*16 + cb;
            if (col < Nreal)
                OutF[(size_t)row*ldc + col] = acc[mi][ni][j] + bias[col];
        }
      }
    }
}

// ---------------- split-K GEMM (3-buffer counted-vmcnt) ----------------
template<int SPLITS, bool ATOMIC>
__global__ __launch_bounds__(256) void gemm3_sk(
    const short* __restrict__ A, const short* __restrict__ Bt,
    const float* __restrict__ bias, float* __restrict__ X, float* __restrict__ PB,
    int K, int lda)
{
    __shared__ __align__(16) short As[3][128*32];
    __shared__ __align__(16) short Bs[3][128*32];

    const int tid  = threadIdx.x;
    const int lane = tid & 63, wv = tid >> 6;
    const int wm = wv & 1, wn = wv >> 1;

    const int panel = blockIdx.x / SPLITS;
    const int sp    = blockIdx.x % SPLITS;
    const int m0 = (panel & 15) * 128;
    const int n0 = (panel >> 4) * 128;
    const int Ks = K / SPLITS;
    const int kbeg = sp * Ks;

    f32x4 acc[4][4];
    #pragma unroll
    for (int i = 0; i < 4; i++)
        #pragma unroll
        for (int j = 0; j < 4; j++) acc[i][j] = (f32x4){0.f,0.f,0.f,0.f};

    const int srow0 = wv*32 + (lane >> 2);
    const int ssl   = lane & 3;

#define STAGESK(buf, kk) do {                                                 \
    _Pragma("unroll")                                                         \
    for (int i_ = 0; i_ < 2; i_++) {                                          \
        int row_ = srow0 + i_*16;                                             \
        GLOAD16(A  + (size_t)(m0 + row_)*lda + (kk) + ssl*8,                  \
                &As[buf][(wv*128 + i_*64)*8]);                                \
        GLOAD16(Bt + (size_t)(n0 + row_)*K   + (kk) + ssl*8,                  \
                &Bs[buf][(wv*128 + i_*64)*8]);                                \
    } } while(0)

    const int nt = Ks >> 5;
    STAGESK(0, kbeg);
    if (nt > 1) STAGESK(1, kbeg + 32);

    int cur = 0, nxt2 = 2;
    for (int kt = 0; kt < nt; ++kt) {
        if (kt + 1 < nt) asm volatile("s_waitcnt vmcnt(4)" ::: "memory");
        else             asm volatile("s_waitcnt vmcnt(0)" ::: "memory");
        __builtin_amdgcn_s_barrier();

        bf16x8 af[4], bf[4];
        #pragma unroll
        for (int mi = 0; mi < 4; mi++) {
            int row = wm*64 + mi*16 + (lane & 15);
            af[mi] = *(const bf16x8*)&As[cur][row*32 + (lane >> 4)*8];
        }
        #pragma unroll
        for (int ni = 0; ni < 4; ni++) {
            int col = wn*64 + ni*16 + (lane & 15);
            bf[ni] = *(const bf16x8*)&Bs[cur][col*32 + (lane >> 4)*8];
        }
        if (kt + 2 < nt) STAGESK(nxt2, kbeg + ((kt + 2) << 5));

        #pragma unroll
        for (int ni = 0; ni < 4; ni++)
            #pragma unroll
            for (int mi = 0; mi < 4; mi++)
                acc[mi][ni] = __builtin_amdgcn_mfma_f32_16x16x32_bf16(af[mi], bf[ni], acc[mi][ni], 0,0,0);

        cur  = (cur  == 2) ? 0 : cur + 1;
        nxt2 = (nxt2 == 2) ? 0 : nxt2 + 1;
    }
#undef STAGESK

    const int rb = (lane >> 4) << 2;
    const int cb = lane & 15;
    #pragma unroll
    for (int mi = 0; mi < 4; mi++) {
      #pragma unroll
      for (int ni = 0; ni < 4; ni++) {
        #pragma unroll
        for (int j = 0; j < 4; j++) {
            int row = m0 + wm*64 + mi*16 + rb + j;
            int col = n0 + wn*64 + ni*16 + cb;
            float v = acc[mi][ni][j];
            if (ATOMIC) {
                if (sp == 0) v += bias[col];
                atomicAdd(&X[(size_t)row*E_ + col], v);
            } else {
                PB[((size_t)sp*NTOK + row)*E_ + col] = v;
            }
        }
      }
    }
}

// ---------------- flash attention (faithful swap: "Q"=k-proj, "K"=q-proj) ----------------
__global__ __launch_bounds__(256) void attn2(
    const short* __restrict__ qg, const short* __restrict__ kg,
    const short* __restrict__ vg, short* __restrict__ ao)
{
    __shared__ __align__(16) short Kt[64*64];
    __shared__ __align__(16) short Qs[64*64];
    __shared__ __align__(16) short Vs[64*64];
    __shared__ __align__(16) short Ps[4][16*64];

    const int tid = threadIdx.x, lane = tid & 63, w = tid >> 6, g = lane >> 4;
    const int t0 = blockIdx.x * 64;
    const int bh = blockIdx.y;
    const size_t base = (size_t)bh * T_ * 64;

    #pragma unroll
    for (int is = 0; is < 2; is++) {
        int idx = is*256 + tid;
        int row = idx >> 3, sl = idx & 7;
        short8 v = *(const short8*)(kg + base + (size_t)(t0+row)*64 + sl*8);
        *(short8*)&Kt[row*64 + (sl ^ (row&7))*8] = v;
    }
    __syncthreads();

    bf16x8 akt[2];
    {
        int lt = w*16 + (lane & 15);
        #pragma unroll
        for (int c = 0; c < 2; c++)
            akt[c] = *(const bf16x8*)&Kt[lt*64 + ((c*4+g) ^ (lt&7))*8];
    }

    f32x4 o[4]; float m_run[4], l_run[4];
    #pragma unroll
    for (int i = 0; i < 4; i++) { o[i] = (f32x4){0,0,0,0}; m_run[i] = -1e30f; l_run[i] = 0.f; }

    const int qrow = tid >> 3, qsl = tid & 7;
    const int vd0 = (tid & 31) * 2;
    const int vsh = tid >> 5;

    short8 qv[2];
    unsigned vvr[8];

#define REGLOAD(s0_) do {                                                        \
    _Pragma("unroll")                                                            \
    for (int is_ = 0; is_ < 2; is_++)                                            \
        qv[is_] = *(const short8*)(qg + base + (size_t)((s0_) + qrow + is_*32)*64 + qsl*8); \
    _Pragma("unroll")                                                            \
    for (int i_ = 0; i_ < 8; i_++)                                               \
        vvr[i_] = *(const unsigned*)(vg + base + (size_t)((s0_) + vsh*8 + i_)*64 + vd0);    \
    } while(0)

    const int ntiles = (t0 >> 6) + 1;
    REGLOAD(0);

    for (int it = 0; it < ntiles; ++it) {
        __syncthreads();
        #pragma unroll
        for (int is = 0; is < 2; is++) {
            int row = qrow + is*32;
            *(short8*)&Qs[row*64 + (qsl ^ (row&7))*8] = qv[is];
        }
        #pragma unroll
        for (int dp = 0; dp < 2; dp++) {
            int d = vd0 + dp;
            short tmp[8];
            #pragma unroll
            for (int i = 0; i < 8; i++) tmp[i] = (short)((vvr[i] >> (dp*16)) & 0xffffu);
            *(short8*)&Vs[d*64 + (vsh ^ (d&7))*8] = *(short8*)tmp;
        }
        if (it + 1 < ntiles) REGLOAD((it+1)*64);
        __syncthreads();

        const int s0 = it*64;
        f32x4 s4[4];
        #pragma unroll
        for (int j = 0; j < 4; j++) s4[j] = (f32x4){0,0,0,0};
        #pragma unroll
        for (int c = 0; c < 2; c++) {
            #pragma unroll
            for (int j = 0; j < 4; j++) {
                int sr = j*16 + (lane & 15);
                bf16x8 bq = *(const bf16x8*)&Qs[sr*64 + ((c*4+g) ^ (sr&7))*8];
                s4[j] = __builtin_amdgcn_mfma_f32_16x16x32_bf16(akt[c], bq, s4[j], 0,0,0);
            }
        }
        float p[4][4];
        const bool diag = (it == ntiles-1);
        #pragma unroll
        for (int j = 0; j < 4; j++) {
          #pragma unroll
          for (int r = 0; r < 4; r++) {
            float v = s4[j][r] * SCALE_;
            if (diag) {
                int tglob = t0 + w*16 + g*4 + r;
                int sglob = s0 + j*16 + (lane & 15);
                if (sglob > tglob) v = -1e30f;
            }
            p[j][r] = v;
          }
        }
        #pragma unroll
        for (int r = 0; r < 4; r++) {
            float mx = fmaxf(fmaxf(p[0][r], p[1][r]), fmaxf(p[2][r], p[3][r]));
            #pragma unroll
            for (int off = 1; off < 16; off <<= 1) mx = fmaxf(mx, __shfl_xor(mx, off, 64));
            float mnew  = fmaxf(m_run[r], mx);
            float alpha = __expf(m_run[r] - mnew);
            float rs = 0.f;
            #pragma unroll
            for (int j = 0; j < 4; j++) { p[j][r] = __expf(p[j][r] - mnew); rs += p[j][r]; }
            #pragma unroll
            for (int off = 1; off < 16; off <<= 1) rs += __shfl_xor(rs, off, 64);
            l_run[r] = l_run[r]*alpha + rs;
            m_run[r] = mnew;
            #pragma unroll
            for (int ni = 0; ni < 4; ni++) o[ni][r] *= alpha;
        }
        #pragma unroll
        for (int j = 0; j < 4; j++) {
          #pragma unroll
          for (int r = 0; r < 4; r++) {
            int tl = g*4 + r, sc = j*16 + (lane & 15);
            Ps[w][tl*64 + ((sc>>3) ^ (tl&7))*8 + (sc&7)] = f2b(p[j][r]);
          }
        }
        asm volatile("s_waitcnt lgkmcnt(0)" ::: "memory");
        __builtin_amdgcn_sched_barrier(0);
        #pragma unroll
        for (int c = 0; c < 2; c++) {
            int tl = lane & 15;
            bf16x8 pa = *(const bf16x8*)&Ps[w][tl*64 + ((c*4+g) ^ (tl&7))*8];
            #pragma unroll
            for (int ni = 0; ni < 4; ni++) {
                int d = ni*16 + (lane & 15);
                bf16x8 bv = *(const bf16x8*)&Vs[d*64 + ((c*4+g) ^ (d&7))*8];
                o[ni] = __builtin_amdgcn_mfma_f32_16x16x32_bf16(pa, bv, o[ni], 0,0,0);
            }
        }
    }
#undef REGLOAD

    const int b = bh / H_, h = bh - b*H_;
    #pragma unroll
    for (int ni = 0; ni < 4; ni++) {
      #pragma unroll
      for (int r = 0; r < 4; r++) {
        int t = t0 + w*16 + g*4 + r;
        int d = ni*16 + (lane & 15);
        ao[((size_t)(b*T_ + t))*E_ + h*64 + d] = f2b(o[ni][r] / l_run[r]);
      }
    }
}

// ---------------- fallback GEMM (fp32 B on the fly) ----------------
template<int MODE, bool QKV3>
__global__ __launch_bounds__(256) void gemm2(
    const short* __restrict__ A,
    const float* __restrict__ Bq, const float* __restrict__ Bk2, const float* __restrict__ Bv2,
    const float* __restrict__ bias,
    float* __restrict__ X, short* __restrict__ Out, float* __restrict__ OutF,
    int M, int Ntot, int K, int lda, int kstride, int ldc)
{
    __shared__ __align__(16) short As[128*32];
    __shared__ __align__(16) short Bs[128*32];

    const int tid  = threadIdx.x;
    const int lane = tid & 63, wave = tid >> 6;
    const int wm = wave & 1, wn = wave >> 1;
    const int m0 = blockIdx.x * 128;
    const int n0 = blockIdx.y * 128;
    const int g  = lane >> 4;

    const float* Bm = Bq;
    int nsel = 0, c0 = n0;
    if (QKV3) {
        nsel = n0 / 768;
        c0 = n0 - nsel*768;
        Bm = (nsel == 0) ? Bq : (nsel == 1 ? Bk2 : Bv2);
    }

    f32x4 acc[4][4];
    #pragma unroll
    for (int i = 0; i < 4; i++)
        #pragma unroll
        for (int j = 0; j < 4; j++) acc[i][j] = (f32x4){0.f,0.f,0.f,0.f};

    const int bn  = tid & 127;
    const int bkh = tid >> 7;
    const int cg  = c0 + bn;
    const bool bvalid = QKV3 ? true : (cg < Ntot);
    size_t bbase;
    if (QKV3) bbase = (size_t)(cg >> 6) * ((size_t)E_*D_) + (cg & 63);
    else      bbase = (size_t)cg;

    for (int k0 = 0; k0 < K; k0 += 32) {
        #pragma unroll
        for (int is = 0; is < 2; is++) {
            int idx = is*256 + tid;
            int row = idx >> 2, sl = idx & 3;
            short8 v = *(const short8*)(A + (size_t)(m0+row)*lda + k0 + sl*8);
            int sl2 = sl ^ ((row ^ (row>>2)) & 3);
            *(short8*)&As[row*32 + sl2*8] = v;
        }
        {
            float bv[16];
            #pragma unroll
            for (int i = 0; i < 16; i++) {
                int k = k0 + bkh*16 + i;
                bv[i] = bvalid ? Bm[bbase + (size_t)k*kstride] : 0.f;
            }
            short bh16[16];
            #pragma unroll
            for (int i = 0; i < 16; i++) {
                __bf16 h = (__bf16)bv[i];
                bh16[i] = __builtin_bit_cast(short, h);
            }
            #pragma unroll
            for (int q = 0; q < 2; q++) {
                int kb  = bkh*2 + q;
                int sl2 = kb ^ ((bn ^ (bn>>2)) & 3);
                *(short8*)&Bs[bn*32 + sl2*8] = *(short8*)&bh16[q*8];
            }
        }
        __syncthreads();

        bf16x8 af[4];
        #pragma unroll
        for (int mi = 0; mi < 4; mi++) {
            int row = wm*64 + mi*16 + (lane & 15);
            int sl2 = g ^ ((row ^ (row>>2)) & 3);
            af[mi] = *(const bf16x8*)&As[row*32 + sl2*8];
        }
        #pragma unroll
        for (int ni = 0; ni < 4; ni++) {
            int nn  = wn*64 + ni*16 + (lane & 15);
            int sl2 = g ^ ((nn ^ (nn>>2)) & 3);
            bf16x8 bfr = *(const bf16x8*)&Bs[nn*32 + sl2*8];
            #pragma unroll
            for (int mi = 0; mi < 4; mi++)
                acc[mi][ni] = __builtin_amdgcn_mfma_f32_16x16x32_bf16(af[mi], bfr, acc[mi][ni], 0,0,0);
        }
        __syncthreads();
    }

    const int rb = g << 2;
    const int cb = lane & 15;
    #pragma unroll
    for (int mi = 0; mi < 4; mi++) {
      #pragma unroll
      for (int ni = 0; ni < 4; ni++) {
        #pragma unroll
        for (int j = 0; j < 4; j++) {
            int row = m0 + wm*64 + mi*16 + rb + j;
            int col = n0 + wn*64 + ni*16 + cb;
            float v = acc[mi][ni][j];
            if (MODE == 0) {
                if (col < Ntot) OutF[(size_t)row*ldc + col] = v + bias[col];
            } else if (MODE == 1) {
                v += bias[col];
                v = v > 0.f ? v : 0.f;
                Out[(size_t)row*ldc + col] = f2b(v);
            } else if (MODE == 2) {
                X[(size_t)row*E_ + col] += v + bias[col];
            } else {
                int c = col - nsel*768;
                int h = c >> 6, d = c & 63;
                int b = row >> 10, t = row & (T_-1);
                short* dst = Out + (size_t)nsel*((size_t)NTOK*E_);
                dst[(((size_t)(b*H_ + h)*T_ + t) << 6) + d] = f2b(v);
            }
        }
      }
    }
}

// ---------------- host launch ----------------
extern "C" void kernel_launch(void* const* d_in, const int* in_sizes, int n_in,
                              void* d_out, int out_size, void* d_ws, size_t ws_size,
                              hipStream_t stream)
{
    (void)in_sizes; (void)n_in; (void)out_size;

    const int*   idx     = (const int*)  d_in[0];
    const float* tok_emb = (const float*)d_in[1];
    const float* pos_emb = (const float*)d_in[2];
    const float* Wk      = (const float*)d_in[3];
    const float* Wq      = (const float*)d_in[4];
    const float* Wv      = (const float*)d_in[5];
    const float* Wproj   = (const float*)d_in[6];
    const float* bproj   = (const float*)d_in[7];
    const float* ln1_g   = (const float*)d_in[8];
    const float* ln1_b   = (const float*)d_in[9];
    const float* W1      = (const float*)d_in[10];
    const float* b1      = (const float*)d_in[11];
    const float* W2      = (const float*)d_in[12];
    const float* b2      = (const float*)d_in[13];
    const float* ln2_g   = (const float*)d_in[14];
    const float* ln2_b   = (const float*)d_in[15];
    const float* lnf_g   = (const float*)d_in[16];
    const float* lnf_b   = (const float*)d_in[17];
    const float* Wlm     = (const float*)d_in[18];
    const float* blm     = (const float*)d_in[19];
    float* out = (float*)d_out;

    char* w = (char*)d_ws;
    float* x    = (float*)w; w += (size_t)NTOK*E_*4;
    short* hbuf = (short*)w; w += (size_t)NTOK*E_*2;
    short* qb   = (short*)w; w += (size_t)NTOK*E_*2;
    short* kb   = (short*)w; w += (size_t)NTOK*E_*2;
    short* vb   = (short*)w; w += (size_t)NTOK*E_*2;
    short* aob  = (short*)w; w += (size_t)NTOK*E_*2;
    short* midb = (short*)w; w += (size_t)NTOK*FF_*2;
    float* pbuf = (float*)w; w += (size_t)4*NTOK*E_*4;   // split-K partials (4 slices max)

    const size_t act_bytes = (size_t)(w - (char*)d_ws);
    const size_t wqkv_n = (size_t)L_*2304*E_;
    const size_t wproj_n = (size_t)L_*E_*E_;
    const size_t wff_n = (size_t)L_*E_*FF_;
    const size_t wlm_n = (size_t)VPAD2_*E_;
    const size_t need = act_bytes + 2*(wqkv_n + wproj_n + 2*wff_n + wlm_n);

    const size_t HED = (size_t)H_*E_*D_;
    dim3 gAT(T_/64, B_*H_);

    embed_kernel<<<NTOK, 256, 0, stream>>>(idx, tok_emb, pos_emb, x);

    if (ws_size >= need) {
        // ---------- fast path: prepack weights to bf16 (B^T layout) ----------
        short* qkvw = (short*)w; w += wqkv_n*2;
        short* projw= (short*)w; w += wproj_n*2;
        short* w1w  = (short*)w; w += wff_n*2;
        short* w2w  = (short*)w; w += wff_n*2;
        short* lmw  = (short*)w;

        pack_qkv<<<dim3(E_/64, 36, L_), 256, 0, stream>>>(Wq, Wk, Wv, qkvw);
        pack_t<<<dim3(E_/64, E_/64, L_), 256, 0, stream>>>(Wproj, projw, E_, E_, (size_t)E_*E_, (size_t)E_*E_);
        pack_t<<<dim3(E_/64, FF_/64, L_), 256, 0, stream>>>(W1, w1w, E_, FF_, (size_t)E_*FF_, (size_t)E_*FF_);
        pack_t<<<dim3(FF_/64, E_/64, L_), 256, 0, stream>>>(W2, w2w, FF_, E_, (size_t)E_*FF_, (size_t)E_*FF_);
        pack_t<<<dim3(E_/64, VPAD2_/64, 1), 256, 0, stream>>>(Wlm, lmw, E_, V_, 0, 0);

        const int nQKV = 16*(2304/128), nF1 = 16*(FF_/128);
        const int nP = 16*(E_/128);    // 96 panels for N=768
        const int nLM2 = 8*(VPAD2_/256);   // 8 x 197 = 1576

        for (int l = 0; l < L_; l++) {
            if (l == 0)
                ln_red<0><<<NTOK, 256, 0, stream>>>(x, nullptr, nullptr,
                    ln1_g + (size_t)l*E_, ln1_b + (size_t)l*E_, hbuf);
            else
                ln_red<4><<<NTOK, 256, 0, stream>>>(x, pbuf, b2 + (size_t)(l-1)*E_,
                    ln1_g + (size_t)l*E_, ln1_b + (size_t)l*E_, hbuf);

            gemm3<3><<<nQKV, 256, 0, stream>>>(hbuf, qkvw + (size_t)l*2304*E_, nullptr,
                                               nullptr, qb, nullptr, E_, E_, 0, 2304, nQKV/8);
            attn2<<<gAT, 256, 0, stream>>>(qb, kb, vb, aob);

            gemm3_sk<2,false><<<nP*2, 256, 0, stream>>>(aob, projw + (size_t)l*E_*E_,
                                                        nullptr, nullptr, pbuf, E_, E_);
            ln_red<2><<<NTOK, 256, 0, stream>>>(x, pbuf, bproj + (size_t)l*E_,
                ln2_g + (size_t)l*E_, ln2_b + (size_t)l*E_, hbuf);

            gemm3<1><<<nF1, 256, 0, stream>>>(hbuf, w1w + (size_t)l*E_*FF_, b1 + (size_t)l*FF_,
                                              nullptr, midb, nullptr, E_, E_, FF_, FF_, nF1/8);
            gemm3_sk<4,false><<<nP*4, 256, 0, stream>>>(midb, w2w + (size_t)l*E_*FF_,
                                                        nullptr, nullptr, pbuf, FF_, FF_);
        }
        ln_red<4><<<NTOK, 256, 0, stream>>>(x, pbuf, b2 + (size_t)(L_-1)*E_, lnf_g, lnf_b, hbuf);
        gemm_lm<<<nLM2, 512, 0, stream>>>(hbuf, lmw, blm, out, E_, E_, V_, V_, nLM2/8);
    } else {
        // ---------- fallback: round-3 path ----------
        dim3 gQKV(16, 18), gP(16, 6), gF1(16, 24), gLM(16, 393);
        for (int l = 0; l < L_; l++) {
            ln_kernel<<<NTOK, 256, 0, stream>>>(x, ln1_g + (size_t)l*E_, ln1_b + (size_t)l*E_, hbuf);
            gemm2<3,true><<<gQKV, 256, 0, stream>>>(hbuf,
                Wq + (size_t)l*HED, Wk + (size_t)l*HED, Wv + (size_t)l*HED,
                nullptr, nullptr, qb, nullptr, NTOK, 2304, E_, E_, 64, 0);
            attn2<<<gAT, 256, 0, stream>>>(qb, kb, vb, aob);
            gemm2<2,false><<<gP, 256, 0, stream>>>(aob,
                Wproj + (size_t)l*E_*E_, nullptr, nullptr, bproj + (size_t)l*E_,
                x, nullptr, nullptr, NTOK, E_, E_, E_, E_, 0);
            ln_kernel<<<NTOK, 256, 0, stream>>>(x, ln2_g + (size_t)l*E_, ln2_b + (size_t)l*E_, hbuf);
            gemm2<1,false><<<gF1, 256, 0, stream>>>(hbuf,
                W1 + (size_t)l*E_*FF_, nullptr, nullptr, b1 + (size_t)l*FF_,
                nullptr, midb, nullptr, NTOK, FF_, E_, E_, FF_, FF_);
            gemm2<2,false><<<gP, 256, 0, stream>>>(midb,
                W2 + (size_t)l*FF_*E_, nullptr, nullptr, b2 + (size_t)l*E_,
                x, nullptr, nullptr, NTOK, E_, FF_, FF_, E_, 0);
        }
        ln_kernel<<<NTOK, 256, 0, stream>>>(x, lnf_g, lnf_b, hbuf);
        gemm2<0,false><<<gLM, 256, 0, stream>>>(hbuf,
            Wlm, nullptr, nullptr, blm,
            nullptr, nullptr, out, NTOK, V_, E_, E_, V_, V_);
    }
}